// Round 13
// baseline (504.995 us; speedup 1.0000x reference)
//
#include <hip/hip_runtime.h>
#include <math.h>

// Problem constants
#define NVAR 3
#define BB 4
#define CC 256
#define C1 128
#define HEADS 4
#define HH 64
#define WW 64
#define HW 4096
#define RPE_W 127
#define NP 3
#define SCALE 0.17677669529663687f
// pairs: p=0 -> (i=1,j=0), p=1 -> (i=2,j=0), p=2 -> (i=2,j=1)

typedef short bf16x8 __attribute__((ext_vector_type(8)));
typedef float f32x4 __attribute__((ext_vector_type(4)));
typedef __bf16 bf16x2 __attribute__((ext_vector_type(2)));

__device__ __forceinline__ unsigned short f2bf(float f) {
    unsigned int u = __float_as_uint(f);
    u += 0x7fffu + ((u >> 16) & 1u);          // round-to-nearest-even
    return (unsigned short)(u >> 16);
}
__device__ __forceinline__ float bflo(unsigned u) { return __uint_as_float(u << 16); }
__device__ __forceinline__ float bfhi(unsigned u) { return __uint_as_float(u & 0xffff0000u); }

// packed bf16x2 dot: c + a.lo*b.lo + a.hi*b.hi
__device__ __forceinline__ float dot2bf(unsigned a, unsigned b, float c) {
#if __has_builtin(__builtin_amdgcn_fdot2_f32_bf16)
    return __builtin_amdgcn_fdot2_f32_bf16(__builtin_bit_cast(bf16x2, a),
                                           __builtin_bit_cast(bf16x2, b), c, false);
#else
    return c + bflo(a) * bflo(b) + bfhi(a) * bfhi(b);
#endif
}

// ---------------------------------------------------------------------------
// K1) const prep (blocks 0..23) + copy x0 -> out var0 + flow zeros (24..1047)
__global__ __launch_bounds__(256) void prep_copy(const float* __restrict__ rpe,
                                                 const float* __restrict__ Wq,
                                                 const float* __restrict__ Wo,
                                                 const float* __restrict__ Wk,
                                                 const float* __restrict__ Wv,
                                                 const float* __restrict__ x0,
                                                 unsigned short* __restrict__ tabbf,
                                                 unsigned short* __restrict__ wqh,
                                                 unsigned short* __restrict__ wql,
                                                 unsigned short* __restrict__ woh,
                                                 unsigned short* __restrict__ wkh,
                                                 unsigned short* __restrict__ wvh,
                                                 float* __restrict__ out) {
    int blk = blockIdx.x;
    if (blk >= 24) {
        const long long n4 = (long long)BB * CC * HW / 4;
        long long i = (long long)(blk - 24) * 256 + threadIdx.x;
        const long long stride = 1024LL * 256;
        for (; i < n4 + 12; i += stride) {
            if (i < n4) ((float4*)out)[i] = ((const float4*)x0)[i];
            else out[3LL * BB * CC * HW + (i - n4)] = 0.f;
        }
        return;
    }
    if (blk < 12) {
        const float* src = rpe + (long long)blk * RPE_W * RPE_W;
        unsigned short* dst = tabbf + (long long)blk * 16384;
        for (int idx = threadIdx.x; idx < 16384; idx += 256) {
            int y = idx >> 7, x = idx & 127;
            float v = (y < RPE_W && x < RPE_W) ? src[y * RPE_W + x] : 0.f;
            dst[idx] = f2bf(v);
        }
    } else if (blk < 15) {
        int p = blk - 12;
        for (int i = threadIdx.x; i < 16384; i += 256) {
            float w = Wq[p * 16384 + i];
            unsigned short h = f2bf(w);
            wqh[p * 16384 + i] = h;
            wql[p * 16384 + i] = f2bf(w - bflo((unsigned)h));
        }
    } else if (blk < 18) {
        int p = blk - 15;
        for (int i = threadIdx.x; i < 16384; i += 256)
            woh[p * 16384 + i] = f2bf(Wo[p * 16384 + i]);
    } else if (blk < 21) {
        int p = blk - 18;
        for (int i = threadIdx.x; i < 16384; i += 256)
            wkh[p * 16384 + i] = f2bf(Wk[p * 16384 + i]);
    } else {
        int p = blk - 21;
        for (int i = threadIdx.x; i < 16384; i += 256)
            wvh[p * 16384 + i] = f2bf(Wv[p * 16384 + i]);
    }
}

// ---------------------------------------------------------------------------
// K2) conv_q via MFMA, split bf16 (hi+lo). Outputs qbuf f32 [pb][c][m],
//     qbf bf16 [pb][m][c] (pre-scaled, coalesced via LDS bounce), AND copies
//     x chans 0:128 into out.
__global__ __launch_bounds__(256) void conv_q(const float* __restrict__ x1,
                                              const float* __restrict__ x2,
                                              const unsigned short* __restrict__ wqh,
                                              const unsigned short* __restrict__ wql,
                                              const float* __restrict__ bq,
                                              float* __restrict__ qbuf,
                                              unsigned short* __restrict__ qbf,
                                              float* __restrict__ out) {
    __shared__ unsigned short qlds[4][16][136];   // 17 KB; 16B-aligned rows
    int wid = threadIdx.x >> 6, lane = threadIdx.x & 63;
    int g = lane >> 4, lm = lane & 15;
    int gw = blockIdx.x * 4 + wid;            // 3072 waves
    int mt = gw & 255;
    int pb = gw >> 8;
    int p = pb >> 2, b = pb & 3;
    const float* X = ((p == 0) ? x1 : x2) + (long long)b * CC * HW;
    int m = mt * 16 + lm;
    float* outc = (p < 2)
        ? out + (((long long)((p + 1) * 4 + b)) * CC) * HW + m
        : nullptr;

    bf16x8 bhi[4], blo[4];
#pragma unroll
    for (int ksl = 0; ksl < 4; ksl++) {
        float v[8];
#pragma unroll
        for (int j = 0; j < 8; j++) {
            int k = ksl * 32 + 8 * g + j;
            v[j] = X[(long long)k * HW + m];
            if (outc) outc[(long long)k * HW] = v[j];
        }
        union { unsigned u[4]; bf16x8 v; } H, L;
#pragma unroll
        for (int t = 0; t < 4; t++) {
            unsigned short h0 = f2bf(v[2 * t]), h1 = f2bf(v[2 * t + 1]);
            unsigned short l0 = f2bf(v[2 * t] - bflo((unsigned)h0));
            unsigned short l1 = f2bf(v[2 * t + 1] - bflo((unsigned)h1));
            H.u[t] = (unsigned)h0 | ((unsigned)h1 << 16);
            L.u[t] = (unsigned)l0 | ((unsigned)l1 << 16);
        }
        bhi[ksl] = H.v;
        blo[ksl] = L.v;
    }

    const unsigned short* WH = wqh + p * 16384;
    const unsigned short* WL = wql + p * 16384;
    unsigned short* ql = &qlds[wid][lm][0];
    f32x4 zero = {0.f, 0.f, 0.f, 0.f};
#pragma unroll
    for (int ct2 = 0; ct2 < 4; ct2++) {
        int ct0 = 2 * ct2, ct1 = ct0 + 1;
        f32x4 a0 = zero, a1 = zero;
#pragma unroll
        for (int ksl = 0; ksl < 4; ksl++) {
            bf16x8 Ah0 = *(const bf16x8*)(WH + (ct0 * 16 + lm) * 128 + ksl * 32 + 8 * g);
            bf16x8 Al0 = *(const bf16x8*)(WL + (ct0 * 16 + lm) * 128 + ksl * 32 + 8 * g);
            bf16x8 Ah1 = *(const bf16x8*)(WH + (ct1 * 16 + lm) * 128 + ksl * 32 + 8 * g);
            bf16x8 Al1 = *(const bf16x8*)(WL + (ct1 * 16 + lm) * 128 + ksl * 32 + 8 * g);
            a0 = __builtin_amdgcn_mfma_f32_16x16x32_bf16(Ah0, bhi[ksl], a0, 0, 0, 0);
            a1 = __builtin_amdgcn_mfma_f32_16x16x32_bf16(Ah1, bhi[ksl], a1, 0, 0, 0);
            a0 = __builtin_amdgcn_mfma_f32_16x16x32_bf16(Ah0, blo[ksl], a0, 0, 0, 0);
            a1 = __builtin_amdgcn_mfma_f32_16x16x32_bf16(Ah1, blo[ksl], a1, 0, 0, 0);
            a0 = __builtin_amdgcn_mfma_f32_16x16x32_bf16(Al0, bhi[ksl], a0, 0, 0, 0);
            a1 = __builtin_amdgcn_mfma_f32_16x16x32_bf16(Al1, bhi[ksl], a1, 0, 0, 0);
        }
        float q0[4], q1[4];
#pragma unroll
        for (int r = 0; r < 4; r++) {
            int c0 = ct0 * 16 + 4 * g + r, c1 = ct1 * 16 + 4 * g + r;
            q0[r] = a0[r] + bq[p * 128 + c0];
            q1[r] = a1[r] + bq[p * 128 + c1];
            qbuf[((long long)pb * 128 + c0) * HW + m] = q0[r];
            qbuf[((long long)pb * 128 + c1) * HW + m] = q1[r];
        }
        *(unsigned*)(ql + ct0 * 16 + 4 * g) =
            (unsigned)f2bf(q0[0] * SCALE) | ((unsigned)f2bf(q0[1] * SCALE) << 16);
        *(unsigned*)(ql + ct0 * 16 + 4 * g + 2) =
            (unsigned)f2bf(q0[2] * SCALE) | ((unsigned)f2bf(q0[3] * SCALE) << 16);
        *(unsigned*)(ql + ct1 * 16 + 4 * g) =
            (unsigned)f2bf(q1[0] * SCALE) | ((unsigned)f2bf(q1[1] * SCALE) << 16);
        *(unsigned*)(ql + ct1 * 16 + 4 * g + 2) =
            (unsigned)f2bf(q1[2] * SCALE) | ((unsigned)f2bf(q1[3] * SCALE) << 16);
    }

    // same-wave LDS readback -> coalesced 1KB-contiguous global stores
    unsigned short* Yb = qbf + ((long long)pb * HW + mt * 16) * 128;
    int q = lane >> 4, cg = lane & 15;
#pragma unroll
    for (int i = 0; i < 4; i++) {
        int row = i * 4 + q;
        uint4 vv = *(const uint4*)&qlds[wid][row][cg * 8];
        *(uint4*)(Yb + row * 128 + cg * 8) = vv;
    }
}

// ---------------------------------------------------------------------------
// K3) fused middle kernel:
//   blocks 0..191:  offset net (depthwise conv staged in LDS -> LN -> GELU ->
//                   1x1 -> pos + prm), per (pb,hk); 'off' never leaves LDS.
//   blocks 192..2239: transpose x0,x1 chans 0:128 -> xT bf16 [v][b][m][c].
__global__ __launch_bounds__(256) void mid_kernel(const float* __restrict__ qbuf,
                                                  const float* __restrict__ dw_w,
                                                  const float* __restrict__ dw_b,
                                                  const float* __restrict__ ln_g,
                                                  const float* __restrict__ ln_b,
                                                  const float* __restrict__ pw_w,
                                                  const float* __restrict__ x0,
                                                  const float* __restrict__ x1,
                                                  float* __restrict__ posb,
                                                  uint4* __restrict__ prmb,
                                                  unsigned short* __restrict__ xT) {
    __shared__ float sm[32 * 4 * 65 + 16 * 128];     // 41.5 KB
    int blk = blockIdx.x;
    int tid = threadIdx.x;
    if (blk < 192) {
        float (*ld)[4][65] = (float(*)[4][65])sm;
        float (*dwout)[128] = (float(*)[128])(sm + 32 * 4 * 65);
        int pb = blk >> 4, hk = blk & 15;
        int p = pb >> 2;
        for (int cq = 0; cq < 4; cq++) {
            int c32 = cq * 32;
            __syncthreads();
#pragma unroll
            for (int it = 0; it < 8; it++) {
                int i2 = tid + it * 256;          // 2048 float4
                int c = i2 >> 6, rem = i2 & 63;
                int y = rem >> 4, xq = rem & 15;
                float4 v = *(const float4*)(qbuf + ((long long)pb * 128 + c32 + c) * HW
                                            + (4 * hk + y) * 64 + xq * 4);
                ld[c][y][xq * 4 + 0] = v.x;
                ld[c][y][xq * 4 + 1] = v.y;
                ld[c][y][xq * 4 + 2] = v.z;
                ld[c][y][xq * 4 + 3] = v.w;
            }
            __syncthreads();
            int wk = tid >> 4;
#pragma unroll
            for (int oi = 0; oi < 2; oi++) {
                int c = (tid & 15) + oi * 16;
                const float* dwp = dw_w + (p * 128 + c32 + c) * 16;
                float acc = dw_b[p * 128 + c32 + c];
#pragma unroll
                for (int ky = 0; ky < 4; ky++)
#pragma unroll
                    for (int kx = 0; kx < 4; kx++)
                        acc += ld[c][ky][wk * 4 + kx] * dwp[ky * 4 + kx];
                dwout[wk][c32 + c] = acc;
            }
        }
        __syncthreads();
        // LN phase: 4 waves x 4 wk each
        int wid = tid >> 6, lane = tid & 63;
        for (int i = 0; i < 4; i++) {
            int wk = wid * 4 + i;
            int s = hk * 16 + wk;
            float a0 = dwout[wk][lane], a1 = dwout[wk][lane + 64];
            float s1 = a0 + a1;
#pragma unroll
            for (int o = 1; o < 64; o <<= 1) s1 += __shfl_xor(s1, o);
            float mu = s1 * (1.f / 128.f);
            float d0 = a0 - mu, d1 = a1 - mu;
            float v2 = d0 * d0 + d1 * d1;
#pragma unroll
            for (int o = 1; o < 64; o <<= 1) v2 += __shfl_xor(v2, o);
            float rs = rsqrtf(v2 * (1.f / 128.f) + 1e-5f);
            int c0 = lane, c1 = lane + 64;
            float y0 = d0 * rs * ln_g[p * 128 + c0] + ln_b[p * 128 + c0];
            float y1 = d1 * rs * ln_g[p * 128 + c1] + ln_b[p * 128 + c1];
            float g0 = 0.5f * y0 * (1.f + erff(y0 * 0.70710678118654752f));
            float g1 = 0.5f * y1 * (1.f + erff(y1 * 0.70710678118654752f));
            float o0 = pw_w[(p * 2 + 0) * 128 + c0] * g0
                     + pw_w[(p * 2 + 0) * 128 + c1] * g1;
            float o1 = pw_w[(p * 2 + 1) * 128 + c0] * g0
                     + pw_w[(p * 2 + 1) * 128 + c1] * g1;
#pragma unroll
            for (int o = 1; o < 64; o <<= 1) o0 += __shfl_xor(o0, o);
#pragma unroll
            for (int o = 1; o < 64; o <<= 1) o1 += __shfl_xor(o1, o);
            if (lane == 0) {
                int wk2 = s & 15;
                float refy = (hk + 0.5f) * (2.f / 15.f) - 1.f;
                float refx = (wk2 + 0.5f) * (2.f / 15.f) - 1.f;
                float py = fminf(fmaxf(o0 + refy, -1.f), 1.f);
                float px = fminf(fmaxf(o1 + refx, -1.f), 1.f);
                int pbn = pb * 256 + s;
                posb[pbn * 2 + 0] = py;
                posb[pbn * 2 + 1] = px;
                float cy = 31.5f * (1.f - py), cx = 31.5f * (1.f - px);
                float yf = floorf(cy), xf = floorf(cx);
                float wy = cy - yf, wx = cx - xf;
                int Y0 = (int)yf, X0 = (int)xf;
                uint4 v;
                v.x = (unsigned)f2bf((1.f - wy) * (1.f - wx))
                    | ((unsigned)f2bf((1.f - wy) * wx) << 16);
                v.y = (unsigned)f2bf(wy * (1.f - wx))
                    | ((unsigned)f2bf(wy * wx) << 16);
                v.z = (unsigned)((Y0 * 128 + X0) * 2);
                v.w = 0;
                prmb[pbn] = v;
            }
        }
    } else {
        // transpose part
        float (*ld2)[65] = (float(*)[65])sm;
        int rem = blk - 192;                  // 0..2047
        int v = rem >> 10;
        int rem1 = rem & 1023;
        int b = rem1 >> 8;
        int rem2 = rem1 & 255;
        int ct = rem2 >> 6;
        int mt = rem2 & 63;
        const float* src = ((v == 0) ? x0 : x1) + (long long)b * CC * HW
                           + (long long)(ct * 32) * HW + mt * 64;
#pragma unroll
        for (int it = 0; it < 2; it++) {
            int c = tid >> 3, x4 = (tid & 7) + it * 8;
            float4 w = *(const float4*)(src + (long long)c * HW + x4 * 4);
            ld2[c][x4 * 4 + 0] = w.x;
            ld2[c][x4 * 4 + 1] = w.y;
            ld2[c][x4 * 4 + 2] = w.z;
            ld2[c][x4 * 4 + 3] = w.w;
        }
        __syncthreads();
        int m = tid >> 2, cg = tid & 3;
        union { unsigned u[4]; } pk;
#pragma unroll
        for (int t = 0; t < 4; t++) {
            unsigned short h0 = f2bf(ld2[cg * 8 + 2 * t][m]);
            unsigned short h1 = f2bf(ld2[cg * 8 + 2 * t + 1][m]);
            pk.u[t] = (unsigned)h0 | ((unsigned)h1 << 16);
        }
        *(uint4*)(xT + (((long long)(v * 4 + b)) * HW + mt * 64 + m) * 128
                  + ct * 32 + cg * 8) = *(uint4*)pk.u;
    }
}

// ---------------------------------------------------------------------------
// K4) fused sample + K/V conv (MFMA), clamped-base bilinear (NaN-safe).
__global__ __launch_bounds__(256) void sample_kv(const unsigned short* __restrict__ xT,
                                                 const float* __restrict__ posb,
                                                 const unsigned short* __restrict__ wkh,
                                                 const unsigned short* __restrict__ wvh,
                                                 const float* __restrict__ bk,
                                                 const float* __restrict__ bv,
                                                 unsigned short* __restrict__ kbf,
                                                 unsigned short* __restrict__ vbf) {
    __shared__ unsigned short xls[32 * 128];      // 8 KB, XOR-swizzled rows
    int blk = blockIdx.x;                 // 96
    int pb = blk >> 3;
    int nt = blk & 7;
    int p = pb >> 2, b = pb & 3;
    int n0 = nt * 32;
    int tid = threadIdx.x;

    {
        int nl = tid >> 3, co = tid & 7;
        int n = n0 + nl;
        float py = posb[(pb * 256 + n) * 2 + 0];
        float px = posb[(pb * 256 + n) * 2 + 1];
        float yi = (py + 1.f) * 31.5f, xi = (px + 1.f) * 31.5f;
        yi = fminf(fmaxf(yi, 0.f), 63.f);
        xi = fminf(fmaxf(xi, 0.f), 63.f);
        int y0 = min((int)yi, 62);
        int x0i = min((int)xi, 62);
        float wy = yi - (float)y0, wx = xi - (float)x0i;
        float w00 = (1.f - wy) * (1.f - wx), w01 = (1.f - wy) * wx;
        float w10 = wy * (1.f - wx), w11 = wy * wx;
        int vsel = (p == 2) ? 1 : 0;
        const unsigned short* base = xT + ((long long)(vsel * 4 + b)) * HW * 128;
        int m00 = y0 * 64 + x0i;
        char* dst = (char*)xls;
#pragma unroll
        for (int cb = 0; cb < 2; cb++) {
            int c0 = co * 16 + cb * 8;
            bf16x8 a = *(const bf16x8*)(base + (long long)m00 * 128 + c0);
            bf16x8 bb = *(const bf16x8*)(base + (long long)(m00 + 1) * 128 + c0);
            bf16x8 cc = *(const bf16x8*)(base + (long long)(m00 + 64) * 128 + c0);
            bf16x8 dd = *(const bf16x8*)(base + (long long)(m00 + 65) * 128 + c0);
            union { unsigned u[4]; bf16x8 v; } R;
#pragma unroll
            for (int t = 0; t < 4; t++) {
                float r0 = w00 * bflo((unsigned)(unsigned short)a[2 * t])
                         + w01 * bflo((unsigned)(unsigned short)bb[2 * t])
                         + w10 * bflo((unsigned)(unsigned short)cc[2 * t])
                         + w11 * bflo((unsigned)(unsigned short)dd[2 * t]);
                float r1 = w00 * bflo((unsigned)(unsigned short)a[2 * t + 1])
                         + w01 * bflo((unsigned)(unsigned short)bb[2 * t + 1])
                         + w10 * bflo((unsigned)(unsigned short)cc[2 * t + 1])
                         + w11 * bflo((unsigned)(unsigned short)dd[2 * t + 1]);
                R.u[t] = (unsigned)f2bf(r0) | ((unsigned)f2bf(r1) << 16);
            }
            *(bf16x8*)(dst + ((nl * 256 + c0 * 2) ^ ((nl & 7) << 4))) = R.v;
        }
    }
    __syncthreads();

    int wid = tid >> 6, lane = tid & 63;
    int g = lane >> 4, lm = lane & 15;
    int ntile = wid & 1, isv = wid >> 1;
    int nl = ntile * 16 + lm;
    const char* srcl = (const char*)xls;
    bf16x8 xf[4];
#pragma unroll
    for (int ks = 0; ks < 4; ks++)
        xf[ks] = *(const bf16x8*)(srcl + ((nl * 256 + (ks * 32 + 8 * g) * 2)
                                          ^ ((nl & 7) << 4)));
    f32x4 zero = {0.f, 0.f, 0.f, 0.f};
    if (!isv) {
        const unsigned short* WK = wkh + p * 16384;
#pragma unroll
        for (int ct = 0; ct < 8; ct++) {
            f32x4 acc = zero;
#pragma unroll
            for (int ks = 0; ks < 4; ks++) {
                bf16x8 wf = *(const bf16x8*)(WK + (ct * 16 + lm) * 128 + ks * 32 + 8 * g);
                acc = __builtin_amdgcn_mfma_f32_16x16x32_bf16(xf[ks], wf, acc, 0, 0, 0);
            }
            float bias = bk[p * 128 + ct * 16 + lm];
#pragma unroll
            for (int r = 0; r < 4; r++) {
                int n = n0 + ntile * 16 + 4 * g + r;
                kbf[((long long)pb * 256 + n) * 128 + ct * 16 + lm] = f2bf(acc[r] + bias);
            }
        }
    } else {
        const unsigned short* WV = wvh + p * 16384;
#pragma unroll
        for (int ct = 0; ct < 8; ct++) {
            f32x4 acc = zero;
#pragma unroll
            for (int ks = 0; ks < 4; ks++) {
                bf16x8 wf = *(const bf16x8*)(WV + (ct * 16 + lm) * 128 + ks * 32 + 8 * g);
                acc = __builtin_amdgcn_mfma_f32_16x16x32_bf16(wf, xf[ks], acc, 0, 0, 0);
            }
#pragma unroll
            for (int r = 0; r < 4; r++) {
                int c = ct * 16 + 4 * g + r;
                vbf[((long long)pb * 128 + c) * 256 + n0 + ntile * 16 + lm]
                    = f2bf(acc[r] + bv[p * 128 + c]);
            }
        }
    }
}

// ---------------------------------------------------------------------------
// K5) MFMA attention (R9 structure, 256 thr, LDS table) with 4 query rows per
//     block: table+prm staged ONCE per 4 rows (grid 3072 -> 768), i-loop
//     reuses registers (unroll 1).
__global__ __launch_bounds__(256, 4) void attn_mfma(
        const unsigned short* __restrict__ qbf,
        const unsigned short* __restrict__ kbf,
        const unsigned short* __restrict__ vbf,
        const unsigned short* __restrict__ tabbf,
        const uint4* __restrict__ prmb,
        float* __restrict__ obuf) {
    __shared__ unsigned short tab[16384 + 8];   // +8: speculative dword pad
    __shared__ uint4 prm[256];
    int tid = threadIdx.x;
    int wid = tid >> 6, lane = tid & 63;
    int g = lane >> 4, lm = lane & 15;
    int bid = blockIdx.x;                     // 768
    int myg = bid & 15;
    int h = (bid >> 4) & 3;
    int b = (bid >> 6) & 3;
    int p = bid >> 8;
    int pb = p * 4 + b;

    {   // stage table + params (once per 4 query rows)
        const uint4* ts = (const uint4*)(tabbf + (long long)(p * 4 + h) * 16384);
        uint4* td = (uint4*)tab;
#pragma unroll
        for (int i = 0; i < 8; i++) td[tid + i * 256] = ts[tid + i * 256];
        prm[tid] = prmb[pb * 256 + tid];
    }
    __syncthreads();

    int mx = (wid << 4) + lm;
    const unsigned short* kbase = kbf + ((long long)pb * 256 + lm) * 128
                                  + h * 32 + 8 * g;
    const unsigned short* vb0 = vbf + ((long long)pb * 128 + h * 32 + lm) * 256
                                + 8 * g;
    const char* tb = (const char*)tab;
    f32x4 zero = {0.f, 0.f, 0.f, 0.f};
    int src0 = ((g & 1) << 5) + lm;
    int src1 = src0 + 16;
    bool sel = (g >> 1) != 0;

#pragma unroll 1
    for (int i = 0; i < 4; i++) {
        int my = myg * 4 + i;

        // ---- QK^T (swapped): A = K[n][c], B = Q^T[c][m]; q pre-scaled ----
        bf16x8 qf = *(const bf16x8*)(qbf + ((long long)pb * HW + my * 64 + mx) * 128
                                     + h * 32 + 8 * g);
        f32x4 acc[16];
        __builtin_amdgcn_s_setprio(1);
#pragma unroll
        for (int ni = 0; ni < 16; ni++) {
            bf16x8 kf = *(const bf16x8*)(kbase + ni * 16 * 128);
            acc[ni] = __builtin_amdgcn_mfma_f32_16x16x32_bf16(kf, qf, zero, 0, 0, 0);
        }
        __builtin_amdgcn_s_setprio(0);

        // ---- RPE bias: aligned b32 pair reads + alignbyte + dot2 ----
        int laneoff = (my * 128 + mx) * 2;
#pragma unroll
        for (int ni = 0; ni < 16; ni++) {
#pragma unroll
            for (int r = 0; r < 4; r++) {
                int n = ni * 16 + 4 * g + r;
                uint4 pw = prm[n];
                int va = (int)pw.z + laneoff;
                int va4 = va & ~3;
                int sh = va & 3;
                unsigned r0 = *(const unsigned*)(tb + va4);
                unsigned r1 = *(const unsigned*)(tb + va4 + 4);
                unsigned r2 = *(const unsigned*)(tb + va4 + 256);
                unsigned r3 = *(const unsigned*)(tb + va4 + 260);
                unsigned p0 = __builtin_amdgcn_alignbyte(r1, r0, sh);
                unsigned p1 = __builtin_amdgcn_alignbyte(r3, r2, sh);
                float t = acc[ni][r];
                t = dot2bf(p0, pw.x, t);
                t = dot2bf(p1, pw.y, t);
                acc[ni][r] = t;
            }
        }

        // ---- softmax over n ----
        float mxv = -1e30f;
#pragma unroll
        for (int ni = 0; ni < 16; ni++)
            mxv = fmaxf(mxv, fmaxf(fmaxf(acc[ni][0], acc[ni][1]),
                                   fmaxf(acc[ni][2], acc[ni][3])));
        mxv = fmaxf(mxv, __shfl_xor(mxv, 16));
        mxv = fmaxf(mxv, __shfl_xor(mxv, 32));
        float sum = 0.f;
        unsigned dwA[16], dwB[16];
#pragma unroll
        for (int ni = 0; ni < 16; ni++) {
            float e0 = __expf(acc[ni][0] - mxv);
            float e1 = __expf(acc[ni][1] - mxv);
            float e2 = __expf(acc[ni][2] - mxv);
            float e3 = __expf(acc[ni][3] - mxv);
            sum += (e0 + e1) + (e2 + e3);
            asm("v_cvt_pk_bf16_f32 %0, %1, %2" : "=v"(dwA[ni]) : "v"(e0), "v"(e1));
            asm("v_cvt_pk_bf16_f32 %0, %1, %2" : "=v"(dwB[ni]) : "v"(e2), "v"(e3));
        }
        sum += __shfl_xor(sum, 16);
        sum += __shfl_xor(sum, 32);

        // ---- PV: pf assembled via shfl exchange ----
        f32x4 o0 = zero, o1 = zero;
#pragma unroll
        for (int st = 0; st < 8; st++) {
            unsigned d0a = __shfl(dwA[2 * st], src0), d0b = __shfl(dwA[2 * st + 1], src0);
            unsigned d1a = __shfl(dwB[2 * st], src0), d1b = __shfl(dwB[2 * st + 1], src0);
            unsigned d2a = __shfl(dwA[2 * st], src1), d2b = __shfl(dwA[2 * st + 1], src1);
            unsigned d3a = __shfl(dwB[2 * st], src1), d3b = __shfl(dwB[2 * st + 1], src1);
            union { unsigned u[4]; bf16x8 v; } pf;
            pf.u[0] = sel ? d0b : d0a;
            pf.u[1] = sel ? d1b : d1a;
            pf.u[2] = sel ? d2b : d2a;
            pf.u[3] = sel ? d3b : d3a;
            bf16x8 v0 = *(const bf16x8*)(vb0 + st * 32);
            bf16x8 v1 = *(const bf16x8*)(vb0 + 4096 + st * 32);
            __builtin_amdgcn_s_setprio(1);
            o0 = __builtin_amdgcn_mfma_f32_16x16x32_bf16(v0, pf.v, o0, 0, 0, 0);
            o1 = __builtin_amdgcn_mfma_f32_16x16x32_bf16(v1, pf.v, o1, 0, 0, 0);
            __builtin_amdgcn_s_setprio(0);
        }

        float inv = 1.f / sum;
        float* ob = obuf + ((long long)pb * 128 + h * 32) * HW + my * 64 + mx;
#pragma unroll
        for (int r = 0; r < 4; r++) {
            ob[(g * 4 + r) * HW] = o0[r] * inv;
            ob[(16 + g * 4 + r) * HW] = o1[r] * inv;
        }
    }
}

// ---------------------------------------------------------------------------
// K6) conv_wo via MFMA (bf16): out = x + sum_p Wo[p] o[p] + bo on chans
//     128:256 of vars 1,2.
__global__ __launch_bounds__(256) void conv_wo(const float* __restrict__ x1,
                                               const float* __restrict__ x2,
                                               const float* __restrict__ obuf,
                                               const unsigned short* __restrict__ woh,
                                               const float* __restrict__ bo,
                                               float* __restrict__ out) {
    int wid = threadIdx.x >> 6, lane = threadIdx.x & 63;
    int g = lane >> 4, lm = lane & 15;
    int gw = blockIdx.x * 4 + wid;            // 2048 waves
    int mt = gw & 255;
    int b = (gw >> 8) & 3;
    int vs = gw >> 10;
    int m = mt * 16 + lm;
    int np = vs + 1;

    f32x4 acc[8];
#pragma unroll
    for (int ct = 0; ct < 8; ct++) acc[ct] = (f32x4){0.f, 0.f, 0.f, 0.f};

    for (int pi = 0; pi < np; pi++) {
        int p = vs ? (1 + pi) : 0;
        const float* O = obuf + (long long)(p * 4 + b) * 128 * HW;
        bf16x8 bh[4];
#pragma unroll
        for (int ksl = 0; ksl < 4; ksl++) {
            float v[8];
#pragma unroll
            for (int j = 0; j < 8; j++)
                v[j] = O[(long long)(ksl * 32 + 8 * g + j) * HW + m];
            union { unsigned u[4]; bf16x8 v; } H;
#pragma unroll
            for (int t = 0; t < 4; t++)
                H.u[t] = (unsigned)f2bf(v[2 * t]) | ((unsigned)f2bf(v[2 * t + 1]) << 16);
            bh[ksl] = H.v;
        }
        const unsigned short* WH = woh + p * 16384;
#pragma unroll
        for (int ct = 0; ct < 8; ct++)
#pragma unroll
            for (int ksl = 0; ksl < 4; ksl++) {
                bf16x8 A = *(const bf16x8*)(WH + (ct * 16 + lm) * 128 + ksl * 32 + 8 * g);
                acc[ct] = __builtin_amdgcn_mfma_f32_16x16x32_bf16(A, bh[ksl], acc[ct], 0, 0, 0);
            }
    }

    int qi = vs + 1;
    const float* xq = (vs ? x2 : x1) + (long long)b * CC * HW;
#pragma unroll
    for (int ct = 0; ct < 8; ct++)
#pragma unroll
        for (int r = 0; r < 4; r++) {
            int c = ct * 16 + 4 * g + r;
            float bias = vs ? (bo[128 + c] + bo[256 + c]) : bo[c];
            float base = xq[(long long)(128 + c) * HW + m];
            out[(((long long)(qi * 4 + b)) * CC + 128 + c) * HW + m]
                = base + acc[ct][r] + bias;
        }
}

// ---------------------------------------------------------------------------
extern "C" void kernel_launch(void* const* d_in, const int* in_sizes, int n_in,
                              void* d_out, int out_size, void* d_ws, size_t ws_size,
                              hipStream_t stream) {
    const float* x0 = (const float*)d_in[0];
    const float* x1 = (const float*)d_in[1];
    const float* x2 = (const float*)d_in[2];
    const float* Wq = (const float*)d_in[3];
    const float* bq = (const float*)d_in[4];
    const float* Wk = (const float*)d_in[5];
    const float* bk = (const float*)d_in[6];
    const float* Wv = (const float*)d_in[7];
    const float* bv = (const float*)d_in[8];
    const float* Wo = (const float*)d_in[9];
    const float* bo = (const float*)d_in[10];
    const float* dw_w = (const float*)d_in[11];
    const float* dw_b = (const float*)d_in[12];
    const float* ln_g = (const float*)d_in[13];
    const float* ln_b = (const float*)d_in[14];
    const float* pw_w = (const float*)d_in[15];
    const float* rpe = (const float*)d_in[16];
    float* out = (float*)d_out;

    // Region A: qbuf f32 (K2 w, K3 r) -> obuf f32 (K5 w, K6 r), disjoint.
    float* ws = (float*)d_ws;
    float* qbuf = ws;                                   // 6291456 f (24 MB)
    float* obuf = qbuf;                                 // alias (disjoint lifetime)
    float* posb = ws + 6291456;                         // 6144 f
    unsigned short* xT = (unsigned short*)(posb + 6144);     // 4194304 s (8 MB)
    unsigned short* qbf = xT + 4194304;                      // 12582912 s (24 MB)
    unsigned short* kbf = qbf + 12582912;                    // 393216 s
    unsigned short* vbf = kbf + 393216;                      // 393216 s
    unsigned short* tabbf = vbf + 393216;                    // 196608 s
    uint4* prmb = (uint4*)(tabbf + 196608);                  // 3072 uint4
    unsigned short* wqh = (unsigned short*)(prmb + 3072);    // 49152 s
    unsigned short* wql = wqh + 49152;
    unsigned short* woh = wql + 49152;
    unsigned short* wkh = woh + 49152;
    unsigned short* wvh = wkh + 49152;
    // total ~ 59 MB

    prep_copy<<<1048, 256, 0, stream>>>(rpe, Wq, Wo, Wk, Wv, x0, tabbf,
                                        wqh, wql, woh, wkh, wvh, out);
    conv_q<<<768, 256, 0, stream>>>(x1, x2, wqh, wql, bq, qbuf, qbf, out);
    mid_kernel<<<2240, 256, 0, stream>>>(qbuf, dw_w, dw_b, ln_g, ln_b, pw_w,
                                         x0, x1, posb, prmb, xT);
    sample_kv<<<96, 256, 0, stream>>>(xT, posb, wkh, wvh, bk, bv, kbf, vbf);
    attn_mfma<<<768, 256, 0, stream>>>(qbf, kbf, vbf, tabbf, prmb, obuf);
    conv_wo<<<512, 256, 0, stream>>>(x1, x2, obuf, woh, bo, out);
}

// Round 14
// 180.614 us; speedup vs baseline: 2.7960x; 2.7960x over previous
//
#include <hip/hip_runtime.h>
#include <math.h>

// Problem constants
#define NVAR 3
#define BB 4
#define CC 256
#define C1 128
#define HEADS 4
#define HH 64
#define WW 64
#define HW 4096
#define RPE_W 127
#define NP 3
#define SCALE 0.17677669529663687f
// pairs: p=0 -> (i=1,j=0), p=1 -> (i=2,j=0), p=2 -> (i=2,j=1)

typedef short bf16x8 __attribute__((ext_vector_type(8)));
typedef float f32x4 __attribute__((ext_vector_type(4)));
typedef __bf16 bf16x2 __attribute__((ext_vector_type(2)));

__device__ __forceinline__ unsigned short f2bf(float f) {
    unsigned int u = __float_as_uint(f);
    u += 0x7fffu + ((u >> 16) & 1u);          // round-to-nearest-even
    return (unsigned short)(u >> 16);
}
__device__ __forceinline__ float bflo(unsigned u) { return __uint_as_float(u << 16); }
__device__ __forceinline__ float bfhi(unsigned u) { return __uint_as_float(u & 0xffff0000u); }

// packed bf16x2 dot: c + a.lo*b.lo + a.hi*b.hi
__device__ __forceinline__ float dot2bf(unsigned a, unsigned b, float c) {
#if __has_builtin(__builtin_amdgcn_fdot2_f32_bf16)
    return __builtin_amdgcn_fdot2_f32_bf16(__builtin_bit_cast(bf16x2, a),
                                           __builtin_bit_cast(bf16x2, b), c, false);
#else
    return c + bflo(a) * bflo(b) + bfhi(a) * bfhi(b);
#endif
}

// ---------------------------------------------------------------------------
// K1) const prep (blocks 0..23) + copy x0 -> out var0 + flow zeros (24..1047)
__global__ __launch_bounds__(256) void prep_copy(const float* __restrict__ rpe,
                                                 const float* __restrict__ Wq,
                                                 const float* __restrict__ Wo,
                                                 const float* __restrict__ Wk,
                                                 const float* __restrict__ Wv,
                                                 const float* __restrict__ x0,
                                                 unsigned short* __restrict__ tabbf,
                                                 unsigned short* __restrict__ wqh,
                                                 unsigned short* __restrict__ wql,
                                                 unsigned short* __restrict__ woh,
                                                 unsigned short* __restrict__ wkh,
                                                 unsigned short* __restrict__ wvh,
                                                 float* __restrict__ out) {
    int blk = blockIdx.x;
    if (blk >= 24) {
        const long long n4 = (long long)BB * CC * HW / 4;
        long long i = (long long)(blk - 24) * 256 + threadIdx.x;
        const long long stride = 1024LL * 256;
        for (; i < n4 + 12; i += stride) {
            if (i < n4) ((float4*)out)[i] = ((const float4*)x0)[i];
            else out[3LL * BB * CC * HW + (i - n4)] = 0.f;
        }
        return;
    }
    if (blk < 12) {
        const float* src = rpe + (long long)blk * RPE_W * RPE_W;
        unsigned short* dst = tabbf + (long long)blk * 16384;
        for (int idx = threadIdx.x; idx < 16384; idx += 256) {
            int y = idx >> 7, x = idx & 127;
            float v = (y < RPE_W && x < RPE_W) ? src[y * RPE_W + x] : 0.f;
            dst[idx] = f2bf(v);
        }
    } else if (blk < 15) {
        int p = blk - 12;
        for (int i = threadIdx.x; i < 16384; i += 256) {
            float w = Wq[p * 16384 + i];
            unsigned short h = f2bf(w);
            wqh[p * 16384 + i] = h;
            wql[p * 16384 + i] = f2bf(w - bflo((unsigned)h));
        }
    } else if (blk < 18) {
        int p = blk - 15;
        for (int i = threadIdx.x; i < 16384; i += 256)
            woh[p * 16384 + i] = f2bf(Wo[p * 16384 + i]);
    } else if (blk < 21) {
        int p = blk - 18;
        for (int i = threadIdx.x; i < 16384; i += 256)
            wkh[p * 16384 + i] = f2bf(Wk[p * 16384 + i]);
    } else {
        int p = blk - 21;
        for (int i = threadIdx.x; i < 16384; i += 256)
            wvh[p * 16384 + i] = f2bf(Wv[p * 16384 + i]);
    }
}

// ---------------------------------------------------------------------------
// K2) conv_q via MFMA, split bf16 (hi+lo). Outputs qbuf f32 [pb][c][m],
//     qbf bf16 [pb][m][c] (pre-scaled, coalesced via LDS bounce), AND copies
//     x chans 0:128 into out.
__global__ __launch_bounds__(256) void conv_q(const float* __restrict__ x1,
                                              const float* __restrict__ x2,
                                              const unsigned short* __restrict__ wqh,
                                              const unsigned short* __restrict__ wql,
                                              const float* __restrict__ bq,
                                              float* __restrict__ qbuf,
                                              unsigned short* __restrict__ qbf,
                                              float* __restrict__ out) {
    __shared__ unsigned short qlds[4][16][136];   // 17 KB; 16B-aligned rows
    int wid = threadIdx.x >> 6, lane = threadIdx.x & 63;
    int g = lane >> 4, lm = lane & 15;
    int gw = blockIdx.x * 4 + wid;            // 3072 waves
    int mt = gw & 255;
    int pb = gw >> 8;
    int p = pb >> 2, b = pb & 3;
    const float* X = ((p == 0) ? x1 : x2) + (long long)b * CC * HW;
    int m = mt * 16 + lm;
    float* outc = (p < 2)
        ? out + (((long long)((p + 1) * 4 + b)) * CC) * HW + m
        : nullptr;

    bf16x8 bhi[4], blo[4];
#pragma unroll
    for (int ksl = 0; ksl < 4; ksl++) {
        float v[8];
#pragma unroll
        for (int j = 0; j < 8; j++) {
            int k = ksl * 32 + 8 * g + j;
            v[j] = X[(long long)k * HW + m];
            if (outc) outc[(long long)k * HW] = v[j];
        }
        union { unsigned u[4]; bf16x8 v; } H, L;
#pragma unroll
        for (int t = 0; t < 4; t++) {
            unsigned short h0 = f2bf(v[2 * t]), h1 = f2bf(v[2 * t + 1]);
            unsigned short l0 = f2bf(v[2 * t] - bflo((unsigned)h0));
            unsigned short l1 = f2bf(v[2 * t + 1] - bflo((unsigned)h1));
            H.u[t] = (unsigned)h0 | ((unsigned)h1 << 16);
            L.u[t] = (unsigned)l0 | ((unsigned)l1 << 16);
        }
        bhi[ksl] = H.v;
        blo[ksl] = L.v;
    }

    const unsigned short* WH = wqh + p * 16384;
    const unsigned short* WL = wql + p * 16384;
    unsigned short* ql = &qlds[wid][lm][0];
    f32x4 zero = {0.f, 0.f, 0.f, 0.f};
#pragma unroll
    for (int ct2 = 0; ct2 < 4; ct2++) {
        int ct0 = 2 * ct2, ct1 = ct0 + 1;
        f32x4 a0 = zero, a1 = zero;
#pragma unroll
        for (int ksl = 0; ksl < 4; ksl++) {
            bf16x8 Ah0 = *(const bf16x8*)(WH + (ct0 * 16 + lm) * 128 + ksl * 32 + 8 * g);
            bf16x8 Al0 = *(const bf16x8*)(WL + (ct0 * 16 + lm) * 128 + ksl * 32 + 8 * g);
            bf16x8 Ah1 = *(const bf16x8*)(WH + (ct1 * 16 + lm) * 128 + ksl * 32 + 8 * g);
            bf16x8 Al1 = *(const bf16x8*)(WL + (ct1 * 16 + lm) * 128 + ksl * 32 + 8 * g);
            a0 = __builtin_amdgcn_mfma_f32_16x16x32_bf16(Ah0, bhi[ksl], a0, 0, 0, 0);
            a1 = __builtin_amdgcn_mfma_f32_16x16x32_bf16(Ah1, bhi[ksl], a1, 0, 0, 0);
            a0 = __builtin_amdgcn_mfma_f32_16x16x32_bf16(Ah0, blo[ksl], a0, 0, 0, 0);
            a1 = __builtin_amdgcn_mfma_f32_16x16x32_bf16(Ah1, blo[ksl], a1, 0, 0, 0);
            a0 = __builtin_amdgcn_mfma_f32_16x16x32_bf16(Al0, bhi[ksl], a0, 0, 0, 0);
            a1 = __builtin_amdgcn_mfma_f32_16x16x32_bf16(Al1, bhi[ksl], a1, 0, 0, 0);
        }
        float q0[4], q1[4];
#pragma unroll
        for (int r = 0; r < 4; r++) {
            int c0 = ct0 * 16 + 4 * g + r, c1 = ct1 * 16 + 4 * g + r;
            q0[r] = a0[r] + bq[p * 128 + c0];
            q1[r] = a1[r] + bq[p * 128 + c1];
            qbuf[((long long)pb * 128 + c0) * HW + m] = q0[r];
            qbuf[((long long)pb * 128 + c1) * HW + m] = q1[r];
        }
        *(unsigned*)(ql + ct0 * 16 + 4 * g) =
            (unsigned)f2bf(q0[0] * SCALE) | ((unsigned)f2bf(q0[1] * SCALE) << 16);
        *(unsigned*)(ql + ct0 * 16 + 4 * g + 2) =
            (unsigned)f2bf(q0[2] * SCALE) | ((unsigned)f2bf(q0[3] * SCALE) << 16);
        *(unsigned*)(ql + ct1 * 16 + 4 * g) =
            (unsigned)f2bf(q1[0] * SCALE) | ((unsigned)f2bf(q1[1] * SCALE) << 16);
        *(unsigned*)(ql + ct1 * 16 + 4 * g + 2) =
            (unsigned)f2bf(q1[2] * SCALE) | ((unsigned)f2bf(q1[3] * SCALE) << 16);
    }

    // same-wave LDS readback -> coalesced 1KB-contiguous global stores
    unsigned short* Yb = qbf + ((long long)pb * HW + mt * 16) * 128;
    int q = lane >> 4, cg = lane & 15;
#pragma unroll
    for (int i = 0; i < 4; i++) {
        int row = i * 4 + q;
        uint4 vv = *(const uint4*)&qlds[wid][row][cg * 8];
        *(uint4*)(Yb + row * 128 + cg * 8) = vv;
    }
}

// ---------------------------------------------------------------------------
// K3) fused middle kernel:
//   blocks 0..191:  offset net (depthwise conv staged in LDS -> LN -> GELU ->
//                   1x1 -> pos + prm), per (pb,hk); 'off' never leaves LDS.
//   blocks 192..2239: transpose x0,x1 chans 0:128 -> xT bf16 [v][b][m][c].
__global__ __launch_bounds__(256) void mid_kernel(const float* __restrict__ qbuf,
                                                  const float* __restrict__ dw_w,
                                                  const float* __restrict__ dw_b,
                                                  const float* __restrict__ ln_g,
                                                  const float* __restrict__ ln_b,
                                                  const float* __restrict__ pw_w,
                                                  const float* __restrict__ x0,
                                                  const float* __restrict__ x1,
                                                  float* __restrict__ posb,
                                                  uint4* __restrict__ prmb,
                                                  unsigned short* __restrict__ xT) {
    __shared__ float sm[32 * 4 * 65 + 16 * 128];     // 41.5 KB
    int blk = blockIdx.x;
    int tid = threadIdx.x;
    if (blk < 192) {
        float (*ld)[4][65] = (float(*)[4][65])sm;
        float (*dwout)[128] = (float(*)[128])(sm + 32 * 4 * 65);
        int pb = blk >> 4, hk = blk & 15;
        int p = pb >> 2;
        for (int cq = 0; cq < 4; cq++) {
            int c32 = cq * 32;
            __syncthreads();
#pragma unroll
            for (int it = 0; it < 8; it++) {
                int i2 = tid + it * 256;          // 2048 float4
                int c = i2 >> 6, rem = i2 & 63;
                int y = rem >> 4, xq = rem & 15;
                float4 v = *(const float4*)(qbuf + ((long long)pb * 128 + c32 + c) * HW
                                            + (4 * hk + y) * 64 + xq * 4);
                ld[c][y][xq * 4 + 0] = v.x;
                ld[c][y][xq * 4 + 1] = v.y;
                ld[c][y][xq * 4 + 2] = v.z;
                ld[c][y][xq * 4 + 3] = v.w;
            }
            __syncthreads();
            int wk = tid >> 4;
#pragma unroll
            for (int oi = 0; oi < 2; oi++) {
                int c = (tid & 15) + oi * 16;
                const float* dwp = dw_w + (p * 128 + c32 + c) * 16;
                float acc = dw_b[p * 128 + c32 + c];
#pragma unroll
                for (int ky = 0; ky < 4; ky++)
#pragma unroll
                    for (int kx = 0; kx < 4; kx++)
                        acc += ld[c][ky][wk * 4 + kx] * dwp[ky * 4 + kx];
                dwout[wk][c32 + c] = acc;
            }
        }
        __syncthreads();
        // LN phase: 4 waves x 4 wk each
        int wid = tid >> 6, lane = tid & 63;
        for (int i = 0; i < 4; i++) {
            int wk = wid * 4 + i;
            int s = hk * 16 + wk;
            float a0 = dwout[wk][lane], a1 = dwout[wk][lane + 64];
            float s1 = a0 + a1;
#pragma unroll
            for (int o = 1; o < 64; o <<= 1) s1 += __shfl_xor(s1, o);
            float mu = s1 * (1.f / 128.f);
            float d0 = a0 - mu, d1 = a1 - mu;
            float v2 = d0 * d0 + d1 * d1;
#pragma unroll
            for (int o = 1; o < 64; o <<= 1) v2 += __shfl_xor(v2, o);
            float rs = rsqrtf(v2 * (1.f / 128.f) + 1e-5f);
            int c0 = lane, c1 = lane + 64;
            float y0 = d0 * rs * ln_g[p * 128 + c0] + ln_b[p * 128 + c0];
            float y1 = d1 * rs * ln_g[p * 128 + c1] + ln_b[p * 128 + c1];
            float g0 = 0.5f * y0 * (1.f + erff(y0 * 0.70710678118654752f));
            float g1 = 0.5f * y1 * (1.f + erff(y1 * 0.70710678118654752f));
            float o0 = pw_w[(p * 2 + 0) * 128 + c0] * g0
                     + pw_w[(p * 2 + 0) * 128 + c1] * g1;
            float o1 = pw_w[(p * 2 + 1) * 128 + c0] * g0
                     + pw_w[(p * 2 + 1) * 128 + c1] * g1;
#pragma unroll
            for (int o = 1; o < 64; o <<= 1) o0 += __shfl_xor(o0, o);
#pragma unroll
            for (int o = 1; o < 64; o <<= 1) o1 += __shfl_xor(o1, o);
            if (lane == 0) {
                int wk2 = s & 15;
                float refy = (hk + 0.5f) * (2.f / 15.f) - 1.f;
                float refx = (wk2 + 0.5f) * (2.f / 15.f) - 1.f;
                float py = fminf(fmaxf(o0 + refy, -1.f), 1.f);
                float px = fminf(fmaxf(o1 + refx, -1.f), 1.f);
                int pbn = pb * 256 + s;
                posb[pbn * 2 + 0] = py;
                posb[pbn * 2 + 1] = px;
                float cy = 31.5f * (1.f - py), cx = 31.5f * (1.f - px);
                float yf = floorf(cy), xf = floorf(cx);
                float wy = cy - yf, wx = cx - xf;
                int Y0 = (int)yf, X0 = (int)xf;
                uint4 v;
                v.x = (unsigned)f2bf((1.f - wy) * (1.f - wx))
                    | ((unsigned)f2bf((1.f - wy) * wx) << 16);
                v.y = (unsigned)f2bf(wy * (1.f - wx))
                    | ((unsigned)f2bf(wy * wx) << 16);
                v.z = (unsigned)((Y0 * 128 + X0) * 2);
                v.w = 0;
                prmb[pbn] = v;
            }
        }
    } else {
        // transpose part
        float (*ld2)[65] = (float(*)[65])sm;
        int rem = blk - 192;                  // 0..2047
        int v = rem >> 10;
        int rem1 = rem & 1023;
        int b = rem1 >> 8;
        int rem2 = rem1 & 255;
        int ct = rem2 >> 6;
        int mt = rem2 & 63;
        const float* src = ((v == 0) ? x0 : x1) + (long long)b * CC * HW
                           + (long long)(ct * 32) * HW + mt * 64;
#pragma unroll
        for (int it = 0; it < 2; it++) {
            int c = tid >> 3, x4 = (tid & 7) + it * 8;
            float4 w = *(const float4*)(src + (long long)c * HW + x4 * 4);
            ld2[c][x4 * 4 + 0] = w.x;
            ld2[c][x4 * 4 + 1] = w.y;
            ld2[c][x4 * 4 + 2] = w.z;
            ld2[c][x4 * 4 + 3] = w.w;
        }
        __syncthreads();
        int m = tid >> 2, cg = tid & 3;
        union { unsigned u[4]; } pk;
#pragma unroll
        for (int t = 0; t < 4; t++) {
            unsigned short h0 = f2bf(ld2[cg * 8 + 2 * t][m]);
            unsigned short h1 = f2bf(ld2[cg * 8 + 2 * t + 1][m]);
            pk.u[t] = (unsigned)h0 | ((unsigned)h1 << 16);
        }
        *(uint4*)(xT + (((long long)(v * 4 + b)) * HW + mt * 64 + m) * 128
                  + ct * 32 + cg * 8) = *(uint4*)pk.u;
    }
}

// ---------------------------------------------------------------------------
// K4) fused sample + K/V conv (MFMA), clamped-base bilinear (NaN-safe).
__global__ __launch_bounds__(256) void sample_kv(const unsigned short* __restrict__ xT,
                                                 const float* __restrict__ posb,
                                                 const unsigned short* __restrict__ wkh,
                                                 const unsigned short* __restrict__ wvh,
                                                 const float* __restrict__ bk,
                                                 const float* __restrict__ bv,
                                                 unsigned short* __restrict__ kbf,
                                                 unsigned short* __restrict__ vbf) {
    __shared__ unsigned short xls[32 * 128];      // 8 KB, XOR-swizzled rows
    int blk = blockIdx.x;                 // 96
    int pb = blk >> 3;
    int nt = blk & 7;
    int p = pb >> 2, b = pb & 3;
    int n0 = nt * 32;
    int tid = threadIdx.x;

    {
        int nl = tid >> 3, co = tid & 7;
        int n = n0 + nl;
        float py = posb[(pb * 256 + n) * 2 + 0];
        float px = posb[(pb * 256 + n) * 2 + 1];
        float yi = (py + 1.f) * 31.5f, xi = (px + 1.f) * 31.5f;
        yi = fminf(fmaxf(yi, 0.f), 63.f);
        xi = fminf(fmaxf(xi, 0.f), 63.f);
        int y0 = min((int)yi, 62);
        int x0i = min((int)xi, 62);
        float wy = yi - (float)y0, wx = xi - (float)x0i;
        float w00 = (1.f - wy) * (1.f - wx), w01 = (1.f - wy) * wx;
        float w10 = wy * (1.f - wx), w11 = wy * wx;
        int vsel = (p == 2) ? 1 : 0;
        const unsigned short* base = xT + ((long long)(vsel * 4 + b)) * HW * 128;
        int m00 = y0 * 64 + x0i;
        char* dst = (char*)xls;
#pragma unroll
        for (int cb = 0; cb < 2; cb++) {
            int c0 = co * 16 + cb * 8;
            bf16x8 a = *(const bf16x8*)(base + (long long)m00 * 128 + c0);
            bf16x8 bb = *(const bf16x8*)(base + (long long)(m00 + 1) * 128 + c0);
            bf16x8 cc = *(const bf16x8*)(base + (long long)(m00 + 64) * 128 + c0);
            bf16x8 dd = *(const bf16x8*)(base + (long long)(m00 + 65) * 128 + c0);
            union { unsigned u[4]; bf16x8 v; } R;
#pragma unroll
            for (int t = 0; t < 4; t++) {
                float r0 = w00 * bflo((unsigned)(unsigned short)a[2 * t])
                         + w01 * bflo((unsigned)(unsigned short)bb[2 * t])
                         + w10 * bflo((unsigned)(unsigned short)cc[2 * t])
                         + w11 * bflo((unsigned)(unsigned short)dd[2 * t]);
                float r1 = w00 * bflo((unsigned)(unsigned short)a[2 * t + 1])
                         + w01 * bflo((unsigned)(unsigned short)bb[2 * t + 1])
                         + w10 * bflo((unsigned)(unsigned short)cc[2 * t + 1])
                         + w11 * bflo((unsigned)(unsigned short)dd[2 * t + 1]);
                R.u[t] = (unsigned)f2bf(r0) | ((unsigned)f2bf(r1) << 16);
            }
            *(bf16x8*)(dst + ((nl * 256 + c0 * 2) ^ ((nl & 7) << 4))) = R.v;
        }
    }
    __syncthreads();

    int wid = tid >> 6, lane = tid & 63;
    int g = lane >> 4, lm = lane & 15;
    int ntile = wid & 1, isv = wid >> 1;
    int nl = ntile * 16 + lm;
    const char* srcl = (const char*)xls;
    bf16x8 xf[4];
#pragma unroll
    for (int ks = 0; ks < 4; ks++)
        xf[ks] = *(const bf16x8*)(srcl + ((nl * 256 + (ks * 32 + 8 * g) * 2)
                                          ^ ((nl & 7) << 4)));
    f32x4 zero = {0.f, 0.f, 0.f, 0.f};
    if (!isv) {
        const unsigned short* WK = wkh + p * 16384;
#pragma unroll
        for (int ct = 0; ct < 8; ct++) {
            f32x4 acc = zero;
#pragma unroll
            for (int ks = 0; ks < 4; ks++) {
                bf16x8 wf = *(const bf16x8*)(WK + (ct * 16 + lm) * 128 + ks * 32 + 8 * g);
                acc = __builtin_amdgcn_mfma_f32_16x16x32_bf16(xf[ks], wf, acc, 0, 0, 0);
            }
            float bias = bk[p * 128 + ct * 16 + lm];
#pragma unroll
            for (int r = 0; r < 4; r++) {
                int n = n0 + ntile * 16 + 4 * g + r;
                kbf[((long long)pb * 256 + n) * 128 + ct * 16 + lm] = f2bf(acc[r] + bias);
            }
        }
    } else {
        const unsigned short* WV = wvh + p * 16384;
#pragma unroll
        for (int ct = 0; ct < 8; ct++) {
            f32x4 acc = zero;
#pragma unroll
            for (int ks = 0; ks < 4; ks++) {
                bf16x8 wf = *(const bf16x8*)(WV + (ct * 16 + lm) * 128 + ks * 32 + 8 * g);
                acc = __builtin_amdgcn_mfma_f32_16x16x32_bf16(wf, xf[ks], acc, 0, 0, 0);
            }
#pragma unroll
            for (int r = 0; r < 4; r++) {
                int c = ct * 16 + 4 * g + r;
                vbf[((long long)pb * 128 + c) * 256 + n0 + ntile * 16 + lm]
                    = f2bf(acc[r] + bv[p * 128 + c]);
            }
        }
    }
}

// ---------------------------------------------------------------------------
// K5) MFMA attention (R9 known-best: 256 thr, LDS table, alignbyte+dot2 bias,
//     grid 3072, VGPR 52, no spill).
__global__ __launch_bounds__(256, 4) void attn_mfma(
        const unsigned short* __restrict__ qbf,
        const unsigned short* __restrict__ kbf,
        const unsigned short* __restrict__ vbf,
        const unsigned short* __restrict__ tabbf,
        const uint4* __restrict__ prmb,
        float* __restrict__ obuf) {
    __shared__ unsigned short tab[16384 + 8];   // +8: speculative dword pad
    __shared__ uint4 prm[256];
    int tid = threadIdx.x;
    int wid = tid >> 6, lane = tid & 63;
    int g = lane >> 4, lm = lane & 15;
    int bid = blockIdx.x;                     // 3072
    int my = bid & 63;
    int h = (bid >> 6) & 3;
    int b = (bid >> 8) & 3;
    int p = bid >> 10;
    int pb = p * 4 + b;

    {   // stage table + params
        const uint4* ts = (const uint4*)(tabbf + (long long)(p * 4 + h) * 16384);
        uint4* td = (uint4*)tab;
#pragma unroll
        for (int i = 0; i < 8; i++) td[tid + i * 256] = ts[tid + i * 256];
        prm[tid] = prmb[pb * 256 + tid];
    }
    __syncthreads();

    int mx = (wid << 4) + lm;

    // ---- QK^T (swapped): A = K[n][c], B = Q^T[c][m]; q pre-scaled ----
    bf16x8 qf = *(const bf16x8*)(qbf + ((long long)pb * HW + my * 64 + mx) * 128
                                 + h * 32 + 8 * g);
    const unsigned short* kbase = kbf + ((long long)pb * 256 + lm) * 128
                                  + h * 32 + 8 * g;
    f32x4 zero = {0.f, 0.f, 0.f, 0.f};
    f32x4 acc[16];
    __builtin_amdgcn_s_setprio(1);
#pragma unroll
    for (int ni = 0; ni < 16; ni++) {
        bf16x8 kf = *(const bf16x8*)(kbase + ni * 16 * 128);
        acc[ni] = __builtin_amdgcn_mfma_f32_16x16x32_bf16(kf, qf, zero, 0, 0, 0);
    }
    __builtin_amdgcn_s_setprio(0);

    // ---- RPE bias: aligned b32 pair reads + alignbyte + dot2 ----
    int laneoff = (my * 128 + mx) * 2;
    const char* tb = (const char*)tab;
#pragma unroll
    for (int ni = 0; ni < 16; ni++) {
#pragma unroll
        for (int r = 0; r < 4; r++) {
            int n = ni * 16 + 4 * g + r;
            uint4 pw = prm[n];
            int va = (int)pw.z + laneoff;
            int va4 = va & ~3;
            int sh = va & 3;
            unsigned r0 = *(const unsigned*)(tb + va4);
            unsigned r1 = *(const unsigned*)(tb + va4 + 4);
            unsigned r2 = *(const unsigned*)(tb + va4 + 256);
            unsigned r3 = *(const unsigned*)(tb + va4 + 260);
            unsigned p0 = __builtin_amdgcn_alignbyte(r1, r0, sh);
            unsigned p1 = __builtin_amdgcn_alignbyte(r3, r2, sh);
            float t = acc[ni][r];
            t = dot2bf(p0, pw.x, t);
            t = dot2bf(p1, pw.y, t);
            acc[ni][r] = t;
        }
    }

    // ---- softmax over n ----
    float mxv = -1e30f;
#pragma unroll
    for (int ni = 0; ni < 16; ni++)
        mxv = fmaxf(mxv, fmaxf(fmaxf(acc[ni][0], acc[ni][1]),
                               fmaxf(acc[ni][2], acc[ni][3])));
    mxv = fmaxf(mxv, __shfl_xor(mxv, 16));
    mxv = fmaxf(mxv, __shfl_xor(mxv, 32));
    float sum = 0.f;
    unsigned dwA[16], dwB[16];
#pragma unroll
    for (int ni = 0; ni < 16; ni++) {
        float e0 = __expf(acc[ni][0] - mxv);
        float e1 = __expf(acc[ni][1] - mxv);
        float e2 = __expf(acc[ni][2] - mxv);
        float e3 = __expf(acc[ni][3] - mxv);
        sum += (e0 + e1) + (e2 + e3);
        asm("v_cvt_pk_bf16_f32 %0, %1, %2" : "=v"(dwA[ni]) : "v"(e0), "v"(e1));
        asm("v_cvt_pk_bf16_f32 %0, %1, %2" : "=v"(dwB[ni]) : "v"(e2), "v"(e3));
    }
    sum += __shfl_xor(sum, 16);
    sum += __shfl_xor(sum, 32);

    // ---- PV: pf assembled via shfl exchange ----
    int src0 = ((g & 1) << 5) + lm;
    int src1 = src0 + 16;
    bool sel = (g >> 1) != 0;
    const unsigned short* vb0 = vbf + ((long long)pb * 128 + h * 32 + lm) * 256
                                + 8 * g;
    f32x4 o0 = zero, o1 = zero;
#pragma unroll
    for (int st = 0; st < 8; st++) {
        unsigned d0a = __shfl(dwA[2 * st], src0), d0b = __shfl(dwA[2 * st + 1], src0);
        unsigned d1a = __shfl(dwB[2 * st], src0), d1b = __shfl(dwB[2 * st + 1], src0);
        unsigned d2a = __shfl(dwA[2 * st], src1), d2b = __shfl(dwA[2 * st + 1], src1);
        unsigned d3a = __shfl(dwB[2 * st], src1), d3b = __shfl(dwB[2 * st + 1], src1);
        union { unsigned u[4]; bf16x8 v; } pf;
        pf.u[0] = sel ? d0b : d0a;
        pf.u[1] = sel ? d1b : d1a;
        pf.u[2] = sel ? d2b : d2a;
        pf.u[3] = sel ? d3b : d3a;
        bf16x8 v0 = *(const bf16x8*)(vb0 + st * 32);
        bf16x8 v1 = *(const bf16x8*)(vb0 + 4096 + st * 32);
        __builtin_amdgcn_s_setprio(1);
        o0 = __builtin_amdgcn_mfma_f32_16x16x32_bf16(v0, pf.v, o0, 0, 0, 0);
        o1 = __builtin_amdgcn_mfma_f32_16x16x32_bf16(v1, pf.v, o1, 0, 0, 0);
        __builtin_amdgcn_s_setprio(0);
    }

    float inv = 1.f / sum;
    float* ob = obuf + ((long long)pb * 128 + h * 32) * HW + my * 64 + mx;
#pragma unroll
    for (int r = 0; r < 4; r++) {
        ob[(g * 4 + r) * HW] = o0[r] * inv;
        ob[(16 + g * 4 + r) * HW] = o1[r] * inv;
    }
}

// ---------------------------------------------------------------------------
// K6) conv_wo via MFMA (bf16): out = x + sum_p Wo[p] o[p] + bo on chans
//     128:256 of vars 1,2.
__global__ __launch_bounds__(256) void conv_wo(const float* __restrict__ x1,
                                               const float* __restrict__ x2,
                                               const float* __restrict__ obuf,
                                               const unsigned short* __restrict__ woh,
                                               const float* __restrict__ bo,
                                               float* __restrict__ out) {
    int wid = threadIdx.x >> 6, lane = threadIdx.x & 63;
    int g = lane >> 4, lm = lane & 15;
    int gw = blockIdx.x * 4 + wid;            // 2048 waves
    int mt = gw & 255;
    int b = (gw >> 8) & 3;
    int vs = gw >> 10;
    int m = mt * 16 + lm;
    int np = vs + 1;

    f32x4 acc[8];
#pragma unroll
    for (int ct = 0; ct < 8; ct++) acc[ct] = (f32x4){0.f, 0.f, 0.f, 0.f};

    for (int pi = 0; pi < np; pi++) {
        int p = vs ? (1 + pi) : 0;
        const float* O = obuf + (long long)(p * 4 + b) * 128 * HW;
        bf16x8 bh[4];
#pragma unroll
        for (int ksl = 0; ksl < 4; ksl++) {
            float v[8];
#pragma unroll
            for (int j = 0; j < 8; j++)
                v[j] = O[(long long)(ksl * 32 + 8 * g + j) * HW + m];
            union { unsigned u[4]; bf16x8 v; } H;
#pragma unroll
            for (int t = 0; t < 4; t++)
                H.u[t] = (unsigned)f2bf(v[2 * t]) | ((unsigned)f2bf(v[2 * t + 1]) << 16);
            bh[ksl] = H.v;
        }
        const unsigned short* WH = woh + p * 16384;
#pragma unroll
        for (int ct = 0; ct < 8; ct++)
#pragma unroll
            for (int ksl = 0; ksl < 4; ksl++) {
                bf16x8 A = *(const bf16x8*)(WH + (ct * 16 + lm) * 128 + ksl * 32 + 8 * g);
                acc[ct] = __builtin_amdgcn_mfma_f32_16x16x32_bf16(A, bh[ksl], acc[ct], 0, 0, 0);
            }
    }

    int qi = vs + 1;
    const float* xq = (vs ? x2 : x1) + (long long)b * CC * HW;
#pragma unroll
    for (int ct = 0; ct < 8; ct++)
#pragma unroll
        for (int r = 0; r < 4; r++) {
            int c = ct * 16 + 4 * g + r;
            float bias = vs ? (bo[128 + c] + bo[256 + c]) : bo[c];
            float base = xq[(long long)(128 + c) * HW + m];
            out[(((long long)(qi * 4 + b)) * CC + 128 + c) * HW + m]
                = base + acc[ct][r] + bias;
        }
}

// ---------------------------------------------------------------------------
extern "C" void kernel_launch(void* const* d_in, const int* in_sizes, int n_in,
                              void* d_out, int out_size, void* d_ws, size_t ws_size,
                              hipStream_t stream) {
    const float* x0 = (const float*)d_in[0];
    const float* x1 = (const float*)d_in[1];
    const float* x2 = (const float*)d_in[2];
    const float* Wq = (const float*)d_in[3];
    const float* bq = (const float*)d_in[4];
    const float* Wk = (const float*)d_in[5];
    const float* bk = (const float*)d_in[6];
    const float* Wv = (const float*)d_in[7];
    const float* bv = (const float*)d_in[8];
    const float* Wo = (const float*)d_in[9];
    const float* bo = (const float*)d_in[10];
    const float* dw_w = (const float*)d_in[11];
    const float* dw_b = (const float*)d_in[12];
    const float* ln_g = (const float*)d_in[13];
    const float* ln_b = (const float*)d_in[14];
    const float* pw_w = (const float*)d_in[15];
    const float* rpe = (const float*)d_in[16];
    float* out = (float*)d_out;

    // Region A: qbuf f32 (K2 w, K3 r) -> obuf f32 (K5 w, K6 r), disjoint.
    float* ws = (float*)d_ws;
    float* qbuf = ws;                                   // 6291456 f (24 MB)
    float* obuf = qbuf;                                 // alias (disjoint lifetime)
    float* posb = ws + 6291456;                         // 6144 f
    unsigned short* xT = (unsigned short*)(posb + 6144);     // 4194304 s (8 MB)
    unsigned short* qbf = xT + 4194304;                      // 12582912 s (24 MB)
    unsigned short* kbf = qbf + 12582912;                    // 393216 s
    unsigned short* vbf = kbf + 393216;                      // 393216 s
    unsigned short* tabbf = vbf + 393216;                    // 196608 s
    uint4* prmb = (uint4*)(tabbf + 196608);                  // 3072 uint4
    unsigned short* wqh = (unsigned short*)(prmb + 3072);    // 49152 s
    unsigned short* wql = wqh + 49152;
    unsigned short* woh = wql + 49152;
    unsigned short* wkh = woh + 49152;
    unsigned short* wvh = wkh + 49152;
    // total ~ 59 MB

    prep_copy<<<1048, 256, 0, stream>>>(rpe, Wq, Wo, Wk, Wv, x0, tabbf,
                                        wqh, wql, woh, wkh, wvh, out);
    conv_q<<<768, 256, 0, stream>>>(x1, x2, wqh, wql, bq, qbuf, qbf, out);
    mid_kernel<<<2240, 256, 0, stream>>>(qbuf, dw_w, dw_b, ln_g, ln_b, pw_w,
                                         x0, x1, posb, prmb, xT);
    sample_kv<<<96, 256, 0, stream>>>(xT, posb, wkh, wvh, bk, bv, kbf, vbf);
    attn_mfma<<<3072, 256, 0, stream>>>(qbf, kbf, vbf, tabbf, prmb, obuf);
    conv_wo<<<512, 256, 0, stream>>>(x1, x2, obuf, woh, bo, out);
}

// Round 15
// 178.862 us; speedup vs baseline: 2.8234x; 1.0098x over previous
//
#include <hip/hip_runtime.h>
#include <math.h>

// Problem constants
#define NVAR 3
#define BB 4
#define CC 256
#define C1 128
#define HEADS 4
#define HH 64
#define WW 64
#define HW 4096
#define RPE_W 127
#define NP 3
#define SCALE 0.17677669529663687f
// pairs: p=0 -> (i=1,j=0), p=1 -> (i=2,j=0), p=2 -> (i=2,j=1)

typedef short bf16x8 __attribute__((ext_vector_type(8)));
typedef float f32x4 __attribute__((ext_vector_type(4)));
typedef __bf16 bf16x2 __attribute__((ext_vector_type(2)));

__device__ __forceinline__ unsigned short f2bf(float f) {
    unsigned int u = __float_as_uint(f);
    u += 0x7fffu + ((u >> 16) & 1u);          // round-to-nearest-even
    return (unsigned short)(u >> 16);
}
__device__ __forceinline__ float bflo(unsigned u) { return __uint_as_float(u << 16); }
__device__ __forceinline__ float bfhi(unsigned u) { return __uint_as_float(u & 0xffff0000u); }

// packed bf16x2 dot: c + a.lo*b.lo + a.hi*b.hi
__device__ __forceinline__ float dot2bf(unsigned a, unsigned b, float c) {
#if __has_builtin(__builtin_amdgcn_fdot2_f32_bf16)
    return __builtin_amdgcn_fdot2_f32_bf16(__builtin_bit_cast(bf16x2, a),
                                           __builtin_bit_cast(bf16x2, b), c, false);
#else
    return c + bflo(a) * bflo(b) + bfhi(a) * bfhi(b);
#endif
}

// ---------------------------------------------------------------------------
// K1) const prep (blocks 0..23) + copy x0 -> out var0 + flow zeros (24..1047)
__global__ __launch_bounds__(256) void prep_copy(const float* __restrict__ rpe,
                                                 const float* __restrict__ Wq,
                                                 const float* __restrict__ Wo,
                                                 const float* __restrict__ Wk,
                                                 const float* __restrict__ Wv,
                                                 const float* __restrict__ x0,
                                                 unsigned short* __restrict__ tabbf,
                                                 unsigned short* __restrict__ wqh,
                                                 unsigned short* __restrict__ wql,
                                                 unsigned short* __restrict__ woh,
                                                 unsigned short* __restrict__ wkh,
                                                 unsigned short* __restrict__ wvh,
                                                 float* __restrict__ out) {
    int blk = blockIdx.x;
    if (blk >= 24) {
        const long long n4 = (long long)BB * CC * HW / 4;
        long long i = (long long)(blk - 24) * 256 + threadIdx.x;
        const long long stride = 1024LL * 256;
        for (; i < n4 + 12; i += stride) {
            if (i < n4) ((float4*)out)[i] = ((const float4*)x0)[i];
            else out[3LL * BB * CC * HW + (i - n4)] = 0.f;
        }
        return;
    }
    if (blk < 12) {
        const float* src = rpe + (long long)blk * RPE_W * RPE_W;
        unsigned short* dst = tabbf + (long long)blk * 16384;
        for (int idx = threadIdx.x; idx < 16384; idx += 256) {
            int y = idx >> 7, x = idx & 127;
            float v = (y < RPE_W && x < RPE_W) ? src[y * RPE_W + x] : 0.f;
            dst[idx] = f2bf(v);
        }
    } else if (blk < 15) {
        int p = blk - 12;
        for (int i = threadIdx.x; i < 16384; i += 256) {
            float w = Wq[p * 16384 + i];
            unsigned short h = f2bf(w);
            wqh[p * 16384 + i] = h;
            wql[p * 16384 + i] = f2bf(w - bflo((unsigned)h));
        }
    } else if (blk < 18) {
        int p = blk - 15;
        for (int i = threadIdx.x; i < 16384; i += 256)
            woh[p * 16384 + i] = f2bf(Wo[p * 16384 + i]);
    } else if (blk < 21) {
        int p = blk - 18;
        for (int i = threadIdx.x; i < 16384; i += 256)
            wkh[p * 16384 + i] = f2bf(Wk[p * 16384 + i]);
    } else {
        int p = blk - 21;
        for (int i = threadIdx.x; i < 16384; i += 256)
            wvh[p * 16384 + i] = f2bf(Wv[p * 16384 + i]);
    }
}

// ---------------------------------------------------------------------------
// K2) conv_q via MFMA, split bf16 (hi+lo). Outputs qbuf f32 [pb][c][m],
//     qbf bf16 [pb][m][c] (pre-scaled, coalesced via LDS bounce), AND copies
//     x chans 0:128 into out.
__global__ __launch_bounds__(256) void conv_q(const float* __restrict__ x1,
                                              const float* __restrict__ x2,
                                              const unsigned short* __restrict__ wqh,
                                              const unsigned short* __restrict__ wql,
                                              const float* __restrict__ bq,
                                              float* __restrict__ qbuf,
                                              unsigned short* __restrict__ qbf,
                                              float* __restrict__ out) {
    __shared__ unsigned short qlds[4][16][136];   // 17 KB; 16B-aligned rows
    int wid = threadIdx.x >> 6, lane = threadIdx.x & 63;
    int g = lane >> 4, lm = lane & 15;
    int gw = blockIdx.x * 4 + wid;            // 3072 waves
    int mt = gw & 255;
    int pb = gw >> 8;
    int p = pb >> 2, b = pb & 3;
    const float* X = ((p == 0) ? x1 : x2) + (long long)b * CC * HW;
    int m = mt * 16 + lm;
    float* outc = (p < 2)
        ? out + (((long long)((p + 1) * 4 + b)) * CC) * HW + m
        : nullptr;

    bf16x8 bhi[4], blo[4];
#pragma unroll
    for (int ksl = 0; ksl < 4; ksl++) {
        float v[8];
#pragma unroll
        for (int j = 0; j < 8; j++) {
            int k = ksl * 32 + 8 * g + j;
            v[j] = X[(long long)k * HW + m];
            if (outc) outc[(long long)k * HW] = v[j];
        }
        union { unsigned u[4]; bf16x8 v; } H, L;
#pragma unroll
        for (int t = 0; t < 4; t++) {
            unsigned short h0 = f2bf(v[2 * t]), h1 = f2bf(v[2 * t + 1]);
            unsigned short l0 = f2bf(v[2 * t] - bflo((unsigned)h0));
            unsigned short l1 = f2bf(v[2 * t + 1] - bflo((unsigned)h1));
            H.u[t] = (unsigned)h0 | ((unsigned)h1 << 16);
            L.u[t] = (unsigned)l0 | ((unsigned)l1 << 16);
        }
        bhi[ksl] = H.v;
        blo[ksl] = L.v;
    }

    const unsigned short* WH = wqh + p * 16384;
    const unsigned short* WL = wql + p * 16384;
    unsigned short* ql = &qlds[wid][lm][0];
    f32x4 zero = {0.f, 0.f, 0.f, 0.f};
#pragma unroll
    for (int ct2 = 0; ct2 < 4; ct2++) {
        int ct0 = 2 * ct2, ct1 = ct0 + 1;
        f32x4 a0 = zero, a1 = zero;
#pragma unroll
        for (int ksl = 0; ksl < 4; ksl++) {
            bf16x8 Ah0 = *(const bf16x8*)(WH + (ct0 * 16 + lm) * 128 + ksl * 32 + 8 * g);
            bf16x8 Al0 = *(const bf16x8*)(WL + (ct0 * 16 + lm) * 128 + ksl * 32 + 8 * g);
            bf16x8 Ah1 = *(const bf16x8*)(WH + (ct1 * 16 + lm) * 128 + ksl * 32 + 8 * g);
            bf16x8 Al1 = *(const bf16x8*)(WL + (ct1 * 16 + lm) * 128 + ksl * 32 + 8 * g);
            a0 = __builtin_amdgcn_mfma_f32_16x16x32_bf16(Ah0, bhi[ksl], a0, 0, 0, 0);
            a1 = __builtin_amdgcn_mfma_f32_16x16x32_bf16(Ah1, bhi[ksl], a1, 0, 0, 0);
            a0 = __builtin_amdgcn_mfma_f32_16x16x32_bf16(Ah0, blo[ksl], a0, 0, 0, 0);
            a1 = __builtin_amdgcn_mfma_f32_16x16x32_bf16(Ah1, blo[ksl], a1, 0, 0, 0);
            a0 = __builtin_amdgcn_mfma_f32_16x16x32_bf16(Al0, bhi[ksl], a0, 0, 0, 0);
            a1 = __builtin_amdgcn_mfma_f32_16x16x32_bf16(Al1, bhi[ksl], a1, 0, 0, 0);
        }
        float q0[4], q1[4];
#pragma unroll
        for (int r = 0; r < 4; r++) {
            int c0 = ct0 * 16 + 4 * g + r, c1 = ct1 * 16 + 4 * g + r;
            q0[r] = a0[r] + bq[p * 128 + c0];
            q1[r] = a1[r] + bq[p * 128 + c1];
            qbuf[((long long)pb * 128 + c0) * HW + m] = q0[r];
            qbuf[((long long)pb * 128 + c1) * HW + m] = q1[r];
        }
        *(unsigned*)(ql + ct0 * 16 + 4 * g) =
            (unsigned)f2bf(q0[0] * SCALE) | ((unsigned)f2bf(q0[1] * SCALE) << 16);
        *(unsigned*)(ql + ct0 * 16 + 4 * g + 2) =
            (unsigned)f2bf(q0[2] * SCALE) | ((unsigned)f2bf(q0[3] * SCALE) << 16);
        *(unsigned*)(ql + ct1 * 16 + 4 * g) =
            (unsigned)f2bf(q1[0] * SCALE) | ((unsigned)f2bf(q1[1] * SCALE) << 16);
        *(unsigned*)(ql + ct1 * 16 + 4 * g + 2) =
            (unsigned)f2bf(q1[2] * SCALE) | ((unsigned)f2bf(q1[3] * SCALE) << 16);
    }

    // same-wave LDS readback -> coalesced 1KB-contiguous global stores
    unsigned short* Yb = qbf + ((long long)pb * HW + mt * 16) * 128;
    int q = lane >> 4, cg = lane & 15;
#pragma unroll
    for (int i = 0; i < 4; i++) {
        int row = i * 4 + q;
        uint4 vv = *(const uint4*)&qlds[wid][row][cg * 8];
        *(uint4*)(Yb + row * 128 + cg * 8) = vv;
    }
}

// ---------------------------------------------------------------------------
// K3) fused middle kernel:
//   blocks 0..191:  offset net (depthwise conv staged in LDS -> LN -> GELU ->
//                   1x1 -> pos + prm), per (pb,hk); 'off' never leaves LDS.
//   blocks 192..2239: transpose x0,x1 chans 0:128 -> xT bf16 [v][b][m][c].
__global__ __launch_bounds__(256) void mid_kernel(const float* __restrict__ qbuf,
                                                  const float* __restrict__ dw_w,
                                                  const float* __restrict__ dw_b,
                                                  const float* __restrict__ ln_g,
                                                  const float* __restrict__ ln_b,
                                                  const float* __restrict__ pw_w,
                                                  const float* __restrict__ x0,
                                                  const float* __restrict__ x1,
                                                  float* __restrict__ posb,
                                                  uint4* __restrict__ prmb,
                                                  unsigned short* __restrict__ xT) {
    __shared__ float sm[32 * 4 * 65 + 16 * 128];     // 41.5 KB
    int blk = blockIdx.x;
    int tid = threadIdx.x;
    if (blk < 192) {
        float (*ld)[4][65] = (float(*)[4][65])sm;
        float (*dwout)[128] = (float(*)[128])(sm + 32 * 4 * 65);
        int pb = blk >> 4, hk = blk & 15;
        int p = pb >> 2;
        for (int cq = 0; cq < 4; cq++) {
            int c32 = cq * 32;
            __syncthreads();
#pragma unroll
            for (int it = 0; it < 8; it++) {
                int i2 = tid + it * 256;          // 2048 float4
                int c = i2 >> 6, rem = i2 & 63;
                int y = rem >> 4, xq = rem & 15;
                float4 v = *(const float4*)(qbuf + ((long long)pb * 128 + c32 + c) * HW
                                            + (4 * hk + y) * 64 + xq * 4);
                ld[c][y][xq * 4 + 0] = v.x;
                ld[c][y][xq * 4 + 1] = v.y;
                ld[c][y][xq * 4 + 2] = v.z;
                ld[c][y][xq * 4 + 3] = v.w;
            }
            __syncthreads();
            int wk = tid >> 4;
#pragma unroll
            for (int oi = 0; oi < 2; oi++) {
                int c = (tid & 15) + oi * 16;
                const float* dwp = dw_w + (p * 128 + c32 + c) * 16;
                float acc = dw_b[p * 128 + c32 + c];
#pragma unroll
                for (int ky = 0; ky < 4; ky++)
#pragma unroll
                    for (int kx = 0; kx < 4; kx++)
                        acc += ld[c][ky][wk * 4 + kx] * dwp[ky * 4 + kx];
                dwout[wk][c32 + c] = acc;
            }
        }
        __syncthreads();
        // LN phase: 4 waves x 4 wk each
        int wid = tid >> 6, lane = tid & 63;
        for (int i = 0; i < 4; i++) {
            int wk = wid * 4 + i;
            int s = hk * 16 + wk;
            float a0 = dwout[wk][lane], a1 = dwout[wk][lane + 64];
            float s1 = a0 + a1;
#pragma unroll
            for (int o = 1; o < 64; o <<= 1) s1 += __shfl_xor(s1, o);
            float mu = s1 * (1.f / 128.f);
            float d0 = a0 - mu, d1 = a1 - mu;
            float v2 = d0 * d0 + d1 * d1;
#pragma unroll
            for (int o = 1; o < 64; o <<= 1) v2 += __shfl_xor(v2, o);
            float rs = rsqrtf(v2 * (1.f / 128.f) + 1e-5f);
            int c0 = lane, c1 = lane + 64;
            float y0 = d0 * rs * ln_g[p * 128 + c0] + ln_b[p * 128 + c0];
            float y1 = d1 * rs * ln_g[p * 128 + c1] + ln_b[p * 128 + c1];
            float g0 = 0.5f * y0 * (1.f + erff(y0 * 0.70710678118654752f));
            float g1 = 0.5f * y1 * (1.f + erff(y1 * 0.70710678118654752f));
            float o0 = pw_w[(p * 2 + 0) * 128 + c0] * g0
                     + pw_w[(p * 2 + 0) * 128 + c1] * g1;
            float o1 = pw_w[(p * 2 + 1) * 128 + c0] * g0
                     + pw_w[(p * 2 + 1) * 128 + c1] * g1;
#pragma unroll
            for (int o = 1; o < 64; o <<= 1) o0 += __shfl_xor(o0, o);
#pragma unroll
            for (int o = 1; o < 64; o <<= 1) o1 += __shfl_xor(o1, o);
            if (lane == 0) {
                int wk2 = s & 15;
                float refy = (hk + 0.5f) * (2.f / 15.f) - 1.f;
                float refx = (wk2 + 0.5f) * (2.f / 15.f) - 1.f;
                float py = fminf(fmaxf(o0 + refy, -1.f), 1.f);
                float px = fminf(fmaxf(o1 + refx, -1.f), 1.f);
                int pbn = pb * 256 + s;
                posb[pbn * 2 + 0] = py;
                posb[pbn * 2 + 1] = px;
                float cy = 31.5f * (1.f - py), cx = 31.5f * (1.f - px);
                float yf = floorf(cy), xf = floorf(cx);
                float wy = cy - yf, wx = cx - xf;
                int Y0 = (int)yf, X0 = (int)xf;
                uint4 v;
                v.x = (unsigned)f2bf((1.f - wy) * (1.f - wx))
                    | ((unsigned)f2bf((1.f - wy) * wx) << 16);
                v.y = (unsigned)f2bf(wy * (1.f - wx))
                    | ((unsigned)f2bf(wy * wx) << 16);
                v.z = (unsigned)((Y0 * 128 + X0) * 2);
                v.w = 0;
                prmb[pbn] = v;
            }
        }
    } else {
        // transpose part
        float (*ld2)[65] = (float(*)[65])sm;
        int rem = blk - 192;                  // 0..2047
        int v = rem >> 10;
        int rem1 = rem & 1023;
        int b = rem1 >> 8;
        int rem2 = rem1 & 255;
        int ct = rem2 >> 6;
        int mt = rem2 & 63;
        const float* src = ((v == 0) ? x0 : x1) + (long long)b * CC * HW
                           + (long long)(ct * 32) * HW + mt * 64;
#pragma unroll
        for (int it = 0; it < 2; it++) {
            int c = tid >> 3, x4 = (tid & 7) + it * 8;
            float4 w = *(const float4*)(src + (long long)c * HW + x4 * 4);
            ld2[c][x4 * 4 + 0] = w.x;
            ld2[c][x4 * 4 + 1] = w.y;
            ld2[c][x4 * 4 + 2] = w.z;
            ld2[c][x4 * 4 + 3] = w.w;
        }
        __syncthreads();
        int m = tid >> 2, cg = tid & 3;
        union { unsigned u[4]; } pk;
#pragma unroll
        for (int t = 0; t < 4; t++) {
            unsigned short h0 = f2bf(ld2[cg * 8 + 2 * t][m]);
            unsigned short h1 = f2bf(ld2[cg * 8 + 2 * t + 1][m]);
            pk.u[t] = (unsigned)h0 | ((unsigned)h1 << 16);
        }
        *(uint4*)(xT + (((long long)(v * 4 + b)) * HW + mt * 64 + m) * 128
                  + ct * 32 + cg * 8) = *(uint4*)pk.u;
    }
}

// ---------------------------------------------------------------------------
// K4) fused sample + K/V conv (MFMA), clamped-base bilinear (NaN-safe).
__global__ __launch_bounds__(256) void sample_kv(const unsigned short* __restrict__ xT,
                                                 const float* __restrict__ posb,
                                                 const unsigned short* __restrict__ wkh,
                                                 const unsigned short* __restrict__ wvh,
                                                 const float* __restrict__ bk,
                                                 const float* __restrict__ bv,
                                                 unsigned short* __restrict__ kbf,
                                                 unsigned short* __restrict__ vbf) {
    __shared__ unsigned short xls[32 * 128];      // 8 KB, XOR-swizzled rows
    int blk = blockIdx.x;                 // 96
    int pb = blk >> 3;
    int nt = blk & 7;
    int p = pb >> 2, b = pb & 3;
    int n0 = nt * 32;
    int tid = threadIdx.x;

    {
        int nl = tid >> 3, co = tid & 7;
        int n = n0 + nl;
        float py = posb[(pb * 256 + n) * 2 + 0];
        float px = posb[(pb * 256 + n) * 2 + 1];
        float yi = (py + 1.f) * 31.5f, xi = (px + 1.f) * 31.5f;
        yi = fminf(fmaxf(yi, 0.f), 63.f);
        xi = fminf(fmaxf(xi, 0.f), 63.f);
        int y0 = min((int)yi, 62);
        int x0i = min((int)xi, 62);
        float wy = yi - (float)y0, wx = xi - (float)x0i;
        float w00 = (1.f - wy) * (1.f - wx), w01 = (1.f - wy) * wx;
        float w10 = wy * (1.f - wx), w11 = wy * wx;
        int vsel = (p == 2) ? 1 : 0;
        const unsigned short* base = xT + ((long long)(vsel * 4 + b)) * HW * 128;
        int m00 = y0 * 64 + x0i;
        char* dst = (char*)xls;
#pragma unroll
        for (int cb = 0; cb < 2; cb++) {
            int c0 = co * 16 + cb * 8;
            bf16x8 a = *(const bf16x8*)(base + (long long)m00 * 128 + c0);
            bf16x8 bb = *(const bf16x8*)(base + (long long)(m00 + 1) * 128 + c0);
            bf16x8 cc = *(const bf16x8*)(base + (long long)(m00 + 64) * 128 + c0);
            bf16x8 dd = *(const bf16x8*)(base + (long long)(m00 + 65) * 128 + c0);
            union { unsigned u[4]; bf16x8 v; } R;
#pragma unroll
            for (int t = 0; t < 4; t++) {
                float r0 = w00 * bflo((unsigned)(unsigned short)a[2 * t])
                         + w01 * bflo((unsigned)(unsigned short)bb[2 * t])
                         + w10 * bflo((unsigned)(unsigned short)cc[2 * t])
                         + w11 * bflo((unsigned)(unsigned short)dd[2 * t]);
                float r1 = w00 * bflo((unsigned)(unsigned short)a[2 * t + 1])
                         + w01 * bflo((unsigned)(unsigned short)bb[2 * t + 1])
                         + w10 * bflo((unsigned)(unsigned short)cc[2 * t + 1])
                         + w11 * bflo((unsigned)(unsigned short)dd[2 * t + 1]);
                R.u[t] = (unsigned)f2bf(r0) | ((unsigned)f2bf(r1) << 16);
            }
            *(bf16x8*)(dst + ((nl * 256 + c0 * 2) ^ ((nl & 7) << 4))) = R.v;
        }
    }
    __syncthreads();

    int wid = tid >> 6, lane = tid & 63;
    int g = lane >> 4, lm = lane & 15;
    int ntile = wid & 1, isv = wid >> 1;
    int nl = ntile * 16 + lm;
    const char* srcl = (const char*)xls;
    bf16x8 xf[4];
#pragma unroll
    for (int ks = 0; ks < 4; ks++)
        xf[ks] = *(const bf16x8*)(srcl + ((nl * 256 + (ks * 32 + 8 * g) * 2)
                                          ^ ((nl & 7) << 4)));
    f32x4 zero = {0.f, 0.f, 0.f, 0.f};
    if (!isv) {
        const unsigned short* WK = wkh + p * 16384;
#pragma unroll
        for (int ct = 0; ct < 8; ct++) {
            f32x4 acc = zero;
#pragma unroll
            for (int ks = 0; ks < 4; ks++) {
                bf16x8 wf = *(const bf16x8*)(WK + (ct * 16 + lm) * 128 + ks * 32 + 8 * g);
                acc = __builtin_amdgcn_mfma_f32_16x16x32_bf16(xf[ks], wf, acc, 0, 0, 0);
            }
            float bias = bk[p * 128 + ct * 16 + lm];
#pragma unroll
            for (int r = 0; r < 4; r++) {
                int n = n0 + ntile * 16 + 4 * g + r;
                kbf[((long long)pb * 256 + n) * 128 + ct * 16 + lm] = f2bf(acc[r] + bias);
            }
        }
    } else {
        const unsigned short* WV = wvh + p * 16384;
#pragma unroll
        for (int ct = 0; ct < 8; ct++) {
            f32x4 acc = zero;
#pragma unroll
            for (int ks = 0; ks < 4; ks++) {
                bf16x8 wf = *(const bf16x8*)(WV + (ct * 16 + lm) * 128 + ks * 32 + 8 * g);
                acc = __builtin_amdgcn_mfma_f32_16x16x32_bf16(wf, xf[ks], acc, 0, 0, 0);
            }
#pragma unroll
            for (int r = 0; r < 4; r++) {
                int c = ct * 16 + 4 * g + r;
                vbf[((long long)pb * 128 + c) * 256 + n0 + ntile * 16 + lm]
                    = f2bf(acc[r] + bv[p * 128 + c]);
            }
        }
    }
}

// ---------------------------------------------------------------------------
// K5) MFMA attention (R9 known-best structure). Output now bf16 [pb][m][c],
//     bounced through the DEAD tab LDS region (tab/prm unused after bias) for
//     coalesced 16B stores. One extra __syncthreads before the bounce.
__global__ __launch_bounds__(256, 4) void attn_mfma(
        const unsigned short* __restrict__ qbf,
        const unsigned short* __restrict__ kbf,
        const unsigned short* __restrict__ vbf,
        const unsigned short* __restrict__ tabbf,
        const uint4* __restrict__ prmb,
        unsigned short* __restrict__ obf) {
    __shared__ unsigned short tab[16384 + 8];   // +8: speculative dword pad
    __shared__ uint4 prm[256];
    int tid = threadIdx.x;
    int wid = tid >> 6, lane = tid & 63;
    int g = lane >> 4, lm = lane & 15;
    int bid = blockIdx.x;                     // 3072
    int my = bid & 63;
    int h = (bid >> 6) & 3;
    int b = (bid >> 8) & 3;
    int p = bid >> 10;
    int pb = p * 4 + b;

    {   // stage table + params
        const uint4* ts = (const uint4*)(tabbf + (long long)(p * 4 + h) * 16384);
        uint4* td = (uint4*)tab;
#pragma unroll
        for (int i = 0; i < 8; i++) td[tid + i * 256] = ts[tid + i * 256];
        prm[tid] = prmb[pb * 256 + tid];
    }
    __syncthreads();

    int mx = (wid << 4) + lm;

    // ---- QK^T (swapped): A = K[n][c], B = Q^T[c][m]; q pre-scaled ----
    bf16x8 qf = *(const bf16x8*)(qbf + ((long long)pb * HW + my * 64 + mx) * 128
                                 + h * 32 + 8 * g);
    const unsigned short* kbase = kbf + ((long long)pb * 256 + lm) * 128
                                  + h * 32 + 8 * g;
    f32x4 zero = {0.f, 0.f, 0.f, 0.f};
    f32x4 acc[16];
    __builtin_amdgcn_s_setprio(1);
#pragma unroll
    for (int ni = 0; ni < 16; ni++) {
        bf16x8 kf = *(const bf16x8*)(kbase + ni * 16 * 128);
        acc[ni] = __builtin_amdgcn_mfma_f32_16x16x32_bf16(kf, qf, zero, 0, 0, 0);
    }
    __builtin_amdgcn_s_setprio(0);

    // ---- RPE bias: aligned b32 pair reads + alignbyte + dot2 ----
    int laneoff = (my * 128 + mx) * 2;
    const char* tb = (const char*)tab;
#pragma unroll
    for (int ni = 0; ni < 16; ni++) {
#pragma unroll
        for (int r = 0; r < 4; r++) {
            int n = ni * 16 + 4 * g + r;
            uint4 pw = prm[n];
            int va = (int)pw.z + laneoff;
            int va4 = va & ~3;
            int sh = va & 3;
            unsigned r0 = *(const unsigned*)(tb + va4);
            unsigned r1 = *(const unsigned*)(tb + va4 + 4);
            unsigned r2 = *(const unsigned*)(tb + va4 + 256);
            unsigned r3 = *(const unsigned*)(tb + va4 + 260);
            unsigned p0 = __builtin_amdgcn_alignbyte(r1, r0, sh);
            unsigned p1 = __builtin_amdgcn_alignbyte(r3, r2, sh);
            float t = acc[ni][r];
            t = dot2bf(p0, pw.x, t);
            t = dot2bf(p1, pw.y, t);
            acc[ni][r] = t;
        }
    }

    // ---- softmax over n ----
    float mxv = -1e30f;
#pragma unroll
    for (int ni = 0; ni < 16; ni++)
        mxv = fmaxf(mxv, fmaxf(fmaxf(acc[ni][0], acc[ni][1]),
                               fmaxf(acc[ni][2], acc[ni][3])));
    mxv = fmaxf(mxv, __shfl_xor(mxv, 16));
    mxv = fmaxf(mxv, __shfl_xor(mxv, 32));
    float sum = 0.f;
    unsigned dwA[16], dwB[16];
#pragma unroll
    for (int ni = 0; ni < 16; ni++) {
        float e0 = __expf(acc[ni][0] - mxv);
        float e1 = __expf(acc[ni][1] - mxv);
        float e2 = __expf(acc[ni][2] - mxv);
        float e3 = __expf(acc[ni][3] - mxv);
        sum += (e0 + e1) + (e2 + e3);
        asm("v_cvt_pk_bf16_f32 %0, %1, %2" : "=v"(dwA[ni]) : "v"(e0), "v"(e1));
        asm("v_cvt_pk_bf16_f32 %0, %1, %2" : "=v"(dwB[ni]) : "v"(e2), "v"(e3));
    }
    sum += __shfl_xor(sum, 16);
    sum += __shfl_xor(sum, 32);

    // ---- PV: pf assembled via shfl exchange ----
    int src0 = ((g & 1) << 5) + lm;
    int src1 = src0 + 16;
    bool sel = (g >> 1) != 0;
    const unsigned short* vb0 = vbf + ((long long)pb * 128 + h * 32 + lm) * 256
                                + 8 * g;
    f32x4 o0 = zero, o1 = zero;
#pragma unroll
    for (int st = 0; st < 8; st++) {
        unsigned d0a = __shfl(dwA[2 * st], src0), d0b = __shfl(dwA[2 * st + 1], src0);
        unsigned d1a = __shfl(dwB[2 * st], src0), d1b = __shfl(dwB[2 * st + 1], src0);
        unsigned d2a = __shfl(dwA[2 * st], src1), d2b = __shfl(dwA[2 * st + 1], src1);
        unsigned d3a = __shfl(dwB[2 * st], src1), d3b = __shfl(dwB[2 * st + 1], src1);
        union { unsigned u[4]; bf16x8 v; } pf;
        pf.u[0] = sel ? d0b : d0a;
        pf.u[1] = sel ? d1b : d1a;
        pf.u[2] = sel ? d2b : d2a;
        pf.u[3] = sel ? d3b : d3a;
        bf16x8 v0 = *(const bf16x8*)(vb0 + st * 32);
        bf16x8 v1 = *(const bf16x8*)(vb0 + 4096 + st * 32);
        __builtin_amdgcn_s_setprio(1);
        o0 = __builtin_amdgcn_mfma_f32_16x16x32_bf16(v0, pf.v, o0, 0, 0, 0);
        o1 = __builtin_amdgcn_mfma_f32_16x16x32_bf16(v1, pf.v, o1, 0, 0, 0);
        __builtin_amdgcn_s_setprio(0);
    }

    float inv = 1.f / sum;
    // ---- output: bf16 [m][c] via LDS bounce (reuse dead tab region).
    //      per-wave tile 16 m x 32 c, rows padded to 40 shorts (80 B:
    //      16B-aligned, 2-way-free banks).
    __syncthreads();                          // all tab/prm reads complete
    {
        unsigned short* rw = tab + wid * 640 + lm * 40;
        *(unsigned*)(rw + g * 4) =
            (unsigned)f2bf(o0[0] * inv) | ((unsigned)f2bf(o0[1] * inv) << 16);
        *(unsigned*)(rw + g * 4 + 2) =
            (unsigned)f2bf(o0[2] * inv) | ((unsigned)f2bf(o0[3] * inv) << 16);
        *(unsigned*)(rw + 16 + g * 4) =
            (unsigned)f2bf(o1[0] * inv) | ((unsigned)f2bf(o1[1] * inv) << 16);
        *(unsigned*)(rw + 16 + g * 4 + 2) =
            (unsigned)f2bf(o1[2] * inv) | ((unsigned)f2bf(o1[3] * inv) << 16);
    }
    // same-wave readback -> coalesced 16B stores (4 lanes = 64 B per m-row)
    int row = lane >> 2, cb = lane & 3;
    uint4 vv = *(const uint4*)(tab + wid * 640 + row * 40 + cb * 8);
    *(uint4*)(obf + ((long long)pb * HW + my * 64 + wid * 16 + row) * 128
              + h * 32 + cb * 8) = vv;
}

// ---------------------------------------------------------------------------
// K6) conv_wo via MFMA (bf16): out = x + sum_p Wo[p] o[p] + bo on chans
//     128:256 of vars 1,2. obuf is bf16 [m][c]: B-fragments are single
//     contiguous 16B loads (no strided f32 gather, no repack).
__global__ __launch_bounds__(256) void conv_wo(const float* __restrict__ x1,
                                               const float* __restrict__ x2,
                                               const unsigned short* __restrict__ obf,
                                               const unsigned short* __restrict__ woh,
                                               const float* __restrict__ bo,
                                               float* __restrict__ out) {
    int wid = threadIdx.x >> 6, lane = threadIdx.x & 63;
    int g = lane >> 4, lm = lane & 15;
    int gw = blockIdx.x * 4 + wid;            // 2048 waves
    int mt = gw & 255;
    int b = (gw >> 8) & 3;
    int vs = gw >> 10;
    int m = mt * 16 + lm;
    int np = vs + 1;

    f32x4 acc[8];
#pragma unroll
    for (int ct = 0; ct < 8; ct++) acc[ct] = (f32x4){0.f, 0.f, 0.f, 0.f};

    for (int pi = 0; pi < np; pi++) {
        int p = vs ? (1 + pi) : 0;
        const unsigned short* Om = obf + ((long long)(p * 4 + b) * HW + m) * 128;
        const unsigned short* WH = woh + p * 16384;
#pragma unroll
        for (int ksl = 0; ksl < 4; ksl++) {
            bf16x8 bh = *(const bf16x8*)(Om + ksl * 32 + 8 * g);
#pragma unroll
            for (int ct = 0; ct < 8; ct++) {
                bf16x8 A = *(const bf16x8*)(WH + (ct * 16 + lm) * 128 + ksl * 32 + 8 * g);
                acc[ct] = __builtin_amdgcn_mfma_f32_16x16x32_bf16(A, bh, acc[ct], 0, 0, 0);
            }
        }
    }

    int qi = vs + 1;
    const float* xq = (vs ? x2 : x1) + (long long)b * CC * HW;
#pragma unroll
    for (int ct = 0; ct < 8; ct++)
#pragma unroll
        for (int r = 0; r < 4; r++) {
            int c = ct * 16 + 4 * g + r;
            float bias = vs ? (bo[128 + c] + bo[256 + c]) : bo[c];
            float base = xq[(long long)(128 + c) * HW + m];
            out[(((long long)(qi * 4 + b)) * CC + 128 + c) * HW + m]
                = base + acc[ct][r] + bias;
        }
}

// ---------------------------------------------------------------------------
extern "C" void kernel_launch(void* const* d_in, const int* in_sizes, int n_in,
                              void* d_out, int out_size, void* d_ws, size_t ws_size,
                              hipStream_t stream) {
    const float* x0 = (const float*)d_in[0];
    const float* x1 = (const float*)d_in[1];
    const float* x2 = (const float*)d_in[2];
    const float* Wq = (const float*)d_in[3];
    const float* bq = (const float*)d_in[4];
    const float* Wk = (const float*)d_in[5];
    const float* bk = (const float*)d_in[6];
    const float* Wv = (const float*)d_in[7];
    const float* bv = (const float*)d_in[8];
    const float* Wo = (const float*)d_in[9];
    const float* bo = (const float*)d_in[10];
    const float* dw_w = (const float*)d_in[11];
    const float* dw_b = (const float*)d_in[12];
    const float* ln_g = (const float*)d_in[13];
    const float* ln_b = (const float*)d_in[14];
    const float* pw_w = (const float*)d_in[15];
    const float* rpe = (const float*)d_in[16];
    float* out = (float*)d_out;

    // Region A: qbuf f32 (K2 w, K3 r) -> obf bf16 (K5 w, K6 r), disjoint.
    float* ws = (float*)d_ws;
    float* qbuf = ws;                                   // 6291456 f (24 MB)
    unsigned short* obf = (unsigned short*)ws;          // 6291456 s (12 MB, alias)
    float* posb = ws + 6291456;                         // 6144 f
    unsigned short* xT = (unsigned short*)(posb + 6144);     // 4194304 s (8 MB)
    unsigned short* qbf = xT + 4194304;                      // 12582912 s (24 MB)
    unsigned short* kbf = qbf + 12582912;                    // 393216 s
    unsigned short* vbf = kbf + 393216;                      // 393216 s
    unsigned short* tabbf = vbf + 393216;                    // 196608 s
    uint4* prmb = (uint4*)(tabbf + 196608);                  // 3072 uint4
    unsigned short* wqh = (unsigned short*)(prmb + 3072);    // 49152 s
    unsigned short* wql = wqh + 49152;
    unsigned short* woh = wql + 49152;
    unsigned short* wkh = woh + 49152;
    unsigned short* wvh = wkh + 49152;
    // total ~ 59 MB

    prep_copy<<<1048, 256, 0, stream>>>(rpe, Wq, Wo, Wk, Wv, x0, tabbf,
                                        wqh, wql, woh, wkh, wvh, out);
    conv_q<<<768, 256, 0, stream>>>(x1, x2, wqh, wql, bq, qbuf, qbf, out);
    mid_kernel<<<2240, 256, 0, stream>>>(qbuf, dw_w, dw_b, ln_g, ln_b, pw_w,
                                         x0, x1, posb, prmb, xT);
    sample_kv<<<96, 256, 0, stream>>>(xT, posb, wkh, wvh, bk, bv, kbf, vbf);
    attn_mfma<<<3072, 256, 0, stream>>>(qbf, kbf, vbf, tabbf, prmb, obf);
    conv_wo<<<512, 256, 0, stream>>>(x1, x2, obf, woh, bo, out);
}

// Round 16
// 163.134 us; speedup vs baseline: 3.0956x; 1.0964x over previous
//
#include <hip/hip_runtime.h>
#include <math.h>

// Problem constants
#define NVAR 3
#define BB 4
#define CC 256
#define C1 128
#define HEADS 4
#define HH 64
#define WW 64
#define HW 4096
#define RPE_W 127
#define NP 3
#define SCALE 0.17677669529663687f
// pairs: p=0 -> (i=1,j=0), p=1 -> (i=2,j=0), p=2 -> (i=2,j=1)

typedef short bf16x8 __attribute__((ext_vector_type(8)));
typedef float f32x4 __attribute__((ext_vector_type(4)));
typedef __bf16 bf16x2 __attribute__((ext_vector_type(2)));

__device__ __forceinline__ unsigned short f2bf(float f) {
    unsigned int u = __float_as_uint(f);
    u += 0x7fffu + ((u >> 16) & 1u);          // round-to-nearest-even
    return (unsigned short)(u >> 16);
}
__device__ __forceinline__ float bflo(unsigned u) { return __uint_as_float(u << 16); }
__device__ __forceinline__ float bfhi(unsigned u) { return __uint_as_float(u & 0xffff0000u); }

// packed bf16x2 dot: c + a.lo*b.lo + a.hi*b.hi
__device__ __forceinline__ float dot2bf(unsigned a, unsigned b, float c) {
#if __has_builtin(__builtin_amdgcn_fdot2_f32_bf16)
    return __builtin_amdgcn_fdot2_f32_bf16(__builtin_bit_cast(bf16x2, a),
                                           __builtin_bit_cast(bf16x2, b), c, false);
#else
    return c + bflo(a) * bflo(b) + bfhi(a) * bfhi(b);
#endif
}

// ---------------------------------------------------------------------------
// K1) const prep (blocks 0..23) + copy x0 -> out var0 + flow zeros (24..1047)
__global__ __launch_bounds__(256) void prep_copy(const float* __restrict__ rpe,
                                                 const float* __restrict__ Wq,
                                                 const float* __restrict__ Wo,
                                                 const float* __restrict__ Wk,
                                                 const float* __restrict__ Wv,
                                                 const float* __restrict__ x0,
                                                 unsigned short* __restrict__ tabbf,
                                                 unsigned short* __restrict__ wqh,
                                                 unsigned short* __restrict__ woh,
                                                 unsigned short* __restrict__ wkh,
                                                 unsigned short* __restrict__ wvh,
                                                 float* __restrict__ out) {
    int blk = blockIdx.x;
    if (blk >= 24) {
        const long long n4 = (long long)BB * CC * HW / 4;
        long long i = (long long)(blk - 24) * 256 + threadIdx.x;
        const long long stride = 1024LL * 256;
        for (; i < n4 + 12; i += stride) {
            if (i < n4) ((float4*)out)[i] = ((const float4*)x0)[i];
            else out[3LL * BB * CC * HW + (i - n4)] = 0.f;
        }
        return;
    }
    if (blk < 12) {
        const float* src = rpe + (long long)blk * RPE_W * RPE_W;
        unsigned short* dst = tabbf + (long long)blk * 16384;
        for (int idx = threadIdx.x; idx < 16384; idx += 256) {
            int y = idx >> 7, x = idx & 127;
            float v = (y < RPE_W && x < RPE_W) ? src[y * RPE_W + x] : 0.f;
            dst[idx] = f2bf(v);
        }
    } else if (blk < 15) {
        int p = blk - 12;
        for (int i = threadIdx.x; i < 16384; i += 256)
            wqh[p * 16384 + i] = f2bf(Wq[p * 16384 + i]);
    } else if (blk < 18) {
        int p = blk - 15;
        for (int i = threadIdx.x; i < 16384; i += 256)
            woh[p * 16384 + i] = f2bf(Wo[p * 16384 + i]);
    } else if (blk < 21) {
        int p = blk - 18;
        for (int i = threadIdx.x; i < 16384; i += 256)
            wkh[p * 16384 + i] = f2bf(Wk[p * 16384 + i]);
    } else {
        int p = blk - 21;
        for (int i = threadIdx.x; i < 16384; i += 256)
            wvh[p * 16384 + i] = f2bf(Wv[p * 16384 + i]);
    }
}

// ---------------------------------------------------------------------------
// K2) conv_q via MFMA (single bf16). Writes qbf bf16 [pb][m][c] (pre-scaled,
//     coalesced via LDS bounce) AND copies x chans 0:128 into out.
//     Waves with pbi>=4 compute BOTH p=1 and p=2 (shared x2 B-fragments).
__global__ __launch_bounds__(256) void conv_q(const float* __restrict__ x1,
                                              const float* __restrict__ x2,
                                              const unsigned short* __restrict__ wqh,
                                              const float* __restrict__ bq,
                                              unsigned short* __restrict__ qbf,
                                              float* __restrict__ out) {
    __shared__ unsigned short qlds[4][16][136];   // 17 KB; 16B-aligned rows
    int wid = threadIdx.x >> 6, lane = threadIdx.x & 63;
    int g = lane >> 4, lm = lane & 15;
    int gw = blockIdx.x * 4 + wid;            // 2048 waves
    int mt = gw & 255;
    int pbi = gw >> 8;                        // 0..7
    int merged = pbi >> 2;                    // 0: p=0 (x1); 1: p=1&2 (x2)
    int b = pbi & 3;
    const float* X = (merged ? x2 : x1) + (long long)b * CC * HW;
    int m = mt * 16 + lm;
    int qi = merged + 1;
    float* outc = out + (((long long)(qi * 4 + b)) * CC) * HW + m;

    // B fragments (bf16) + copy chans 0:128 to out
    bf16x8 bh[4];
#pragma unroll
    for (int ksl = 0; ksl < 4; ksl++) {
        float v[8];
#pragma unroll
        for (int j = 0; j < 8; j++) {
            int k = ksl * 32 + 8 * g + j;
            v[j] = X[(long long)k * HW + m];
            outc[(long long)k * HW] = v[j];
        }
        union { unsigned u[4]; bf16x8 v; } H;
#pragma unroll
        for (int t = 0; t < 4; t++)
            H.u[t] = (unsigned)f2bf(v[2 * t]) | ((unsigned)f2bf(v[2 * t + 1]) << 16);
        bh[ksl] = H.v;
    }

    f32x4 zero = {0.f, 0.f, 0.f, 0.f};
    unsigned short* ql = &qlds[wid][lm][0];
    int qq = lane >> 4, cg = lane & 15;

    for (int rep = 0; rep <= merged; rep++) {
        int p = merged ? (1 + rep) : 0;
        int pb = p * 4 + b;
        const unsigned short* WH = wqh + p * 16384;
#pragma unroll
        for (int ct2 = 0; ct2 < 4; ct2++) {
            int ct0 = 2 * ct2, ct1 = ct0 + 1;
            f32x4 a0 = zero, a1 = zero;
#pragma unroll
            for (int ksl = 0; ksl < 4; ksl++) {
                bf16x8 Ah0 = *(const bf16x8*)(WH + (ct0 * 16 + lm) * 128 + ksl * 32 + 8 * g);
                bf16x8 Ah1 = *(const bf16x8*)(WH + (ct1 * 16 + lm) * 128 + ksl * 32 + 8 * g);
                a0 = __builtin_amdgcn_mfma_f32_16x16x32_bf16(Ah0, bh[ksl], a0, 0, 0, 0);
                a1 = __builtin_amdgcn_mfma_f32_16x16x32_bf16(Ah1, bh[ksl], a1, 0, 0, 0);
            }
            float q0[4], q1[4];
#pragma unroll
            for (int r = 0; r < 4; r++) {
                q0[r] = a0[r] + bq[p * 128 + ct0 * 16 + 4 * g + r];
                q1[r] = a1[r] + bq[p * 128 + ct1 * 16 + 4 * g + r];
            }
            *(unsigned*)(ql + ct0 * 16 + 4 * g) =
                (unsigned)f2bf(q0[0] * SCALE) | ((unsigned)f2bf(q0[1] * SCALE) << 16);
            *(unsigned*)(ql + ct0 * 16 + 4 * g + 2) =
                (unsigned)f2bf(q0[2] * SCALE) | ((unsigned)f2bf(q0[3] * SCALE) << 16);
            *(unsigned*)(ql + ct1 * 16 + 4 * g) =
                (unsigned)f2bf(q1[0] * SCALE) | ((unsigned)f2bf(q1[1] * SCALE) << 16);
            *(unsigned*)(ql + ct1 * 16 + 4 * g + 2) =
                (unsigned)f2bf(q1[2] * SCALE) | ((unsigned)f2bf(q1[3] * SCALE) << 16);
        }
        // same-wave LDS readback -> coalesced 1KB-contiguous stores
        unsigned short* Yb = qbf + ((long long)pb * HW + mt * 16) * 128;
#pragma unroll
        for (int i = 0; i < 4; i++) {
            int row = i * 4 + qq;
            uint4 vv = *(const uint4*)&qlds[wid][row][cg * 8];
            *(uint4*)(Yb + row * 128 + cg * 8) = vv;
        }
    }
}

// ---------------------------------------------------------------------------
// K3) fused middle kernel:
//   blocks 0..191:  offset net from qbf (bf16, pre-scaled; 1/SCALE folded into
//                   the depthwise weights) -> LN -> GELU -> 1x1 -> pos + prm.
//   blocks 192..2239: transpose x0,x1 chans 0:128 -> xT bf16 [v][b][m][c].
__global__ __launch_bounds__(256) void mid_kernel(const unsigned short* __restrict__ qbf,
                                                  const float* __restrict__ dw_w,
                                                  const float* __restrict__ dw_b,
                                                  const float* __restrict__ ln_g,
                                                  const float* __restrict__ ln_b,
                                                  const float* __restrict__ pw_w,
                                                  const float* __restrict__ x0,
                                                  const float* __restrict__ x1,
                                                  float* __restrict__ posb,
                                                  uint4* __restrict__ prmb,
                                                  unsigned short* __restrict__ xT) {
    __shared__ char sm[40960];                // 40 KB (qs 32K + dwout 8K)
    int blk = blockIdx.x;
    int tid = threadIdx.x;
    if (blk < 192) {
        unsigned short* qs = (unsigned short*)sm;            // 32 KB: 128m x 128c
        float (*dwout)[128] = (float(*)[128])(sm + 32768);   // 8 KB
        int pb = blk >> 4, hk = blk & 15;
        int p = pb >> 2;
        int c = tid & 127;
        int wk0 = tid >> 7;
        const float* dwp_g = dw_w + (p * 128 + c) * 16;
        float dwp[16];
#pragma unroll
        for (int j = 0; j < 16; j++) dwp[j] = dwp_g[j] * (1.f / SCALE);
        float acc[8];
#pragma unroll
        for (int o = 0; o < 8; o++) acc[o] = dw_b[p * 128 + c];
        const unsigned short* Q = qbf + ((long long)pb * HW + hk * 256) * 128;
        for (int pass = 0; pass < 2; pass++) {
            __syncthreads();
#pragma unroll
            for (int it = 0; it < 8; it++) {
                int idx = tid + it * 256;          // 2048 uint4
                int mloc = idx >> 4, cg = idx & 15;
                *(uint4*)(qs + mloc * 128 + cg * 8) =
                    *(const uint4*)(Q + (long long)(pass * 128 + mloc) * 128 + cg * 8);
            }
            __syncthreads();
#pragma unroll
            for (int o = 0; o < 8; o++) {
                int wk = wk0 + o * 2;
                float a = acc[o];
#pragma unroll
                for (int kyl = 0; kyl < 2; kyl++)
#pragma unroll
                    for (int kx = 0; kx < 4; kx++)
                        a += bflo((unsigned)qs[(kyl * 64 + wk * 4 + kx) * 128 + c])
                             * dwp[(pass * 2 + kyl) * 4 + kx];
                acc[o] = a;
            }
        }
        __syncthreads();
#pragma unroll
        for (int o = 0; o < 8; o++) dwout[wk0 + o * 2][c] = acc[o];
        __syncthreads();
        // LN phase: 4 waves x 4 wk each
        int wid = tid >> 6, lane = tid & 63;
        for (int i = 0; i < 4; i++) {
            int wk = wid * 4 + i;
            int s = hk * 16 + wk;
            float a0 = dwout[wk][lane], a1 = dwout[wk][lane + 64];
            float s1 = a0 + a1;
#pragma unroll
            for (int o = 1; o < 64; o <<= 1) s1 += __shfl_xor(s1, o);
            float mu = s1 * (1.f / 128.f);
            float d0 = a0 - mu, d1 = a1 - mu;
            float v2 = d0 * d0 + d1 * d1;
#pragma unroll
            for (int o = 1; o < 64; o <<= 1) v2 += __shfl_xor(v2, o);
            float rs = rsqrtf(v2 * (1.f / 128.f) + 1e-5f);
            int c0 = lane, c1 = lane + 64;
            float y0 = d0 * rs * ln_g[p * 128 + c0] + ln_b[p * 128 + c0];
            float y1 = d1 * rs * ln_g[p * 128 + c1] + ln_b[p * 128 + c1];
            float g0 = 0.5f * y0 * (1.f + erff(y0 * 0.70710678118654752f));
            float g1 = 0.5f * y1 * (1.f + erff(y1 * 0.70710678118654752f));
            float o0 = pw_w[(p * 2 + 0) * 128 + c0] * g0
                     + pw_w[(p * 2 + 0) * 128 + c1] * g1;
            float o1 = pw_w[(p * 2 + 1) * 128 + c0] * g0
                     + pw_w[(p * 2 + 1) * 128 + c1] * g1;
#pragma unroll
            for (int o = 1; o < 64; o <<= 1) o0 += __shfl_xor(o0, o);
#pragma unroll
            for (int o = 1; o < 64; o <<= 1) o1 += __shfl_xor(o1, o);
            if (lane == 0) {
                int wk2 = s & 15;
                float refy = (hk + 0.5f) * (2.f / 15.f) - 1.f;
                float refx = (wk2 + 0.5f) * (2.f / 15.f) - 1.f;
                float py = fminf(fmaxf(o0 + refy, -1.f), 1.f);
                float px = fminf(fmaxf(o1 + refx, -1.f), 1.f);
                int pbn = pb * 256 + s;
                posb[pbn * 2 + 0] = py;
                posb[pbn * 2 + 1] = px;
                float cy = 31.5f * (1.f - py), cx = 31.5f * (1.f - px);
                float yf = floorf(cy), xf = floorf(cx);
                float wy = cy - yf, wx = cx - xf;
                int Y0 = (int)yf, X0 = (int)xf;
                uint4 v;
                v.x = (unsigned)f2bf((1.f - wy) * (1.f - wx))
                    | ((unsigned)f2bf((1.f - wy) * wx) << 16);
                v.y = (unsigned)f2bf(wy * (1.f - wx))
                    | ((unsigned)f2bf(wy * wx) << 16);
                v.z = (unsigned)((Y0 * 128 + X0) * 2);
                v.w = 0;
                prmb[pbn] = v;
            }
        }
    } else {
        // transpose part
        float (*ld2)[65] = (float(*)[65])sm;
        int rem = blk - 192;                  // 0..2047
        int v = rem >> 10;
        int rem1 = rem & 1023;
        int b = rem1 >> 8;
        int rem2 = rem1 & 255;
        int ct = rem2 >> 6;
        int mt = rem2 & 63;
        const float* src = ((v == 0) ? x0 : x1) + (long long)b * CC * HW
                           + (long long)(ct * 32) * HW + mt * 64;
#pragma unroll
        for (int it = 0; it < 2; it++) {
            int c = tid >> 3, x4 = (tid & 7) + it * 8;
            float4 w = *(const float4*)(src + (long long)c * HW + x4 * 4);
            ld2[c][x4 * 4 + 0] = w.x;
            ld2[c][x4 * 4 + 1] = w.y;
            ld2[c][x4 * 4 + 2] = w.z;
            ld2[c][x4 * 4 + 3] = w.w;
        }
        __syncthreads();
        int m = tid >> 2, cg = tid & 3;
        union { unsigned u[4]; } pk;
#pragma unroll
        for (int t = 0; t < 4; t++) {
            unsigned short h0 = f2bf(ld2[cg * 8 + 2 * t][m]);
            unsigned short h1 = f2bf(ld2[cg * 8 + 2 * t + 1][m]);
            pk.u[t] = (unsigned)h0 | ((unsigned)h1 << 16);
        }
        *(uint4*)(xT + (((long long)(v * 4 + b)) * HW + mt * 64 + m) * 128
                  + ct * 32 + cg * 8) = *(uint4*)pk.u;
    }
}

// ---------------------------------------------------------------------------
// K4) fused sample + K/V conv (MFMA), clamped-base bilinear (NaN-safe).
__global__ __launch_bounds__(256) void sample_kv(const unsigned short* __restrict__ xT,
                                                 const float* __restrict__ posb,
                                                 const unsigned short* __restrict__ wkh,
                                                 const unsigned short* __restrict__ wvh,
                                                 const float* __restrict__ bk,
                                                 const float* __restrict__ bv,
                                                 unsigned short* __restrict__ kbf,
                                                 unsigned short* __restrict__ vbf) {
    __shared__ unsigned short xls[32 * 128];      // 8 KB, XOR-swizzled rows
    int blk = blockIdx.x;                 // 96
    int pb = blk >> 3;
    int nt = blk & 7;
    int p = pb >> 2, b = pb & 3;
    int n0 = nt * 32;
    int tid = threadIdx.x;

    {
        int nl = tid >> 3, co = tid & 7;
        int n = n0 + nl;
        float py = posb[(pb * 256 + n) * 2 + 0];
        float px = posb[(pb * 256 + n) * 2 + 1];
        float yi = (py + 1.f) * 31.5f, xi = (px + 1.f) * 31.5f;
        yi = fminf(fmaxf(yi, 0.f), 63.f);
        xi = fminf(fmaxf(xi, 0.f), 63.f);
        int y0 = min((int)yi, 62);
        int x0i = min((int)xi, 62);
        float wy = yi - (float)y0, wx = xi - (float)x0i;
        float w00 = (1.f - wy) * (1.f - wx), w01 = (1.f - wy) * wx;
        float w10 = wy * (1.f - wx), w11 = wy * wx;
        int vsel = (p == 2) ? 1 : 0;
        const unsigned short* base = xT + ((long long)(vsel * 4 + b)) * HW * 128;
        int m00 = y0 * 64 + x0i;
        char* dst = (char*)xls;
#pragma unroll
        for (int cb = 0; cb < 2; cb++) {
            int c0 = co * 16 + cb * 8;
            bf16x8 a = *(const bf16x8*)(base + (long long)m00 * 128 + c0);
            bf16x8 bb = *(const bf16x8*)(base + (long long)(m00 + 1) * 128 + c0);
            bf16x8 cc = *(const bf16x8*)(base + (long long)(m00 + 64) * 128 + c0);
            bf16x8 dd = *(const bf16x8*)(base + (long long)(m00 + 65) * 128 + c0);
            union { unsigned u[4]; bf16x8 v; } R;
#pragma unroll
            for (int t = 0; t < 4; t++) {
                float r0 = w00 * bflo((unsigned)(unsigned short)a[2 * t])
                         + w01 * bflo((unsigned)(unsigned short)bb[2 * t])
                         + w10 * bflo((unsigned)(unsigned short)cc[2 * t])
                         + w11 * bflo((unsigned)(unsigned short)dd[2 * t]);
                float r1 = w00 * bflo((unsigned)(unsigned short)a[2 * t + 1])
                         + w01 * bflo((unsigned)(unsigned short)bb[2 * t + 1])
                         + w10 * bflo((unsigned)(unsigned short)cc[2 * t + 1])
                         + w11 * bflo((unsigned)(unsigned short)dd[2 * t + 1]);
                R.u[t] = (unsigned)f2bf(r0) | ((unsigned)f2bf(r1) << 16);
            }
            *(bf16x8*)(dst + ((nl * 256 + c0 * 2) ^ ((nl & 7) << 4))) = R.v;
        }
    }
    __syncthreads();

    int wid = tid >> 6, lane = tid & 63;
    int g = lane >> 4, lm = lane & 15;
    int ntile = wid & 1, isv = wid >> 1;
    int nl = ntile * 16 + lm;
    const char* srcl = (const char*)xls;
    bf16x8 xf[4];
#pragma unroll
    for (int ks = 0; ks < 4; ks++)
        xf[ks] = *(const bf16x8*)(srcl + ((nl * 256 + (ks * 32 + 8 * g) * 2)
                                          ^ ((nl & 7) << 4)));
    f32x4 zero = {0.f, 0.f, 0.f, 0.f};
    if (!isv) {
        const unsigned short* WK = wkh + p * 16384;
#pragma unroll
        for (int ct = 0; ct < 8; ct++) {
            f32x4 acc = zero;
#pragma unroll
            for (int ks = 0; ks < 4; ks++) {
                bf16x8 wf = *(const bf16x8*)(WK + (ct * 16 + lm) * 128 + ks * 32 + 8 * g);
                acc = __builtin_amdgcn_mfma_f32_16x16x32_bf16(xf[ks], wf, acc, 0, 0, 0);
            }
            float bias = bk[p * 128 + ct * 16 + lm];
#pragma unroll
            for (int r = 0; r < 4; r++) {
                int n = n0 + ntile * 16 + 4 * g + r;
                kbf[((long long)pb * 256 + n) * 128 + ct * 16 + lm] = f2bf(acc[r] + bias);
            }
        }
    } else {
        const unsigned short* WV = wvh + p * 16384;
#pragma unroll
        for (int ct = 0; ct < 8; ct++) {
            f32x4 acc = zero;
#pragma unroll
            for (int ks = 0; ks < 4; ks++) {
                bf16x8 wf = *(const bf16x8*)(WV + (ct * 16 + lm) * 128 + ks * 32 + 8 * g);
                acc = __builtin_amdgcn_mfma_f32_16x16x32_bf16(wf, xf[ks], acc, 0, 0, 0);
            }
#pragma unroll
            for (int r = 0; r < 4; r++) {
                int c = ct * 16 + 4 * g + r;
                vbf[((long long)pb * 128 + c) * 256 + n0 + ntile * 16 + lm]
                    = f2bf(acc[r] + bv[p * 128 + c]);
            }
        }
    }
}

// ---------------------------------------------------------------------------
// K5) MFMA attention (R9 known-best structure). Output bf16 [pb][m][c] via
//     LDS bounce through the dead tab region.
__global__ __launch_bounds__(256, 4) void attn_mfma(
        const unsigned short* __restrict__ qbf,
        const unsigned short* __restrict__ kbf,
        const unsigned short* __restrict__ vbf,
        const unsigned short* __restrict__ tabbf,
        const uint4* __restrict__ prmb,
        unsigned short* __restrict__ obf) {
    __shared__ unsigned short tab[16384 + 8];   // +8: speculative dword pad
    __shared__ uint4 prm[256];
    int tid = threadIdx.x;
    int wid = tid >> 6, lane = tid & 63;
    int g = lane >> 4, lm = lane & 15;
    int bid = blockIdx.x;                     // 3072
    int my = bid & 63;
    int h = (bid >> 6) & 3;
    int b = (bid >> 8) & 3;
    int p = bid >> 10;
    int pb = p * 4 + b;

    {   // stage table + params
        const uint4* ts = (const uint4*)(tabbf + (long long)(p * 4 + h) * 16384);
        uint4* td = (uint4*)tab;
#pragma unroll
        for (int i = 0; i < 8; i++) td[tid + i * 256] = ts[tid + i * 256];
        prm[tid] = prmb[pb * 256 + tid];
    }
    __syncthreads();

    int mx = (wid << 4) + lm;

    // ---- QK^T (swapped): A = K[n][c], B = Q^T[c][m]; q pre-scaled ----
    bf16x8 qf = *(const bf16x8*)(qbf + ((long long)pb * HW + my * 64 + mx) * 128
                                 + h * 32 + 8 * g);
    const unsigned short* kbase = kbf + ((long long)pb * 256 + lm) * 128
                                  + h * 32 + 8 * g;
    f32x4 zero = {0.f, 0.f, 0.f, 0.f};
    f32x4 acc[16];
    __builtin_amdgcn_s_setprio(1);
#pragma unroll
    for (int ni = 0; ni < 16; ni++) {
        bf16x8 kf = *(const bf16x8*)(kbase + ni * 16 * 128);
        acc[ni] = __builtin_amdgcn_mfma_f32_16x16x32_bf16(kf, qf, zero, 0, 0, 0);
    }
    __builtin_amdgcn_s_setprio(0);

    // ---- RPE bias: aligned b32 pair reads + alignbyte + dot2 ----
    int laneoff = (my * 128 + mx) * 2;
    const char* tb = (const char*)tab;
#pragma unroll
    for (int ni = 0; ni < 16; ni++) {
#pragma unroll
        for (int r = 0; r < 4; r++) {
            int n = ni * 16 + 4 * g + r;
            uint4 pw = prm[n];
            int va = (int)pw.z + laneoff;
            int va4 = va & ~3;
            int sh = va & 3;
            unsigned r0 = *(const unsigned*)(tb + va4);
            unsigned r1 = *(const unsigned*)(tb + va4 + 4);
            unsigned r2 = *(const unsigned*)(tb + va4 + 256);
            unsigned r3 = *(const unsigned*)(tb + va4 + 260);
            unsigned p0 = __builtin_amdgcn_alignbyte(r1, r0, sh);
            unsigned p1 = __builtin_amdgcn_alignbyte(r3, r2, sh);
            float t = acc[ni][r];
            t = dot2bf(p0, pw.x, t);
            t = dot2bf(p1, pw.y, t);
            acc[ni][r] = t;
        }
    }

    // ---- softmax over n ----
    float mxv = -1e30f;
#pragma unroll
    for (int ni = 0; ni < 16; ni++)
        mxv = fmaxf(mxv, fmaxf(fmaxf(acc[ni][0], acc[ni][1]),
                               fmaxf(acc[ni][2], acc[ni][3])));
    mxv = fmaxf(mxv, __shfl_xor(mxv, 16));
    mxv = fmaxf(mxv, __shfl_xor(mxv, 32));
    float sum = 0.f;
    unsigned dwA[16], dwB[16];
#pragma unroll
    for (int ni = 0; ni < 16; ni++) {
        float e0 = __expf(acc[ni][0] - mxv);
        float e1 = __expf(acc[ni][1] - mxv);
        float e2 = __expf(acc[ni][2] - mxv);
        float e3 = __expf(acc[ni][3] - mxv);
        sum += (e0 + e1) + (e2 + e3);
        asm("v_cvt_pk_bf16_f32 %0, %1, %2" : "=v"(dwA[ni]) : "v"(e0), "v"(e1));
        asm("v_cvt_pk_bf16_f32 %0, %1, %2" : "=v"(dwB[ni]) : "v"(e2), "v"(e3));
    }
    sum += __shfl_xor(sum, 16);
    sum += __shfl_xor(sum, 32);

    // ---- PV: pf assembled via shfl exchange ----
    int src0 = ((g & 1) << 5) + lm;
    int src1 = src0 + 16;
    bool sel = (g >> 1) != 0;
    const unsigned short* vb0 = vbf + ((long long)pb * 128 + h * 32 + lm) * 256
                                + 8 * g;
    f32x4 o0 = zero, o1 = zero;
#pragma unroll
    for (int st = 0; st < 8; st++) {
        unsigned d0a = __shfl(dwA[2 * st], src0), d0b = __shfl(dwA[2 * st + 1], src0);
        unsigned d1a = __shfl(dwB[2 * st], src0), d1b = __shfl(dwB[2 * st + 1], src0);
        unsigned d2a = __shfl(dwA[2 * st], src1), d2b = __shfl(dwA[2 * st + 1], src1);
        unsigned d3a = __shfl(dwB[2 * st], src1), d3b = __shfl(dwB[2 * st + 1], src1);
        union { unsigned u[4]; bf16x8 v; } pf;
        pf.u[0] = sel ? d0b : d0a;
        pf.u[1] = sel ? d1b : d1a;
        pf.u[2] = sel ? d2b : d2a;
        pf.u[3] = sel ? d3b : d3a;
        bf16x8 v0 = *(const bf16x8*)(vb0 + st * 32);
        bf16x8 v1 = *(const bf16x8*)(vb0 + 4096 + st * 32);
        __builtin_amdgcn_s_setprio(1);
        o0 = __builtin_amdgcn_mfma_f32_16x16x32_bf16(v0, pf.v, o0, 0, 0, 0);
        o1 = __builtin_amdgcn_mfma_f32_16x16x32_bf16(v1, pf.v, o1, 0, 0, 0);
        __builtin_amdgcn_s_setprio(0);
    }

    float inv = 1.f / sum;
    // ---- output: bf16 [m][c] via LDS bounce (reuse dead tab region) ----
    __syncthreads();                          // all tab/prm reads complete
    {
        unsigned short* rw = tab + wid * 640 + lm * 40;
        *(unsigned*)(rw + g * 4) =
            (unsigned)f2bf(o0[0] * inv) | ((unsigned)f2bf(o0[1] * inv) << 16);
        *(unsigned*)(rw + g * 4 + 2) =
            (unsigned)f2bf(o0[2] * inv) | ((unsigned)f2bf(o0[3] * inv) << 16);
        *(unsigned*)(rw + 16 + g * 4) =
            (unsigned)f2bf(o1[0] * inv) | ((unsigned)f2bf(o1[1] * inv) << 16);
        *(unsigned*)(rw + 16 + g * 4 + 2) =
            (unsigned)f2bf(o1[2] * inv) | ((unsigned)f2bf(o1[3] * inv) << 16);
    }
    int row = lane >> 2, cb = lane & 3;
    uint4 vv = *(const uint4*)(tab + wid * 640 + row * 40 + cb * 8);
    *(uint4*)(obf + ((long long)pb * HW + my * 64 + wid * 16 + row) * 128
              + h * 32 + cb * 8) = vv;
}

// ---------------------------------------------------------------------------
// K6) conv_wo via MFMA (bf16): out = x + sum_p Wo[p] o[p] + bo on chans
//     128:256 of vars 1,2. obf is bf16 [m][c]: contiguous 16B B-fragments.
__global__ __launch_bounds__(256) void conv_wo(const float* __restrict__ x1,
                                               const float* __restrict__ x2,
                                               const unsigned short* __restrict__ obf,
                                               const unsigned short* __restrict__ woh,
                                               const float* __restrict__ bo,
                                               float* __restrict__ out) {
    int wid = threadIdx.x >> 6, lane = threadIdx.x & 63;
    int g = lane >> 4, lm = lane & 15;
    int gw = blockIdx.x * 4 + wid;            // 2048 waves
    int mt = gw & 255;
    int b = (gw >> 8) & 3;
    int vs = gw >> 10;
    int m = mt * 16 + lm;
    int np = vs + 1;

    f32x4 acc[8];
#pragma unroll
    for (int ct = 0; ct < 8; ct++) acc[ct] = (f32x4){0.f, 0.f, 0.f, 0.f};

    for (int pi = 0; pi < np; pi++) {
        int p = vs ? (1 + pi) : 0;
        const unsigned short* Om = obf + ((long long)(p * 4 + b) * HW + m) * 128;
        const unsigned short* WH = woh + p * 16384;
#pragma unroll
        for (int ksl = 0; ksl < 4; ksl++) {
            bf16x8 bh = *(const bf16x8*)(Om + ksl * 32 + 8 * g);
#pragma unroll
            for (int ct = 0; ct < 8; ct++) {
                bf16x8 A = *(const bf16x8*)(WH + (ct * 16 + lm) * 128 + ksl * 32 + 8 * g);
                acc[ct] = __builtin_amdgcn_mfma_f32_16x16x32_bf16(A, bh, acc[ct], 0, 0, 0);
            }
        }
    }

    int qi = vs + 1;
    const float* xq = (vs ? x2 : x1) + (long long)b * CC * HW;
#pragma unroll
    for (int ct = 0; ct < 8; ct++)
#pragma unroll
        for (int r = 0; r < 4; r++) {
            int c = ct * 16 + 4 * g + r;
            float bias = vs ? (bo[128 + c] + bo[256 + c]) : bo[c];
            float base = xq[(long long)(128 + c) * HW + m];
            out[(((long long)(qi * 4 + b)) * CC + 128 + c) * HW + m]
                = base + acc[ct][r] + bias;
        }
}

// ---------------------------------------------------------------------------
extern "C" void kernel_launch(void* const* d_in, const int* in_sizes, int n_in,
                              void* d_out, int out_size, void* d_ws, size_t ws_size,
                              hipStream_t stream) {
    const float* x0 = (const float*)d_in[0];
    const float* x1 = (const float*)d_in[1];
    const float* x2 = (const float*)d_in[2];
    const float* Wq = (const float*)d_in[3];
    const float* bq = (const float*)d_in[4];
    const float* Wk = (const float*)d_in[5];
    const float* bk = (const float*)d_in[6];
    const float* Wv = (const float*)d_in[7];
    const float* bv = (const float*)d_in[8];
    const float* Wo = (const float*)d_in[9];
    const float* bo = (const float*)d_in[10];
    const float* dw_w = (const float*)d_in[11];
    const float* dw_b = (const float*)d_in[12];
    const float* ln_g = (const float*)d_in[13];
    const float* ln_b = (const float*)d_in[14];
    const float* pw_w = (const float*)d_in[15];
    const float* rpe = (const float*)d_in[16];
    float* out = (float*)d_out;

    // Workspace. obf bf16 at ws start (qbuf f32 removed entirely).
    float* ws = (float*)d_ws;
    unsigned short* obf = (unsigned short*)ws;               // 6291456 s (12 MB)
    float* posb = ws + 6291456;                              // 6144 f
    unsigned short* xT = (unsigned short*)(posb + 6144);     // 4194304 s (8 MB)
    unsigned short* qbf = xT + 4194304;                      // 12582912 s (24 MB)
    unsigned short* kbf = qbf + 12582912;                    // 393216 s
    unsigned short* vbf = kbf + 393216;                      // 393216 s
    unsigned short* tabbf = vbf + 393216;                    // 196608 s
    uint4* prmb = (uint4*)(tabbf + 196608);                  // 3072 uint4
    unsigned short* wqh = (unsigned short*)(prmb + 3072);    // 49152 s
    unsigned short* woh = wqh + 49152;
    unsigned short* wkh = woh + 49152;
    unsigned short* wvh = wkh + 49152;

    prep_copy<<<1048, 256, 0, stream>>>(rpe, Wq, Wo, Wk, Wv, x0, tabbf,
                                        wqh, woh, wkh, wvh, out);
    conv_q<<<512, 256, 0, stream>>>(x1, x2, wqh, bq, qbf, out);
    mid_kernel<<<2240, 256, 0, stream>>>(qbf, dw_w, dw_b, ln_g, ln_b, pw_w,
                                         x0, x1, posb, prmb, xT);
    sample_kv<<<96, 256, 0, stream>>>(xT, posb, wkh, wvh, bk, bv, kbf, vbf);
    attn_mfma<<<3072, 256, 0, stream>>>(qbf, kbf, vbf, tabbf, prmb, obf);
    conv_wo<<<512, 256, 0, stream>>>(x1, x2, obf, woh, bo, out);
}

// Round 17
// 161.509 us; speedup vs baseline: 3.1267x; 1.0101x over previous
//
#include <hip/hip_runtime.h>
#include <math.h>

// Problem constants
#define NVAR 3
#define BB 4
#define CC 256
#define C1 128
#define HEADS 4
#define HH 64
#define WW 64
#define HW 4096
#define RPE_W 127
#define NP 3
#define SCALE 0.17677669529663687f
// pairs: p=0 -> (i=1,j=0), p=1 -> (i=2,j=0), p=2 -> (i=2,j=1)

typedef short bf16x8 __attribute__((ext_vector_type(8)));
typedef float f32x4 __attribute__((ext_vector_type(4)));
typedef __bf16 bf16x2 __attribute__((ext_vector_type(2)));

__device__ __forceinline__ unsigned short f2bf(float f) {
    unsigned int u = __float_as_uint(f);
    u += 0x7fffu + ((u >> 16) & 1u);          // round-to-nearest-even
    return (unsigned short)(u >> 16);
}
__device__ __forceinline__ float bflo(unsigned u) { return __uint_as_float(u << 16); }
__device__ __forceinline__ float bfhi(unsigned u) { return __uint_as_float(u & 0xffff0000u); }

// packed bf16x2 dot: c + a.lo*b.lo + a.hi*b.hi
__device__ __forceinline__ float dot2bf(unsigned a, unsigned b, float c) {
#if __has_builtin(__builtin_amdgcn_fdot2_f32_bf16)
    return __builtin_amdgcn_fdot2_f32_bf16(__builtin_bit_cast(bf16x2, a),
                                           __builtin_bit_cast(bf16x2, b), c, false);
#else
    return c + bflo(a) * bflo(b) + bfhi(a) * bfhi(b);
#endif
}

// ---------------------------------------------------------------------------
// K1) const prep (blocks 0..23) + copy x0 -> out var0 + flow zeros (24..1047)
__global__ __launch_bounds__(256) void prep_copy(const float* __restrict__ rpe,
                                                 const float* __restrict__ Wq,
                                                 const float* __restrict__ Wo,
                                                 const float* __restrict__ Wk,
                                                 const float* __restrict__ Wv,
                                                 const float* __restrict__ x0,
                                                 unsigned short* __restrict__ tabbf,
                                                 unsigned short* __restrict__ wqh,
                                                 unsigned short* __restrict__ woh,
                                                 unsigned short* __restrict__ wkh,
                                                 unsigned short* __restrict__ wvh,
                                                 float* __restrict__ out) {
    int blk = blockIdx.x;
    if (blk >= 24) {
        const long long n4 = (long long)BB * CC * HW / 4;
        long long i = (long long)(blk - 24) * 256 + threadIdx.x;
        const long long stride = 1024LL * 256;
        for (; i < n4 + 12; i += stride) {
            if (i < n4) ((float4*)out)[i] = ((const float4*)x0)[i];
            else out[3LL * BB * CC * HW + (i - n4)] = 0.f;
        }
        return;
    }
    if (blk < 12) {
        const float* src = rpe + (long long)blk * RPE_W * RPE_W;
        unsigned short* dst = tabbf + (long long)blk * 16384;
        for (int idx = threadIdx.x; idx < 16384; idx += 256) {
            int y = idx >> 7, x = idx & 127;
            float v = (y < RPE_W && x < RPE_W) ? src[y * RPE_W + x] : 0.f;
            dst[idx] = f2bf(v);
        }
    } else if (blk < 15) {
        int p = blk - 12;
        for (int i = threadIdx.x; i < 16384; i += 256)
            wqh[p * 16384 + i] = f2bf(Wq[p * 16384 + i]);
    } else if (blk < 18) {
        int p = blk - 15;
        for (int i = threadIdx.x; i < 16384; i += 256)
            woh[p * 16384 + i] = f2bf(Wo[p * 16384 + i]);
    } else if (blk < 21) {
        int p = blk - 18;
        for (int i = threadIdx.x; i < 16384; i += 256)
            wkh[p * 16384 + i] = f2bf(Wk[p * 16384 + i]);
    } else {
        int p = blk - 21;
        for (int i = threadIdx.x; i < 16384; i += 256)
            wvh[p * 16384 + i] = f2bf(Wv[p * 16384 + i]);
    }
}

// ---------------------------------------------------------------------------
// K2) conv_q via MFMA (single bf16). Writes qbf bf16 [pb][m][c] (pre-scaled,
//     coalesced via LDS bounce) AND copies x chans 0:128 into out.
//     Waves with pbi>=4 compute BOTH p=1 and p=2 (shared x2 B-fragments).
__global__ __launch_bounds__(256) void conv_q(const float* __restrict__ x1,
                                              const float* __restrict__ x2,
                                              const unsigned short* __restrict__ wqh,
                                              const float* __restrict__ bq,
                                              unsigned short* __restrict__ qbf,
                                              float* __restrict__ out) {
    __shared__ unsigned short qlds[4][16][136];   // 17 KB; 16B-aligned rows
    int wid = threadIdx.x >> 6, lane = threadIdx.x & 63;
    int g = lane >> 4, lm = lane & 15;
    int gw = blockIdx.x * 4 + wid;            // 2048 waves
    int mt = gw & 255;
    int pbi = gw >> 8;                        // 0..7
    int merged = pbi >> 2;                    // 0: p=0 (x1); 1: p=1&2 (x2)
    int b = pbi & 3;
    const float* X = (merged ? x2 : x1) + (long long)b * CC * HW;
    int m = mt * 16 + lm;
    int qi = merged + 1;
    float* outc = out + (((long long)(qi * 4 + b)) * CC) * HW + m;

    // B fragments (bf16) + copy chans 0:128 to out
    bf16x8 bh[4];
#pragma unroll
    for (int ksl = 0; ksl < 4; ksl++) {
        float v[8];
#pragma unroll
        for (int j = 0; j < 8; j++) {
            int k = ksl * 32 + 8 * g + j;
            v[j] = X[(long long)k * HW + m];
            outc[(long long)k * HW] = v[j];
        }
        union { unsigned u[4]; bf16x8 v; } H;
#pragma unroll
        for (int t = 0; t < 4; t++)
            H.u[t] = (unsigned)f2bf(v[2 * t]) | ((unsigned)f2bf(v[2 * t + 1]) << 16);
        bh[ksl] = H.v;
    }

    f32x4 zero = {0.f, 0.f, 0.f, 0.f};
    unsigned short* ql = &qlds[wid][lm][0];
    int qq = lane >> 4, cg = lane & 15;

    for (int rep = 0; rep <= merged; rep++) {
        int p = merged ? (1 + rep) : 0;
        int pb = p * 4 + b;
        const unsigned short* WH = wqh + p * 16384;
#pragma unroll
        for (int ct2 = 0; ct2 < 4; ct2++) {
            int ct0 = 2 * ct2, ct1 = ct0 + 1;
            f32x4 a0 = zero, a1 = zero;
#pragma unroll
            for (int ksl = 0; ksl < 4; ksl++) {
                bf16x8 Ah0 = *(const bf16x8*)(WH + (ct0 * 16 + lm) * 128 + ksl * 32 + 8 * g);
                bf16x8 Ah1 = *(const bf16x8*)(WH + (ct1 * 16 + lm) * 128 + ksl * 32 + 8 * g);
                a0 = __builtin_amdgcn_mfma_f32_16x16x32_bf16(Ah0, bh[ksl], a0, 0, 0, 0);
                a1 = __builtin_amdgcn_mfma_f32_16x16x32_bf16(Ah1, bh[ksl], a1, 0, 0, 0);
            }
            float q0[4], q1[4];
#pragma unroll
            for (int r = 0; r < 4; r++) {
                q0[r] = a0[r] + bq[p * 128 + ct0 * 16 + 4 * g + r];
                q1[r] = a1[r] + bq[p * 128 + ct1 * 16 + 4 * g + r];
            }
            *(unsigned*)(ql + ct0 * 16 + 4 * g) =
                (unsigned)f2bf(q0[0] * SCALE) | ((unsigned)f2bf(q0[1] * SCALE) << 16);
            *(unsigned*)(ql + ct0 * 16 + 4 * g + 2) =
                (unsigned)f2bf(q0[2] * SCALE) | ((unsigned)f2bf(q0[3] * SCALE) << 16);
            *(unsigned*)(ql + ct1 * 16 + 4 * g) =
                (unsigned)f2bf(q1[0] * SCALE) | ((unsigned)f2bf(q1[1] * SCALE) << 16);
            *(unsigned*)(ql + ct1 * 16 + 4 * g + 2) =
                (unsigned)f2bf(q1[2] * SCALE) | ((unsigned)f2bf(q1[3] * SCALE) << 16);
        }
        // same-wave LDS readback -> coalesced 1KB-contiguous stores
        unsigned short* Yb = qbf + ((long long)pb * HW + mt * 16) * 128;
#pragma unroll
        for (int i = 0; i < 4; i++) {
            int row = i * 4 + qq;
            uint4 vv = *(const uint4*)&qlds[wid][row][cg * 8];
            *(uint4*)(Yb + row * 128 + cg * 8) = vv;
        }
    }
}

// ---------------------------------------------------------------------------
// K3) fused middle kernel:
//   blocks 0..191:  offset net from qbf (bf16, pre-scaled; 1/SCALE folded into
//                   the depthwise weights) -> LN -> GELU -> 1x1 -> pos + prm.
//   blocks 192..2239: transpose x0,x1 chans 0:128 -> xT bf16 [v][b][m][c].
__global__ __launch_bounds__(256) void mid_kernel(const unsigned short* __restrict__ qbf,
                                                  const float* __restrict__ dw_w,
                                                  const float* __restrict__ dw_b,
                                                  const float* __restrict__ ln_g,
                                                  const float* __restrict__ ln_b,
                                                  const float* __restrict__ pw_w,
                                                  const float* __restrict__ x0,
                                                  const float* __restrict__ x1,
                                                  float* __restrict__ posb,
                                                  uint4* __restrict__ prmb,
                                                  unsigned short* __restrict__ xT) {
    __shared__ char sm[40960];                // 40 KB (qs 32K + dwout 8K)
    int blk = blockIdx.x;
    int tid = threadIdx.x;
    if (blk < 192) {
        unsigned short* qs = (unsigned short*)sm;            // 32 KB: 128m x 128c
        float (*dwout)[128] = (float(*)[128])(sm + 32768);   // 8 KB
        int pb = blk >> 4, hk = blk & 15;
        int p = pb >> 2;
        int c = tid & 127;
        int wk0 = tid >> 7;
        const float* dwp_g = dw_w + (p * 128 + c) * 16;
        float dwp[16];
#pragma unroll
        for (int j = 0; j < 16; j++) dwp[j] = dwp_g[j] * (1.f / SCALE);
        float acc[8];
#pragma unroll
        for (int o = 0; o < 8; o++) acc[o] = dw_b[p * 128 + c];
        const unsigned short* Q = qbf + ((long long)pb * HW + hk * 256) * 128;
        for (int pass = 0; pass < 2; pass++) {
            __syncthreads();
#pragma unroll
            for (int it = 0; it < 8; it++) {
                int idx = tid + it * 256;          // 2048 uint4
                int mloc = idx >> 4, cg = idx & 15;
                *(uint4*)(qs + mloc * 128 + cg * 8) =
                    *(const uint4*)(Q + (long long)(pass * 128 + mloc) * 128 + cg * 8);
            }
            __syncthreads();
#pragma unroll
            for (int o = 0; o < 8; o++) {
                int wk = wk0 + o * 2;
                float a = acc[o];
#pragma unroll
                for (int kyl = 0; kyl < 2; kyl++)
#pragma unroll
                    for (int kx = 0; kx < 4; kx++)
                        a += bflo((unsigned)qs[(kyl * 64 + wk * 4 + kx) * 128 + c])
                             * dwp[(pass * 2 + kyl) * 4 + kx];
                acc[o] = a;
            }
        }
        __syncthreads();
#pragma unroll
        for (int o = 0; o < 8; o++) dwout[wk0 + o * 2][c] = acc[o];
        __syncthreads();
        // LN phase: 4 waves x 4 wk each
        int wid = tid >> 6, lane = tid & 63;
        for (int i = 0; i < 4; i++) {
            int wk = wid * 4 + i;
            int s = hk * 16 + wk;
            float a0 = dwout[wk][lane], a1 = dwout[wk][lane + 64];
            float s1 = a0 + a1;
#pragma unroll
            for (int o = 1; o < 64; o <<= 1) s1 += __shfl_xor(s1, o);
            float mu = s1 * (1.f / 128.f);
            float d0 = a0 - mu, d1 = a1 - mu;
            float v2 = d0 * d0 + d1 * d1;
#pragma unroll
            for (int o = 1; o < 64; o <<= 1) v2 += __shfl_xor(v2, o);
            float rs = rsqrtf(v2 * (1.f / 128.f) + 1e-5f);
            int c0 = lane, c1 = lane + 64;
            float y0 = d0 * rs * ln_g[p * 128 + c0] + ln_b[p * 128 + c0];
            float y1 = d1 * rs * ln_g[p * 128 + c1] + ln_b[p * 128 + c1];
            float g0 = 0.5f * y0 * (1.f + erff(y0 * 0.70710678118654752f));
            float g1 = 0.5f * y1 * (1.f + erff(y1 * 0.70710678118654752f));
            float o0 = pw_w[(p * 2 + 0) * 128 + c0] * g0
                     + pw_w[(p * 2 + 0) * 128 + c1] * g1;
            float o1 = pw_w[(p * 2 + 1) * 128 + c0] * g0
                     + pw_w[(p * 2 + 1) * 128 + c1] * g1;
#pragma unroll
            for (int o = 1; o < 64; o <<= 1) o0 += __shfl_xor(o0, o);
#pragma unroll
            for (int o = 1; o < 64; o <<= 1) o1 += __shfl_xor(o1, o);
            if (lane == 0) {
                int wk2 = s & 15;
                float refy = (hk + 0.5f) * (2.f / 15.f) - 1.f;
                float refx = (wk2 + 0.5f) * (2.f / 15.f) - 1.f;
                float py = fminf(fmaxf(o0 + refy, -1.f), 1.f);
                float px = fminf(fmaxf(o1 + refx, -1.f), 1.f);
                int pbn = pb * 256 + s;
                posb[pbn * 2 + 0] = py;
                posb[pbn * 2 + 1] = px;
                float cy = 31.5f * (1.f - py), cx = 31.5f * (1.f - px);
                float yf = floorf(cy), xf = floorf(cx);
                float wy = cy - yf, wx = cx - xf;
                int Y0 = (int)yf, X0 = (int)xf;
                uint4 v;
                v.x = (unsigned)f2bf((1.f - wy) * (1.f - wx))
                    | ((unsigned)f2bf((1.f - wy) * wx) << 16);
                v.y = (unsigned)f2bf(wy * (1.f - wx))
                    | ((unsigned)f2bf(wy * wx) << 16);
                v.z = (unsigned)((Y0 * 128 + X0) * 2);
                v.w = 0;
                prmb[pbn] = v;
            }
        }
    } else {
        // transpose part
        float (*ld2)[65] = (float(*)[65])sm;
        int rem = blk - 192;                  // 0..2047
        int v = rem >> 10;
        int rem1 = rem & 1023;
        int b = rem1 >> 8;
        int rem2 = rem1 & 255;
        int ct = rem2 >> 6;
        int mt = rem2 & 63;
        const float* src = ((v == 0) ? x0 : x1) + (long long)b * CC * HW
                           + (long long)(ct * 32) * HW + mt * 64;
#pragma unroll
        for (int it = 0; it < 2; it++) {
            int c = tid >> 3, x4 = (tid & 7) + it * 8;
            float4 w = *(const float4*)(src + (long long)c * HW + x4 * 4);
            ld2[c][x4 * 4 + 0] = w.x;
            ld2[c][x4 * 4 + 1] = w.y;
            ld2[c][x4 * 4 + 2] = w.z;
            ld2[c][x4 * 4 + 3] = w.w;
        }
        __syncthreads();
        int m = tid >> 2, cg = tid & 3;
        union { unsigned u[4]; } pk;
#pragma unroll
        for (int t = 0; t < 4; t++) {
            unsigned short h0 = f2bf(ld2[cg * 8 + 2 * t][m]);
            unsigned short h1 = f2bf(ld2[cg * 8 + 2 * t + 1][m]);
            pk.u[t] = (unsigned)h0 | ((unsigned)h1 << 16);
        }
        *(uint4*)(xT + (((long long)(v * 4 + b)) * HW + mt * 64 + m) * 128
                  + ct * 32 + cg * 8) = *(uint4*)pk.u;
    }
}

// ---------------------------------------------------------------------------
// K4) fused sample + K/V conv (MFMA), clamped-base bilinear (NaN-safe).
__global__ __launch_bounds__(256) void sample_kv(const unsigned short* __restrict__ xT,
                                                 const float* __restrict__ posb,
                                                 const unsigned short* __restrict__ wkh,
                                                 const unsigned short* __restrict__ wvh,
                                                 const float* __restrict__ bk,
                                                 const float* __restrict__ bv,
                                                 unsigned short* __restrict__ kbf,
                                                 unsigned short* __restrict__ vbf) {
    __shared__ unsigned short xls[32 * 128];      // 8 KB, XOR-swizzled rows
    int blk = blockIdx.x;                 // 96
    int pb = blk >> 3;
    int nt = blk & 7;
    int p = pb >> 2, b = pb & 3;
    int n0 = nt * 32;
    int tid = threadIdx.x;

    {
        int nl = tid >> 3, co = tid & 7;
        int n = n0 + nl;
        float py = posb[(pb * 256 + n) * 2 + 0];
        float px = posb[(pb * 256 + n) * 2 + 1];
        float yi = (py + 1.f) * 31.5f, xi = (px + 1.f) * 31.5f;
        yi = fminf(fmaxf(yi, 0.f), 63.f);
        xi = fminf(fmaxf(xi, 0.f), 63.f);
        int y0 = min((int)yi, 62);
        int x0i = min((int)xi, 62);
        float wy = yi - (float)y0, wx = xi - (float)x0i;
        float w00 = (1.f - wy) * (1.f - wx), w01 = (1.f - wy) * wx;
        float w10 = wy * (1.f - wx), w11 = wy * wx;
        int vsel = (p == 2) ? 1 : 0;
        const unsigned short* base = xT + ((long long)(vsel * 4 + b)) * HW * 128;
        int m00 = y0 * 64 + x0i;
        char* dst = (char*)xls;
#pragma unroll
        for (int cb = 0; cb < 2; cb++) {
            int c0 = co * 16 + cb * 8;
            bf16x8 a = *(const bf16x8*)(base + (long long)m00 * 128 + c0);
            bf16x8 bb = *(const bf16x8*)(base + (long long)(m00 + 1) * 128 + c0);
            bf16x8 cc = *(const bf16x8*)(base + (long long)(m00 + 64) * 128 + c0);
            bf16x8 dd = *(const bf16x8*)(base + (long long)(m00 + 65) * 128 + c0);
            union { unsigned u[4]; bf16x8 v; } R;
#pragma unroll
            for (int t = 0; t < 4; t++) {
                float r0 = w00 * bflo((unsigned)(unsigned short)a[2 * t])
                         + w01 * bflo((unsigned)(unsigned short)bb[2 * t])
                         + w10 * bflo((unsigned)(unsigned short)cc[2 * t])
                         + w11 * bflo((unsigned)(unsigned short)dd[2 * t]);
                float r1 = w00 * bflo((unsigned)(unsigned short)a[2 * t + 1])
                         + w01 * bflo((unsigned)(unsigned short)bb[2 * t + 1])
                         + w10 * bflo((unsigned)(unsigned short)cc[2 * t + 1])
                         + w11 * bflo((unsigned)(unsigned short)dd[2 * t + 1]);
                R.u[t] = (unsigned)f2bf(r0) | ((unsigned)f2bf(r1) << 16);
            }
            *(bf16x8*)(dst + ((nl * 256 + c0 * 2) ^ ((nl & 7) << 4))) = R.v;
        }
    }
    __syncthreads();

    int wid = tid >> 6, lane = tid & 63;
    int g = lane >> 4, lm = lane & 15;
    int ntile = wid & 1, isv = wid >> 1;
    int nl = ntile * 16 + lm;
    const char* srcl = (const char*)xls;
    bf16x8 xf[4];
#pragma unroll
    for (int ks = 0; ks < 4; ks++)
        xf[ks] = *(const bf16x8*)(srcl + ((nl * 256 + (ks * 32 + 8 * g) * 2)
                                          ^ ((nl & 7) << 4)));
    f32x4 zero = {0.f, 0.f, 0.f, 0.f};
    if (!isv) {
        const unsigned short* WK = wkh + p * 16384;
#pragma unroll
        for (int ct = 0; ct < 8; ct++) {
            f32x4 acc = zero;
#pragma unroll
            for (int ks = 0; ks < 4; ks++) {
                bf16x8 wf = *(const bf16x8*)(WK + (ct * 16 + lm) * 128 + ks * 32 + 8 * g);
                acc = __builtin_amdgcn_mfma_f32_16x16x32_bf16(xf[ks], wf, acc, 0, 0, 0);
            }
            float bias = bk[p * 128 + ct * 16 + lm];
#pragma unroll
            for (int r = 0; r < 4; r++) {
                int n = n0 + ntile * 16 + 4 * g + r;
                kbf[((long long)pb * 256 + n) * 128 + ct * 16 + lm] = f2bf(acc[r] + bias);
            }
        }
    } else {
        const unsigned short* WV = wvh + p * 16384;
#pragma unroll
        for (int ct = 0; ct < 8; ct++) {
            f32x4 acc = zero;
#pragma unroll
            for (int ks = 0; ks < 4; ks++) {
                bf16x8 wf = *(const bf16x8*)(WV + (ct * 16 + lm) * 128 + ks * 32 + 8 * g);
                acc = __builtin_amdgcn_mfma_f32_16x16x32_bf16(wf, xf[ks], acc, 0, 0, 0);
            }
#pragma unroll
            for (int r = 0; r < 4; r++) {
                int c = ct * 16 + 4 * g + r;
                vbf[((long long)pb * 128 + c) * 256 + n0 + ntile * 16 + lm]
                    = f2bf(acc[r] + bv[p * 128 + c]);
            }
        }
    }
}

// ---------------------------------------------------------------------------
// K5) MFMA attention v5: n SPLIT across wave pairs. 512 thr = 8 waves:
//     4 mx-quarters (mq) x 2 n-halves (nh). Per wave: 8 QK MFMA + 128 bias
//     gathers + 4 PV MFMA (half the R9 chain, ~half the register state).
//     Exact softmax via staged exchange in dead-tab LDS:
//       B0 (tab reads drained) -> max exch -> B1 -> e/lsum + sum exch + PV
//       -> O exch -> B2 -> nh=0 combines, scales, bf16 bounce store.
__global__ __launch_bounds__(512, 4) void attn_mfma(
        const unsigned short* __restrict__ qbf,
        const unsigned short* __restrict__ kbf,
        const unsigned short* __restrict__ vbf,
        const unsigned short* __restrict__ tabbf,
        const uint4* __restrict__ prmb,
        unsigned short* __restrict__ obf) {
    __shared__ unsigned short tab[16384 + 8];   // +8: speculative dword pad
    __shared__ uint4 prm[256];
    int tid = threadIdx.x;
    int wid = tid >> 6, lane = tid & 63;
    int g = lane >> 4, lm = lane & 15;
    int nh = wid >> 2;                        // n-half
    int mq = wid & 3;                         // mx quarter
    int bid = blockIdx.x;                     // 3072
    int my = bid & 63;
    int h = (bid >> 6) & 3;
    int b = (bid >> 8) & 3;
    int p = bid >> 10;
    int pb = p * 4 + b;

    {   // stage table + params (512 threads)
        const uint4* ts = (const uint4*)(tabbf + (long long)(p * 4 + h) * 16384);
        uint4* td = (uint4*)tab;
#pragma unroll
        for (int i = 0; i < 4; i++) td[tid + i * 512] = ts[tid + i * 512];
        if (tid < 256) prm[tid] = prmb[pb * 256 + tid];
    }
    __syncthreads();

    int mx = (mq << 4) + lm;
    int nb = nh * 128;

    // ---- QK^T (swapped) for this wave's n-half ----
    bf16x8 qf = *(const bf16x8*)(qbf + ((long long)pb * HW + my * 64 + mx) * 128
                                 + h * 32 + 8 * g);
    const unsigned short* kbase = kbf + ((long long)pb * 256 + lm) * 128
                                  + h * 32 + 8 * g;
    f32x4 zero = {0.f, 0.f, 0.f, 0.f};
    f32x4 acc[8];
    __builtin_amdgcn_s_setprio(1);
#pragma unroll
    for (int ni = 0; ni < 8; ni++) {
        bf16x8 kf = *(const bf16x8*)(kbase + (nb + ni * 16) * 128);
        acc[ni] = __builtin_amdgcn_mfma_f32_16x16x32_bf16(kf, qf, zero, 0, 0, 0);
    }
    __builtin_amdgcn_s_setprio(0);

    // ---- RPE bias for this n-half ----
    int laneoff = (my * 128 + mx) * 2;
    const char* tb = (const char*)tab;
#pragma unroll
    for (int ni = 0; ni < 8; ni++) {
#pragma unroll
        for (int r = 0; r < 4; r++) {
            int n = nb + ni * 16 + 4 * g + r;
            uint4 pw = prm[n];
            int va = (int)pw.z + laneoff;
            int va4 = va & ~3;
            int sh = va & 3;
            unsigned r0 = *(const unsigned*)(tb + va4);
            unsigned r1 = *(const unsigned*)(tb + va4 + 4);
            unsigned r2 = *(const unsigned*)(tb + va4 + 256);
            unsigned r3 = *(const unsigned*)(tb + va4 + 260);
            unsigned p0 = __builtin_amdgcn_alignbyte(r1, r0, sh);
            unsigned p1 = __builtin_amdgcn_alignbyte(r3, r2, sh);
            float t = acc[ni][r];
            t = dot2bf(p0, pw.x, t);
            t = dot2bf(p1, pw.y, t);
            acc[ni][r] = t;
        }
    }

    // ---- local max over this half ----
    float mloc = -1e30f;
#pragma unroll
    for (int ni = 0; ni < 8; ni++)
        mloc = fmaxf(mloc, fmaxf(fmaxf(acc[ni][0], acc[ni][1]),
                                 fmaxf(acc[ni][2], acc[ni][3])));
    mloc = fmaxf(mloc, __shfl_xor(mloc, 16));
    mloc = fmaxf(mloc, __shfl_xor(mloc, 32));

    // exchange buffers live in the (now dead) tab region, AFTER B0 drains all
    // bias reads block-wide.
    float* mex = (float*)tab;                 // [2][64]
    float* sex = (float*)tab + 128;           // [2][64]
    float* oex = (float*)tab + 256;           // [4 mq][64 lane][8]
    __syncthreads();                          // B0: all tab reads complete
    if (g == 0) mex[nh * 64 + mx] = mloc;
    __syncthreads();                          // B1
    float mglob = fmaxf(mex[mx], mex[64 + mx]);

    // ---- e, local sum, pack ----
    float lsum = 0.f;
    unsigned dwA[8], dwB[8];
#pragma unroll
    for (int ni = 0; ni < 8; ni++) {
        float e0 = __expf(acc[ni][0] - mglob);
        float e1 = __expf(acc[ni][1] - mglob);
        float e2 = __expf(acc[ni][2] - mglob);
        float e3 = __expf(acc[ni][3] - mglob);
        lsum += (e0 + e1) + (e2 + e3);
        asm("v_cvt_pk_bf16_f32 %0, %1, %2" : "=v"(dwA[ni]) : "v"(e0), "v"(e1));
        asm("v_cvt_pk_bf16_f32 %0, %1, %2" : "=v"(dwB[ni]) : "v"(e2), "v"(e3));
    }
    lsum += __shfl_xor(lsum, 16);
    lsum += __shfl_xor(lsum, 32);
    if (g == 0) sex[nh * 64 + mx] = lsum;

    // ---- PV for this n-half ----
    int src0 = ((g & 1) << 5) + lm;
    int src1 = src0 + 16;
    bool sel = (g >> 1) != 0;
    const unsigned short* vb0 = vbf + ((long long)pb * 128 + h * 32 + lm) * 256
                                + 8 * g + nb;
    f32x4 o0 = zero, o1 = zero;
#pragma unroll
    for (int st = 0; st < 4; st++) {
        unsigned d0a = __shfl(dwA[2 * st], src0), d0b = __shfl(dwA[2 * st + 1], src0);
        unsigned d1a = __shfl(dwB[2 * st], src0), d1b = __shfl(dwB[2 * st + 1], src0);
        unsigned d2a = __shfl(dwA[2 * st], src1), d2b = __shfl(dwA[2 * st + 1], src1);
        unsigned d3a = __shfl(dwB[2 * st], src1), d3b = __shfl(dwB[2 * st + 1], src1);
        union { unsigned u[4]; bf16x8 v; } pf;
        pf.u[0] = sel ? d0b : d0a;
        pf.u[1] = sel ? d1b : d1a;
        pf.u[2] = sel ? d2b : d2a;
        pf.u[3] = sel ? d3b : d3a;
        bf16x8 v0 = *(const bf16x8*)(vb0 + st * 32);
        bf16x8 v1 = *(const bf16x8*)(vb0 + 4096 + st * 32);
        __builtin_amdgcn_s_setprio(1);
        o0 = __builtin_amdgcn_mfma_f32_16x16x32_bf16(v0, pf.v, o0, 0, 0, 0);
        o1 = __builtin_amdgcn_mfma_f32_16x16x32_bf16(v1, pf.v, o1, 0, 0, 0);
        __builtin_amdgcn_s_setprio(0);
    }

    // ---- combine halves ----
    if (nh == 1) {
        float* od = oex + (mq * 64 + lane) * 8;
#pragma unroll
        for (int r = 0; r < 4; r++) { od[r] = o0[r]; od[4 + r] = o1[r]; }
    }
    __syncthreads();                          // B2
    if (nh == 1) return;

    const float* os = oex + (mq * 64 + lane) * 8;
#pragma unroll
    for (int r = 0; r < 4; r++) { o0[r] += os[r]; o1[r] += os[4 + r]; }
    float inv = 1.f / (sex[mx] + sex[64 + mx]);

    // ---- output: bf16 [m][c] via LDS bounce (region disjoint from oex) ----
    unsigned short* bounce = tab + 6144;      // 12 KB offset (shorts)
    {
        unsigned short* rw = bounce + mq * 640 + lm * 40;
        *(unsigned*)(rw + g * 4) =
            (unsigned)f2bf(o0[0] * inv) | ((unsigned)f2bf(o0[1] * inv) << 16);
        *(unsigned*)(rw + g * 4 + 2) =
            (unsigned)f2bf(o0[2] * inv) | ((unsigned)f2bf(o0[3] * inv) << 16);
        *(unsigned*)(rw + 16 + g * 4) =
            (unsigned)f2bf(o1[0] * inv) | ((unsigned)f2bf(o1[1] * inv) << 16);
        *(unsigned*)(rw + 16 + g * 4 + 2) =
            (unsigned)f2bf(o1[2] * inv) | ((unsigned)f2bf(o1[3] * inv) << 16);
    }
    int row = lane >> 2, cb = lane & 3;
    uint4 vv = *(const uint4*)(bounce + mq * 640 + row * 40 + cb * 8);
    *(uint4*)(obf + ((long long)pb * HW + my * 64 + mq * 16 + row) * 128
              + h * 32 + cb * 8) = vv;
}

// ---------------------------------------------------------------------------
// K6) conv_wo via MFMA (bf16): out = x + sum_p Wo[p] o[p] + bo on chans
//     128:256 of vars 1,2. obf is bf16 [m][c]: contiguous 16B B-fragments.
__global__ __launch_bounds__(256) void conv_wo(const float* __restrict__ x1,
                                               const float* __restrict__ x2,
                                               const unsigned short* __restrict__ obf,
                                               const unsigned short* __restrict__ woh,
                                               const float* __restrict__ bo,
                                               float* __restrict__ out) {
    int wid = threadIdx.x >> 6, lane = threadIdx.x & 63;
    int g = lane >> 4, lm = lane & 15;
    int gw = blockIdx.x * 4 + wid;            // 2048 waves
    int mt = gw & 255;
    int b = (gw >> 8) & 3;
    int vs = gw >> 10;
    int m = mt * 16 + lm;
    int np = vs + 1;

    f32x4 acc[8];
#pragma unroll
    for (int ct = 0; ct < 8; ct++) acc[ct] = (f32x4){0.f, 0.f, 0.f, 0.f};

    for (int pi = 0; pi < np; pi++) {
        int p = vs ? (1 + pi) : 0;
        const unsigned short* Om = obf + ((long long)(p * 4 + b) * HW + m) * 128;
        const unsigned short* WH = woh + p * 16384;
#pragma unroll
        for (int ksl = 0; ksl < 4; ksl++) {
            bf16x8 bh = *(const bf16x8*)(Om + ksl * 32 + 8 * g);
#pragma unroll
            for (int ct = 0; ct < 8; ct++) {
                bf16x8 A = *(const bf16x8*)(WH + (ct * 16 + lm) * 128 + ksl * 32 + 8 * g);
                acc[ct] = __builtin_amdgcn_mfma_f32_16x16x32_bf16(A, bh, acc[ct], 0, 0, 0);
            }
        }
    }

    int qi = vs + 1;
    const float* xq = (vs ? x2 : x1) + (long long)b * CC * HW;
#pragma unroll
    for (int ct = 0; ct < 8; ct++)
#pragma unroll
        for (int r = 0; r < 4; r++) {
            int c = ct * 16 + 4 * g + r;
            float bias = vs ? (bo[128 + c] + bo[256 + c]) : bo[c];
            float base = xq[(long long)(128 + c) * HW + m];
            out[(((long long)(qi * 4 + b)) * CC + 128 + c) * HW + m]
                = base + acc[ct][r] + bias;
        }
}

// ---------------------------------------------------------------------------
extern "C" void kernel_launch(void* const* d_in, const int* in_sizes, int n_in,
                              void* d_out, int out_size, void* d_ws, size_t ws_size,
                              hipStream_t stream) {
    const float* x0 = (const float*)d_in[0];
    const float* x1 = (const float*)d_in[1];
    const float* x2 = (const float*)d_in[2];
    const float* Wq = (const float*)d_in[3];
    const float* bq = (const float*)d_in[4];
    const float* Wk = (const float*)d_in[5];
    const float* bk = (const float*)d_in[6];
    const float* Wv = (const float*)d_in[7];
    const float* bv = (const float*)d_in[8];
    const float* Wo = (const float*)d_in[9];
    const float* bo = (const float*)d_in[10];
    const float* dw_w = (const float*)d_in[11];
    const float* dw_b = (const float*)d_in[12];
    const float* ln_g = (const float*)d_in[13];
    const float* ln_b = (const float*)d_in[14];
    const float* pw_w = (const float*)d_in[15];
    const float* rpe = (const float*)d_in[16];
    float* out = (float*)d_out;

    // Workspace. obf bf16 at ws start.
    float* ws = (float*)d_ws;
    unsigned short* obf = (unsigned short*)ws;               // 6291456 s (12 MB)
    float* posb = ws + 6291456;                              // 6144 f
    unsigned short* xT = (unsigned short*)(posb + 6144);     // 4194304 s (8 MB)
    unsigned short* qbf = xT + 4194304;                      // 12582912 s (24 MB)
    unsigned short* kbf = qbf + 12582912;                    // 393216 s
    unsigned short* vbf = kbf + 393216;                      // 393216 s
    unsigned short* tabbf = vbf + 393216;                    // 196608 s
    uint4* prmb = (uint4*)(tabbf + 196608);                  // 3072 uint4
    unsigned short* wqh = (unsigned short*)(prmb + 3072);    // 49152 s
    unsigned short* woh = wqh + 49152;
    unsigned short* wkh = woh + 49152;
    unsigned short* wvh = wkh + 49152;

    prep_copy<<<1048, 256, 0, stream>>>(rpe, Wq, Wo, Wk, Wv, x0, tabbf,
                                        wqh, woh, wkh, wvh, out);
    conv_q<<<512, 256, 0, stream>>>(x1, x2, wqh, bq, qbf, out);
    mid_kernel<<<2240, 256, 0, stream>>>(qbf, dw_w, dw_b, ln_g, ln_b, pw_w,
                                         x0, x1, posb, prmb, xT);
    sample_kv<<<96, 256, 0, stream>>>(xT, posb, wkh, wvh, bk, bv, kbf, vbf);
    attn_mfma<<<3072, 512, 0, stream>>>(qbf, kbf, vbf, tabbf, prmb, obf);
    conv_wo<<<512, 256, 0, stream>>>(x1, x2, obf, woh, bo, out);
}

// Round 18
// 160.444 us; speedup vs baseline: 3.1475x; 1.0066x over previous
//
#include <hip/hip_runtime.h>
#include <math.h>

// Problem constants
#define NVAR 3
#define BB 4
#define CC 256
#define C1 128
#define HEADS 4
#define HH 64
#define WW 64
#define HW 4096
#define RPE_W 127
#define NP 3
#define SCALE 0.17677669529663687f
// pairs: p=0 -> (i=1,j=0), p=1 -> (i=2,j=0), p=2 -> (i=2,j=1)

typedef short bf16x8 __attribute__((ext_vector_type(8)));
typedef float f32x4 __attribute__((ext_vector_type(4)));
typedef __bf16 bf16x2 __attribute__((ext_vector_type(2)));

__device__ __forceinline__ unsigned short f2bf(float f) {
    unsigned int u = __float_as_uint(f);
    u += 0x7fffu + ((u >> 16) & 1u);          // round-to-nearest-even
    return (unsigned short)(u >> 16);
}
__device__ __forceinline__ float bflo(unsigned u) { return __uint_as_float(u << 16); }
__device__ __forceinline__ float bfhi(unsigned u) { return __uint_as_float(u & 0xffff0000u); }

// packed bf16x2 dot: c + a.lo*b.lo + a.hi*b.hi
__device__ __forceinline__ float dot2bf(unsigned a, unsigned b, float c) {
#if __has_builtin(__builtin_amdgcn_fdot2_f32_bf16)
    return __builtin_amdgcn_fdot2_f32_bf16(__builtin_bit_cast(bf16x2, a),
                                           __builtin_bit_cast(bf16x2, b), c, false);
#else
    return c + bflo(a) * bflo(b) + bfhi(a) * bfhi(b);
#endif
}

// ---------------------------------------------------------------------------
// K1) const prep (blocks 0..23) + copy x0 -> out var0 + flow zeros (24..1047)
__global__ __launch_bounds__(256) void prep_copy(const float* __restrict__ rpe,
                                                 const float* __restrict__ Wq,
                                                 const float* __restrict__ Wo,
                                                 const float* __restrict__ Wk,
                                                 const float* __restrict__ Wv,
                                                 const float* __restrict__ x0,
                                                 unsigned short* __restrict__ tabbf,
                                                 unsigned short* __restrict__ wqh,
                                                 unsigned short* __restrict__ woh,
                                                 unsigned short* __restrict__ wkh,
                                                 unsigned short* __restrict__ wvh,
                                                 float* __restrict__ out) {
    int blk = blockIdx.x;
    if (blk >= 24) {
        const long long n4 = (long long)BB * CC * HW / 4;
        long long i = (long long)(blk - 24) * 256 + threadIdx.x;
        const long long stride = 1024LL * 256;
        for (; i < n4 + 12; i += stride) {
            if (i < n4) ((float4*)out)[i] = ((const float4*)x0)[i];
            else out[3LL * BB * CC * HW + (i - n4)] = 0.f;
        }
        return;
    }
    if (blk < 12) {
        const float* src = rpe + (long long)blk * RPE_W * RPE_W;
        unsigned short* dst = tabbf + (long long)blk * 16384;
        for (int idx = threadIdx.x; idx < 16384; idx += 256) {
            int y = idx >> 7, x = idx & 127;
            float v = (y < RPE_W && x < RPE_W) ? src[y * RPE_W + x] : 0.f;
            dst[idx] = f2bf(v);
        }
    } else if (blk < 15) {
        int p = blk - 12;
        for (int i = threadIdx.x; i < 16384; i += 256)
            wqh[p * 16384 + i] = f2bf(Wq[p * 16384 + i]);
    } else if (blk < 18) {
        int p = blk - 15;
        for (int i = threadIdx.x; i < 16384; i += 256)
            woh[p * 16384 + i] = f2bf(Wo[p * 16384 + i]);
    } else if (blk < 21) {
        int p = blk - 18;
        for (int i = threadIdx.x; i < 16384; i += 256)
            wkh[p * 16384 + i] = f2bf(Wk[p * 16384 + i]);
    } else {
        int p = blk - 21;
        for (int i = threadIdx.x; i < 16384; i += 256)
            wvh[p * 16384 + i] = f2bf(Wv[p * 16384 + i]);
    }
}

// ---------------------------------------------------------------------------
// K2) conv_q via MFMA (single bf16). Writes qbf bf16 [pb][m][c] (pre-scaled,
//     coalesced via LDS bounce) AND copies x chans 0:128 into out.
//     Waves with pbi>=4 compute BOTH p=1 and p=2 (shared x2 B-fragments).
__global__ __launch_bounds__(256) void conv_q(const float* __restrict__ x1,
                                              const float* __restrict__ x2,
                                              const unsigned short* __restrict__ wqh,
                                              const float* __restrict__ bq,
                                              unsigned short* __restrict__ qbf,
                                              float* __restrict__ out) {
    __shared__ unsigned short qlds[4][16][136];   // 17 KB; 16B-aligned rows
    int wid = threadIdx.x >> 6, lane = threadIdx.x & 63;
    int g = lane >> 4, lm = lane & 15;
    int gw = blockIdx.x * 4 + wid;            // 2048 waves
    int mt = gw & 255;
    int pbi = gw >> 8;                        // 0..7
    int merged = pbi >> 2;                    // 0: p=0 (x1); 1: p=1&2 (x2)
    int b = pbi & 3;
    const float* X = (merged ? x2 : x1) + (long long)b * CC * HW;
    int m = mt * 16 + lm;
    int qi = merged + 1;
    float* outc = out + (((long long)(qi * 4 + b)) * CC) * HW + m;

    // B fragments (bf16) + copy chans 0:128 to out
    bf16x8 bh[4];
#pragma unroll
    for (int ksl = 0; ksl < 4; ksl++) {
        float v[8];
#pragma unroll
        for (int j = 0; j < 8; j++) {
            int k = ksl * 32 + 8 * g + j;
            v[j] = X[(long long)k * HW + m];
            outc[(long long)k * HW] = v[j];
        }
        union { unsigned u[4]; bf16x8 v; } H;
#pragma unroll
        for (int t = 0; t < 4; t++)
            H.u[t] = (unsigned)f2bf(v[2 * t]) | ((unsigned)f2bf(v[2 * t + 1]) << 16);
        bh[ksl] = H.v;
    }

    f32x4 zero = {0.f, 0.f, 0.f, 0.f};
    unsigned short* ql = &qlds[wid][lm][0];
    int qq = lane >> 4, cg = lane & 15;

    for (int rep = 0; rep <= merged; rep++) {
        int p = merged ? (1 + rep) : 0;
        int pb = p * 4 + b;
        const unsigned short* WH = wqh + p * 16384;
#pragma unroll
        for (int ct2 = 0; ct2 < 4; ct2++) {
            int ct0 = 2 * ct2, ct1 = ct0 + 1;
            f32x4 a0 = zero, a1 = zero;
#pragma unroll
            for (int ksl = 0; ksl < 4; ksl++) {
                bf16x8 Ah0 = *(const bf16x8*)(WH + (ct0 * 16 + lm) * 128 + ksl * 32 + 8 * g);
                bf16x8 Ah1 = *(const bf16x8*)(WH + (ct1 * 16 + lm) * 128 + ksl * 32 + 8 * g);
                a0 = __builtin_amdgcn_mfma_f32_16x16x32_bf16(Ah0, bh[ksl], a0, 0, 0, 0);
                a1 = __builtin_amdgcn_mfma_f32_16x16x32_bf16(Ah1, bh[ksl], a1, 0, 0, 0);
            }
            float q0[4], q1[4];
#pragma unroll
            for (int r = 0; r < 4; r++) {
                q0[r] = a0[r] + bq[p * 128 + ct0 * 16 + 4 * g + r];
                q1[r] = a1[r] + bq[p * 128 + ct1 * 16 + 4 * g + r];
            }
            *(unsigned*)(ql + ct0 * 16 + 4 * g) =
                (unsigned)f2bf(q0[0] * SCALE) | ((unsigned)f2bf(q0[1] * SCALE) << 16);
            *(unsigned*)(ql + ct0 * 16 + 4 * g + 2) =
                (unsigned)f2bf(q0[2] * SCALE) | ((unsigned)f2bf(q0[3] * SCALE) << 16);
            *(unsigned*)(ql + ct1 * 16 + 4 * g) =
                (unsigned)f2bf(q1[0] * SCALE) | ((unsigned)f2bf(q1[1] * SCALE) << 16);
            *(unsigned*)(ql + ct1 * 16 + 4 * g + 2) =
                (unsigned)f2bf(q1[2] * SCALE) | ((unsigned)f2bf(q1[3] * SCALE) << 16);
        }
        // same-wave LDS readback -> coalesced 1KB-contiguous stores
        unsigned short* Yb = qbf + ((long long)pb * HW + mt * 16) * 128;
#pragma unroll
        for (int i = 0; i < 4; i++) {
            int row = i * 4 + qq;
            uint4 vv = *(const uint4*)&qlds[wid][row][cg * 8];
            *(uint4*)(Yb + row * 128 + cg * 8) = vv;
        }
    }
}

// ---------------------------------------------------------------------------
// K3) fused middle kernel:
//   blocks 0..191:  offset net from qbf (bf16, pre-scaled; 1/SCALE folded into
//                   the depthwise weights) -> LN -> GELU -> 1x1 -> pos + prm.
//   blocks 192..2239: transpose x0,x1 chans 0:128 -> xT bf16 [v][b][m][c].
__global__ __launch_bounds__(256) void mid_kernel(const unsigned short* __restrict__ qbf,
                                                  const float* __restrict__ dw_w,
                                                  const float* __restrict__ dw_b,
                                                  const float* __restrict__ ln_g,
                                                  const float* __restrict__ ln_b,
                                                  const float* __restrict__ pw_w,
                                                  const float* __restrict__ x0,
                                                  const float* __restrict__ x1,
                                                  float* __restrict__ posb,
                                                  uint4* __restrict__ prmb,
                                                  unsigned short* __restrict__ xT) {
    __shared__ char sm[40960];                // 40 KB (qs 32K + dwout 8K)
    int blk = blockIdx.x;
    int tid = threadIdx.x;
    if (blk < 192) {
        unsigned short* qs = (unsigned short*)sm;            // 32 KB: 128m x 128c
        float (*dwout)[128] = (float(*)[128])(sm + 32768);   // 8 KB
        int pb = blk >> 4, hk = blk & 15;
        int p = pb >> 2;
        int c = tid & 127;
        int wk0 = tid >> 7;
        const float* dwp_g = dw_w + (p * 128 + c) * 16;
        float dwp[16];
#pragma unroll
        for (int j = 0; j < 16; j++) dwp[j] = dwp_g[j] * (1.f / SCALE);
        float acc[8];
#pragma unroll
        for (int o = 0; o < 8; o++) acc[o] = dw_b[p * 128 + c];
        const unsigned short* Q = qbf + ((long long)pb * HW + hk * 256) * 128;
        for (int pass = 0; pass < 2; pass++) {
            __syncthreads();
#pragma unroll
            for (int it = 0; it < 8; it++) {
                int idx = tid + it * 256;          // 2048 uint4
                int mloc = idx >> 4, cg = idx & 15;
                *(uint4*)(qs + mloc * 128 + cg * 8) =
                    *(const uint4*)(Q + (long long)(pass * 128 + mloc) * 128 + cg * 8);
            }
            __syncthreads();
#pragma unroll
            for (int o = 0; o < 8; o++) {
                int wk = wk0 + o * 2;
                float a = acc[o];
#pragma unroll
                for (int kyl = 0; kyl < 2; kyl++)
#pragma unroll
                    for (int kx = 0; kx < 4; kx++)
                        a += bflo((unsigned)qs[(kyl * 64 + wk * 4 + kx) * 128 + c])
                             * dwp[(pass * 2 + kyl) * 4 + kx];
                acc[o] = a;
            }
        }
        __syncthreads();
#pragma unroll
        for (int o = 0; o < 8; o++) dwout[wk0 + o * 2][c] = acc[o];
        __syncthreads();
        // LN phase: 4 waves x 4 wk each
        int wid = tid >> 6, lane = tid & 63;
        for (int i = 0; i < 4; i++) {
            int wk = wid * 4 + i;
            int s = hk * 16 + wk;
            float a0 = dwout[wk][lane], a1 = dwout[wk][lane + 64];
            float s1 = a0 + a1;
#pragma unroll
            for (int o = 1; o < 64; o <<= 1) s1 += __shfl_xor(s1, o);
            float mu = s1 * (1.f / 128.f);
            float d0 = a0 - mu, d1 = a1 - mu;
            float v2 = d0 * d0 + d1 * d1;
#pragma unroll
            for (int o = 1; o < 64; o <<= 1) v2 += __shfl_xor(v2, o);
            float rs = rsqrtf(v2 * (1.f / 128.f) + 1e-5f);
            int c0 = lane, c1 = lane + 64;
            float y0 = d0 * rs * ln_g[p * 128 + c0] + ln_b[p * 128 + c0];
            float y1 = d1 * rs * ln_g[p * 128 + c1] + ln_b[p * 128 + c1];
            float g0 = 0.5f * y0 * (1.f + erff(y0 * 0.70710678118654752f));
            float g1 = 0.5f * y1 * (1.f + erff(y1 * 0.70710678118654752f));
            float o0 = pw_w[(p * 2 + 0) * 128 + c0] * g0
                     + pw_w[(p * 2 + 0) * 128 + c1] * g1;
            float o1 = pw_w[(p * 2 + 1) * 128 + c0] * g0
                     + pw_w[(p * 2 + 1) * 128 + c1] * g1;
#pragma unroll
            for (int o = 1; o < 64; o <<= 1) o0 += __shfl_xor(o0, o);
#pragma unroll
            for (int o = 1; o < 64; o <<= 1) o1 += __shfl_xor(o1, o);
            if (lane == 0) {
                int wk2 = s & 15;
                float refy = (hk + 0.5f) * (2.f / 15.f) - 1.f;
                float refx = (wk2 + 0.5f) * (2.f / 15.f) - 1.f;
                float py = fminf(fmaxf(o0 + refy, -1.f), 1.f);
                float px = fminf(fmaxf(o1 + refx, -1.f), 1.f);
                int pbn = pb * 256 + s;
                posb[pbn * 2 + 0] = py;
                posb[pbn * 2 + 1] = px;
                float cy = 31.5f * (1.f - py), cx = 31.5f * (1.f - px);
                float yf = floorf(cy), xf = floorf(cx);
                float wy = cy - yf, wx = cx - xf;
                int Y0 = (int)yf, X0 = (int)xf;
                uint4 v;
                v.x = (unsigned)f2bf((1.f - wy) * (1.f - wx))
                    | ((unsigned)f2bf((1.f - wy) * wx) << 16);
                v.y = (unsigned)f2bf(wy * (1.f - wx))
                    | ((unsigned)f2bf(wy * wx) << 16);
                v.z = (unsigned)((Y0 * 128 + X0) * 2);
                v.w = 0;
                prmb[pbn] = v;
            }
        }
    } else {
        // transpose part
        float (*ld2)[65] = (float(*)[65])sm;
        int rem = blk - 192;                  // 0..2047
        int v = rem >> 10;
        int rem1 = rem & 1023;
        int b = rem1 >> 8;
        int rem2 = rem1 & 255;
        int ct = rem2 >> 6;
        int mt = rem2 & 63;
        const float* src = ((v == 0) ? x0 : x1) + (long long)b * CC * HW
                           + (long long)(ct * 32) * HW + mt * 64;
#pragma unroll
        for (int it = 0; it < 2; it++) {
            int c = tid >> 3, x4 = (tid & 7) + it * 8;
            float4 w = *(const float4*)(src + (long long)c * HW + x4 * 4);
            ld2[c][x4 * 4 + 0] = w.x;
            ld2[c][x4 * 4 + 1] = w.y;
            ld2[c][x4 * 4 + 2] = w.z;
            ld2[c][x4 * 4 + 3] = w.w;
        }
        __syncthreads();
        int m = tid >> 2, cg = tid & 3;
        union { unsigned u[4]; } pk;
#pragma unroll
        for (int t = 0; t < 4; t++) {
            unsigned short h0 = f2bf(ld2[cg * 8 + 2 * t][m]);
            unsigned short h1 = f2bf(ld2[cg * 8 + 2 * t + 1][m]);
            pk.u[t] = (unsigned)h0 | ((unsigned)h1 << 16);
        }
        *(uint4*)(xT + (((long long)(v * 4 + b)) * HW + mt * 64 + m) * 128
                  + ct * 32 + cg * 8) = *(uint4*)pk.u;
    }
}

// ---------------------------------------------------------------------------
// K4) fused sample + K/V conv (MFMA), clamped-base bilinear (NaN-safe).
__global__ __launch_bounds__(256) void sample_kv(const unsigned short* __restrict__ xT,
                                                 const float* __restrict__ posb,
                                                 const unsigned short* __restrict__ wkh,
                                                 const unsigned short* __restrict__ wvh,
                                                 const float* __restrict__ bk,
                                                 const float* __restrict__ bv,
                                                 unsigned short* __restrict__ kbf,
                                                 unsigned short* __restrict__ vbf) {
    __shared__ unsigned short xls[32 * 128];      // 8 KB, XOR-swizzled rows
    int blk = blockIdx.x;                 // 96
    int pb = blk >> 3;
    int nt = blk & 7;
    int p = pb >> 2, b = pb & 3;
    int n0 = nt * 32;
    int tid = threadIdx.x;

    {
        int nl = tid >> 3, co = tid & 7;
        int n = n0 + nl;
        float py = posb[(pb * 256 + n) * 2 + 0];
        float px = posb[(pb * 256 + n) * 2 + 1];
        float yi = (py + 1.f) * 31.5f, xi = (px + 1.f) * 31.5f;
        yi = fminf(fmaxf(yi, 0.f), 63.f);
        xi = fminf(fmaxf(xi, 0.f), 63.f);
        int y0 = min((int)yi, 62);
        int x0i = min((int)xi, 62);
        float wy = yi - (float)y0, wx = xi - (float)x0i;
        float w00 = (1.f - wy) * (1.f - wx), w01 = (1.f - wy) * wx;
        float w10 = wy * (1.f - wx), w11 = wy * wx;
        int vsel = (p == 2) ? 1 : 0;
        const unsigned short* base = xT + ((long long)(vsel * 4 + b)) * HW * 128;
        int m00 = y0 * 64 + x0i;
        char* dst = (char*)xls;
#pragma unroll
        for (int cb = 0; cb < 2; cb++) {
            int c0 = co * 16 + cb * 8;
            bf16x8 a = *(const bf16x8*)(base + (long long)m00 * 128 + c0);
            bf16x8 bb = *(const bf16x8*)(base + (long long)(m00 + 1) * 128 + c0);
            bf16x8 cc = *(const bf16x8*)(base + (long long)(m00 + 64) * 128 + c0);
            bf16x8 dd = *(const bf16x8*)(base + (long long)(m00 + 65) * 128 + c0);
            union { unsigned u[4]; bf16x8 v; } R;
#pragma unroll
            for (int t = 0; t < 4; t++) {
                float r0 = w00 * bflo((unsigned)(unsigned short)a[2 * t])
                         + w01 * bflo((unsigned)(unsigned short)bb[2 * t])
                         + w10 * bflo((unsigned)(unsigned short)cc[2 * t])
                         + w11 * bflo((unsigned)(unsigned short)dd[2 * t]);
                float r1 = w00 * bflo((unsigned)(unsigned short)a[2 * t + 1])
                         + w01 * bflo((unsigned)(unsigned short)bb[2 * t + 1])
                         + w10 * bflo((unsigned)(unsigned short)cc[2 * t + 1])
                         + w11 * bflo((unsigned)(unsigned short)dd[2 * t + 1]);
                R.u[t] = (unsigned)f2bf(r0) | ((unsigned)f2bf(r1) << 16);
            }
            *(bf16x8*)(dst + ((nl * 256 + c0 * 2) ^ ((nl & 7) << 4))) = R.v;
        }
    }
    __syncthreads();

    int wid = tid >> 6, lane = tid & 63;
    int g = lane >> 4, lm = lane & 15;
    int ntile = wid & 1, isv = wid >> 1;
    int nl = ntile * 16 + lm;
    const char* srcl = (const char*)xls;
    bf16x8 xf[4];
#pragma unroll
    for (int ks = 0; ks < 4; ks++)
        xf[ks] = *(const bf16x8*)(srcl + ((nl * 256 + (ks * 32 + 8 * g) * 2)
                                          ^ ((nl & 7) << 4)));
    f32x4 zero = {0.f, 0.f, 0.f, 0.f};
    if (!isv) {
        const unsigned short* WK = wkh + p * 16384;
#pragma unroll
        for (int ct = 0; ct < 8; ct++) {
            f32x4 acc = zero;
#pragma unroll
            for (int ks = 0; ks < 4; ks++) {
                bf16x8 wf = *(const bf16x8*)(WK + (ct * 16 + lm) * 128 + ks * 32 + 8 * g);
                acc = __builtin_amdgcn_mfma_f32_16x16x32_bf16(xf[ks], wf, acc, 0, 0, 0);
            }
            float bias = bk[p * 128 + ct * 16 + lm];
#pragma unroll
            for (int r = 0; r < 4; r++) {
                int n = n0 + ntile * 16 + 4 * g + r;
                kbf[((long long)pb * 256 + n) * 128 + ct * 16 + lm] = f2bf(acc[r] + bias);
            }
        }
    } else {
        const unsigned short* WV = wvh + p * 16384;
#pragma unroll
        for (int ct = 0; ct < 8; ct++) {
            f32x4 acc = zero;
#pragma unroll
            for (int ks = 0; ks < 4; ks++) {
                bf16x8 wf = *(const bf16x8*)(WV + (ct * 16 + lm) * 128 + ks * 32 + 8 * g);
                acc = __builtin_amdgcn_mfma_f32_16x16x32_bf16(wf, xf[ks], acc, 0, 0, 0);
            }
#pragma unroll
            for (int r = 0; r < 4; r++) {
                int c = ct * 16 + 4 * g + r;
                vbf[((long long)pb * 128 + c) * 256 + n0 + ntile * 16 + lm]
                    = f2bf(acc[r] + bv[p * 128 + c]);
            }
        }
    }
}

// ---------------------------------------------------------------------------
// K5) MFMA attention v6: n split across wave pairs (R17) + PARTIAL table
//     staging: only rows my..my+65 are reachable (yimg = my + cy, cy in
//     [0,63], +1 tap) -> 66 rows x 128 cols = 16.9 KB (vs 32 KB). The my*128
//     term in the gather offset cancels against the staging base, so
//     va = prm.z + mx*2. LDS/block ~21 KB -> 7 blocks/CU.
__global__ __launch_bounds__(512, 4) void attn_mfma(
        const unsigned short* __restrict__ qbf,
        const unsigned short* __restrict__ kbf,
        const unsigned short* __restrict__ vbf,
        const unsigned short* __restrict__ tabbf,
        const uint4* __restrict__ prmb,
        unsigned short* __restrict__ obf) {
    __shared__ unsigned short tab[66 * 128 + 8];  // 16.9 KB (+pad)
    __shared__ uint4 prm[256];
    int tid = threadIdx.x;
    int wid = tid >> 6, lane = tid & 63;
    int g = lane >> 4, lm = lane & 15;
    int nh = wid >> 2;                        // n-half
    int mq = wid & 3;                         // mx quarter
    int bid = blockIdx.x;                     // 3072
    int my = bid & 63;
    int h = (bid >> 6) & 3;
    int b = (bid >> 8) & 3;
    int p = bid >> 10;
    int pb = p * 4 + b;

    {   // stage table rows my..my+65 + params (512 threads)
        const uint4* ts = (const uint4*)(tabbf + (long long)(p * 4 + h) * 16384
                                         + my * 128);
        uint4* td = (uint4*)tab;
        for (int i = tid; i < 1056; i += 512) td[i] = ts[i];   // 66*128/8
        if (tid < 256) prm[tid] = prmb[pb * 256 + tid];
    }
    __syncthreads();

    int mx = (mq << 4) + lm;
    int nb = nh * 128;

    // ---- QK^T (swapped) for this wave's n-half ----
    bf16x8 qf = *(const bf16x8*)(qbf + ((long long)pb * HW + my * 64 + mx) * 128
                                 + h * 32 + 8 * g);
    const unsigned short* kbase = kbf + ((long long)pb * 256 + lm) * 128
                                  + h * 32 + 8 * g;
    f32x4 zero = {0.f, 0.f, 0.f, 0.f};
    f32x4 acc[8];
    __builtin_amdgcn_s_setprio(1);
#pragma unroll
    for (int ni = 0; ni < 8; ni++) {
        bf16x8 kf = *(const bf16x8*)(kbase + (nb + ni * 16) * 128);
        acc[ni] = __builtin_amdgcn_mfma_f32_16x16x32_bf16(kf, qf, zero, 0, 0, 0);
    }
    __builtin_amdgcn_s_setprio(0);

    // ---- RPE bias for this n-half (va = prm.z + mx*2; my cancels) ----
    int laneoff = mx * 2;
    const char* tb = (const char*)tab;
#pragma unroll
    for (int ni = 0; ni < 8; ni++) {
#pragma unroll
        for (int r = 0; r < 4; r++) {
            int n = nb + ni * 16 + 4 * g + r;
            uint4 pw = prm[n];
            int va = (int)pw.z + laneoff;
            int va4 = va & ~3;
            int sh = va & 3;
            unsigned r0 = *(const unsigned*)(tb + va4);
            unsigned r1 = *(const unsigned*)(tb + va4 + 4);
            unsigned r2 = *(const unsigned*)(tb + va4 + 256);
            unsigned r3 = *(const unsigned*)(tb + va4 + 260);
            unsigned p0 = __builtin_amdgcn_alignbyte(r1, r0, sh);
            unsigned p1 = __builtin_amdgcn_alignbyte(r3, r2, sh);
            float t = acc[ni][r];
            t = dot2bf(p0, pw.x, t);
            t = dot2bf(p1, pw.y, t);
            acc[ni][r] = t;
        }
    }

    // ---- local max over this half ----
    float mloc = -1e30f;
#pragma unroll
    for (int ni = 0; ni < 8; ni++)
        mloc = fmaxf(mloc, fmaxf(fmaxf(acc[ni][0], acc[ni][1]),
                                 fmaxf(acc[ni][2], acc[ni][3])));
    mloc = fmaxf(mloc, __shfl_xor(mloc, 16));
    mloc = fmaxf(mloc, __shfl_xor(mloc, 32));

    // exchange buffers in the dead tab region (after B0):
    //   mex bytes [0,512), sex [512,1024), oex [1024,9216),
    //   bounce shorts [4608..7168) = bytes [9216,14336) -- all disjoint.
    float* mex = (float*)tab;                 // [2][64]
    float* sex = (float*)tab + 128;           // [2][64]
    float* oex = (float*)tab + 256;           // [4 mq][64 lane][8]
    __syncthreads();                          // B0: all tab reads complete
    if (g == 0) mex[nh * 64 + mx] = mloc;
    __syncthreads();                          // B1
    float mglob = fmaxf(mex[mx], mex[64 + mx]);

    // ---- e, local sum, pack ----
    float lsum = 0.f;
    unsigned dwA[8], dwB[8];
#pragma unroll
    for (int ni = 0; ni < 8; ni++) {
        float e0 = __expf(acc[ni][0] - mglob);
        float e1 = __expf(acc[ni][1] - mglob);
        float e2 = __expf(acc[ni][2] - mglob);
        float e3 = __expf(acc[ni][3] - mglob);
        lsum += (e0 + e1) + (e2 + e3);
        asm("v_cvt_pk_bf16_f32 %0, %1, %2" : "=v"(dwA[ni]) : "v"(e0), "v"(e1));
        asm("v_cvt_pk_bf16_f32 %0, %1, %2" : "=v"(dwB[ni]) : "v"(e2), "v"(e3));
    }
    lsum += __shfl_xor(lsum, 16);
    lsum += __shfl_xor(lsum, 32);
    if (g == 0) sex[nh * 64 + mx] = lsum;

    // ---- PV for this n-half ----
    int src0 = ((g & 1) << 5) + lm;
    int src1 = src0 + 16;
    bool sel = (g >> 1) != 0;
    const unsigned short* vb0 = vbf + ((long long)pb * 128 + h * 32 + lm) * 256
                                + 8 * g + nb;
    f32x4 o0 = zero, o1 = zero;
#pragma unroll
    for (int st = 0; st < 4; st++) {
        unsigned d0a = __shfl(dwA[2 * st], src0), d0b = __shfl(dwA[2 * st + 1], src0);
        unsigned d1a = __shfl(dwB[2 * st], src0), d1b = __shfl(dwB[2 * st + 1], src0);
        unsigned d2a = __shfl(dwA[2 * st], src1), d2b = __shfl(dwA[2 * st + 1], src1);
        unsigned d3a = __shfl(dwB[2 * st], src1), d3b = __shfl(dwB[2 * st + 1], src1);
        union { unsigned u[4]; bf16x8 v; } pf;
        pf.u[0] = sel ? d0b : d0a;
        pf.u[1] = sel ? d1b : d1a;
        pf.u[2] = sel ? d2b : d2a;
        pf.u[3] = sel ? d3b : d3a;
        bf16x8 v0 = *(const bf16x8*)(vb0 + st * 32);
        bf16x8 v1 = *(const bf16x8*)(vb0 + 4096 + st * 32);
        __builtin_amdgcn_s_setprio(1);
        o0 = __builtin_amdgcn_mfma_f32_16x16x32_bf16(v0, pf.v, o0, 0, 0, 0);
        o1 = __builtin_amdgcn_mfma_f32_16x16x32_bf16(v1, pf.v, o1, 0, 0, 0);
        __builtin_amdgcn_s_setprio(0);
    }

    // ---- combine halves ----
    if (nh == 1) {
        float* od = oex + (mq * 64 + lane) * 8;
#pragma unroll
        for (int r = 0; r < 4; r++) { od[r] = o0[r]; od[4 + r] = o1[r]; }
    }
    __syncthreads();                          // B2
    if (nh == 1) return;

    const float* os = oex + (mq * 64 + lane) * 8;
#pragma unroll
    for (int r = 0; r < 4; r++) { o0[r] += os[r]; o1[r] += os[4 + r]; }
    float inv = 1.f / (sex[mx] + sex[64 + mx]);

    // ---- output: bf16 [m][c] via LDS bounce ----
    unsigned short* bounce = tab + 4608;
    {
        unsigned short* rw = bounce + mq * 640 + lm * 40;
        *(unsigned*)(rw + g * 4) =
            (unsigned)f2bf(o0[0] * inv) | ((unsigned)f2bf(o0[1] * inv) << 16);
        *(unsigned*)(rw + g * 4 + 2) =
            (unsigned)f2bf(o0[2] * inv) | ((unsigned)f2bf(o0[3] * inv) << 16);
        *(unsigned*)(rw + 16 + g * 4) =
            (unsigned)f2bf(o1[0] * inv) | ((unsigned)f2bf(o1[1] * inv) << 16);
        *(unsigned*)(rw + 16 + g * 4 + 2) =
            (unsigned)f2bf(o1[2] * inv) | ((unsigned)f2bf(o1[3] * inv) << 16);
    }
    int row = lane >> 2, cb = lane & 3;
    uint4 vv = *(const uint4*)(bounce + mq * 640 + row * 40 + cb * 8);
    *(uint4*)(obf + ((long long)pb * HW + my * 64 + mq * 16 + row) * 128
              + h * 32 + cb * 8) = vv;
}

// ---------------------------------------------------------------------------
// K6) conv_wo via MFMA (bf16): out = x + sum_p Wo[p] o[p] + bo on chans
//     128:256 of vars 1,2. obf is bf16 [m][c]: contiguous 16B B-fragments.
__global__ __launch_bounds__(256) void conv_wo(const float* __restrict__ x1,
                                               const float* __restrict__ x2,
                                               const unsigned short* __restrict__ obf,
                                               const unsigned short* __restrict__ woh,
                                               const float* __restrict__ bo,
                                               float* __restrict__ out) {
    int wid = threadIdx.x >> 6, lane = threadIdx.x & 63;
    int g = lane >> 4, lm = lane & 15;
    int gw = blockIdx.x * 4 + wid;            // 2048 waves
    int mt = gw & 255;
    int b = (gw >> 8) & 3;
    int vs = gw >> 10;
    int m = mt * 16 + lm;
    int np = vs + 1;

    f32x4 acc[8];
#pragma unroll
    for (int ct = 0; ct < 8; ct++) acc[ct] = (f32x4){0.f, 0.f, 0.f, 0.f};

    for (int pi = 0; pi < np; pi++) {
        int p = vs ? (1 + pi) : 0;
        const unsigned short* Om = obf + ((long long)(p * 4 + b) * HW + m) * 128;
        const unsigned short* WH = woh + p * 16384;
#pragma unroll
        for (int ksl = 0; ksl < 4; ksl++) {
            bf16x8 bh = *(const bf16x8*)(Om + ksl * 32 + 8 * g);
#pragma unroll
            for (int ct = 0; ct < 8; ct++) {
                bf16x8 A = *(const bf16x8*)(WH + (ct * 16 + lm) * 128 + ksl * 32 + 8 * g);
                acc[ct] = __builtin_amdgcn_mfma_f32_16x16x32_bf16(A, bh, acc[ct], 0, 0, 0);
            }
        }
    }

    int qi = vs + 1;
    const float* xq = (vs ? x2 : x1) + (long long)b * CC * HW;
#pragma unroll
    for (int ct = 0; ct < 8; ct++)
#pragma unroll
        for (int r = 0; r < 4; r++) {
            int c = ct * 16 + 4 * g + r;
            float bias = vs ? (bo[128 + c] + bo[256 + c]) : bo[c];
            float base = xq[(long long)(128 + c) * HW + m];
            out[(((long long)(qi * 4 + b)) * CC + 128 + c) * HW + m]
                = base + acc[ct][r] + bias;
        }
}

// ---------------------------------------------------------------------------
extern "C" void kernel_launch(void* const* d_in, const int* in_sizes, int n_in,
                              void* d_out, int out_size, void* d_ws, size_t ws_size,
                              hipStream_t stream) {
    const float* x0 = (const float*)d_in[0];
    const float* x1 = (const float*)d_in[1];
    const float* x2 = (const float*)d_in[2];
    const float* Wq = (const float*)d_in[3];
    const float* bq = (const float*)d_in[4];
    const float* Wk = (const float*)d_in[5];
    const float* bk = (const float*)d_in[6];
    const float* Wv = (const float*)d_in[7];
    const float* bv = (const float*)d_in[8];
    const float* Wo = (const float*)d_in[9];
    const float* bo = (const float*)d_in[10];
    const float* dw_w = (const float*)d_in[11];
    const float* dw_b = (const float*)d_in[12];
    const float* ln_g = (const float*)d_in[13];
    const float* ln_b = (const float*)d_in[14];
    const float* pw_w = (const float*)d_in[15];
    const float* rpe = (const float*)d_in[16];
    float* out = (float*)d_out;

    // Workspace. obf bf16 at ws start.
    float* ws = (float*)d_ws;
    unsigned short* obf = (unsigned short*)ws;               // 6291456 s (12 MB)
    float* posb = ws + 6291456;                              // 6144 f
    unsigned short* xT = (unsigned short*)(posb + 6144);     // 4194304 s (8 MB)
    unsigned short* qbf = xT + 4194304;                      // 12582912 s (24 MB)
    unsigned short* kbf = qbf + 12582912;                    // 393216 s
    unsigned short* vbf = kbf + 393216;                      // 393216 s
    unsigned short* tabbf = vbf + 393216;                    // 196608 s
    uint4* prmb = (uint4*)(tabbf + 196608);                  // 3072 uint4
    unsigned short* wqh = (unsigned short*)(prmb + 3072);    // 49152 s
    unsigned short* woh = wqh + 49152;
    unsigned short* wkh = woh + 49152;
    unsigned short* wvh = wkh + 49152;

    prep_copy<<<1048, 256, 0, stream>>>(rpe, Wq, Wo, Wk, Wv, x0, tabbf,
                                        wqh, woh, wkh, wvh, out);
    conv_q<<<512, 256, 0, stream>>>(x1, x2, wqh, bq, qbf, out);
    mid_kernel<<<2240, 256, 0, stream>>>(qbf, dw_w, dw_b, ln_g, ln_b, pw_w,
                                         x0, x1, posb, prmb, xT);
    sample_kv<<<96, 256, 0, stream>>>(xT, posb, wkh, wvh, bk, bv, kbf, vbf);
    attn_mfma<<<3072, 512, 0, stream>>>(qbf, kbf, vbf, tabbf, prmb, obf);
    conv_wo<<<512, 256, 0, stream>>>(x1, x2, obf, woh, bo, out);
}

// Round 19
// 160.256 us; speedup vs baseline: 3.1512x; 1.0012x over previous
//
#include <hip/hip_runtime.h>
#include <math.h>

// Problem constants
#define NVAR 3
#define BB 4
#define CC 256
#define C1 128
#define HEADS 4
#define HH 64
#define WW 64
#define HW 4096
#define RPE_W 127
#define NP 3
#define SCALE 0.17677669529663687f
// pairs: p=0 -> (i=1,j=0), p=1 -> (i=2,j=0), p=2 -> (i=2,j=1)

typedef short bf16x8 __attribute__((ext_vector_type(8)));
typedef float f32x4 __attribute__((ext_vector_type(4)));
typedef __bf16 bf16x2 __attribute__((ext_vector_type(2)));

__device__ __forceinline__ unsigned short f2bf(float f) {
    unsigned int u = __float_as_uint(f);
    u += 0x7fffu + ((u >> 16) & 1u);          // round-to-nearest-even
    return (unsigned short)(u >> 16);
}
__device__ __forceinline__ float bflo(unsigned u) { return __uint_as_float(u << 16); }
__device__ __forceinline__ float bfhi(unsigned u) { return __uint_as_float(u & 0xffff0000u); }

// packed bf16x2 dot: c + a.lo*b.lo + a.hi*b.hi
__device__ __forceinline__ float dot2bf(unsigned a, unsigned b, float c) {
#if __has_builtin(__builtin_amdgcn_fdot2_f32_bf16)
    return __builtin_amdgcn_fdot2_f32_bf16(__builtin_bit_cast(bf16x2, a),
                                           __builtin_bit_cast(bf16x2, b), c, false);
#else
    return c + bflo(a) * bflo(b) + bfhi(a) * bfhi(b);
#endif
}

// ---------------------------------------------------------------------------
// K1) const prep (blocks 0..23) + copy x0 -> out var0 + flow zeros (24..1047).
//     RPE table built as ROW-PAIRED dwords: dtab[y][x] = (tab[y][x], tab[y+1][x]).
__global__ __launch_bounds__(256) void prep_copy(const float* __restrict__ rpe,
                                                 const float* __restrict__ Wq,
                                                 const float* __restrict__ Wo,
                                                 const float* __restrict__ Wk,
                                                 const float* __restrict__ Wv,
                                                 const float* __restrict__ x0,
                                                 unsigned* __restrict__ dtabbf,
                                                 unsigned short* __restrict__ wqh,
                                                 unsigned short* __restrict__ woh,
                                                 unsigned short* __restrict__ wkh,
                                                 unsigned short* __restrict__ wvh,
                                                 float* __restrict__ out) {
    int blk = blockIdx.x;
    if (blk >= 24) {
        const long long n4 = (long long)BB * CC * HW / 4;
        long long i = (long long)(blk - 24) * 256 + threadIdx.x;
        const long long stride = 1024LL * 256;
        for (; i < n4 + 12; i += stride) {
            if (i < n4) ((float4*)out)[i] = ((const float4*)x0)[i];
            else out[3LL * BB * CC * HW + (i - n4)] = 0.f;
        }
        return;
    }
    if (blk < 12) {
        const float* src = rpe + (long long)blk * RPE_W * RPE_W;
        unsigned* dst = dtabbf + (long long)blk * 16384;
        for (int idx = threadIdx.x; idx < 16384; idx += 256) {
            int y = idx >> 7, x = idx & 127;
            float v0 = (y < RPE_W && x < RPE_W) ? src[y * RPE_W + x] : 0.f;
            float v1 = (y + 1 < RPE_W && x < RPE_W) ? src[(y + 1) * RPE_W + x] : 0.f;
            dst[idx] = (unsigned)f2bf(v0) | ((unsigned)f2bf(v1) << 16);
        }
    } else if (blk < 15) {
        int p = blk - 12;
        for (int i = threadIdx.x; i < 16384; i += 256)
            wqh[p * 16384 + i] = f2bf(Wq[p * 16384 + i]);
    } else if (blk < 18) {
        int p = blk - 15;
        for (int i = threadIdx.x; i < 16384; i += 256)
            woh[p * 16384 + i] = f2bf(Wo[p * 16384 + i]);
    } else if (blk < 21) {
        int p = blk - 18;
        for (int i = threadIdx.x; i < 16384; i += 256)
            wkh[p * 16384 + i] = f2bf(Wk[p * 16384 + i]);
    } else {
        int p = blk - 21;
        for (int i = threadIdx.x; i < 16384; i += 256)
            wvh[p * 16384 + i] = f2bf(Wv[p * 16384 + i]);
    }
}

// ---------------------------------------------------------------------------
// K2) conv_q via MFMA (single bf16). Writes qbf bf16 [pb][m][c] (pre-scaled,
//     coalesced via LDS bounce) AND copies x chans 0:128 into out.
//     Waves with pbi>=4 compute BOTH p=1 and p=2 (shared x2 B-fragments).
__global__ __launch_bounds__(256) void conv_q(const float* __restrict__ x1,
                                              const float* __restrict__ x2,
                                              const unsigned short* __restrict__ wqh,
                                              const float* __restrict__ bq,
                                              unsigned short* __restrict__ qbf,
                                              float* __restrict__ out) {
    __shared__ unsigned short qlds[4][16][136];   // 17 KB; 16B-aligned rows
    int wid = threadIdx.x >> 6, lane = threadIdx.x & 63;
    int g = lane >> 4, lm = lane & 15;
    int gw = blockIdx.x * 4 + wid;            // 2048 waves
    int mt = gw & 255;
    int pbi = gw >> 8;                        // 0..7
    int merged = pbi >> 2;                    // 0: p=0 (x1); 1: p=1&2 (x2)
    int b = pbi & 3;
    const float* X = (merged ? x2 : x1) + (long long)b * CC * HW;
    int m = mt * 16 + lm;
    int qi = merged + 1;
    float* outc = out + (((long long)(qi * 4 + b)) * CC) * HW + m;

    // B fragments (bf16) + copy chans 0:128 to out
    bf16x8 bh[4];
#pragma unroll
    for (int ksl = 0; ksl < 4; ksl++) {
        float v[8];
#pragma unroll
        for (int j = 0; j < 8; j++) {
            int k = ksl * 32 + 8 * g + j;
            v[j] = X[(long long)k * HW + m];
            outc[(long long)k * HW] = v[j];
        }
        union { unsigned u[4]; bf16x8 v; } H;
#pragma unroll
        for (int t = 0; t < 4; t++)
            H.u[t] = (unsigned)f2bf(v[2 * t]) | ((unsigned)f2bf(v[2 * t + 1]) << 16);
        bh[ksl] = H.v;
    }

    f32x4 zero = {0.f, 0.f, 0.f, 0.f};
    unsigned short* ql = &qlds[wid][lm][0];
    int qq = lane >> 4, cg = lane & 15;

    for (int rep = 0; rep <= merged; rep++) {
        int p = merged ? (1 + rep) : 0;
        int pb = p * 4 + b;
        const unsigned short* WH = wqh + p * 16384;
#pragma unroll
        for (int ct2 = 0; ct2 < 4; ct2++) {
            int ct0 = 2 * ct2, ct1 = ct0 + 1;
            f32x4 a0 = zero, a1 = zero;
#pragma unroll
            for (int ksl = 0; ksl < 4; ksl++) {
                bf16x8 Ah0 = *(const bf16x8*)(WH + (ct0 * 16 + lm) * 128 + ksl * 32 + 8 * g);
                bf16x8 Ah1 = *(const bf16x8*)(WH + (ct1 * 16 + lm) * 128 + ksl * 32 + 8 * g);
                a0 = __builtin_amdgcn_mfma_f32_16x16x32_bf16(Ah0, bh[ksl], a0, 0, 0, 0);
                a1 = __builtin_amdgcn_mfma_f32_16x16x32_bf16(Ah1, bh[ksl], a1, 0, 0, 0);
            }
            float q0[4], q1[4];
#pragma unroll
            for (int r = 0; r < 4; r++) {
                q0[r] = a0[r] + bq[p * 128 + ct0 * 16 + 4 * g + r];
                q1[r] = a1[r] + bq[p * 128 + ct1 * 16 + 4 * g + r];
            }
            *(unsigned*)(ql + ct0 * 16 + 4 * g) =
                (unsigned)f2bf(q0[0] * SCALE) | ((unsigned)f2bf(q0[1] * SCALE) << 16);
            *(unsigned*)(ql + ct0 * 16 + 4 * g + 2) =
                (unsigned)f2bf(q0[2] * SCALE) | ((unsigned)f2bf(q0[3] * SCALE) << 16);
            *(unsigned*)(ql + ct1 * 16 + 4 * g) =
                (unsigned)f2bf(q1[0] * SCALE) | ((unsigned)f2bf(q1[1] * SCALE) << 16);
            *(unsigned*)(ql + ct1 * 16 + 4 * g + 2) =
                (unsigned)f2bf(q1[2] * SCALE) | ((unsigned)f2bf(q1[3] * SCALE) << 16);
        }
        // same-wave LDS readback -> coalesced 1KB-contiguous stores
        unsigned short* Yb = qbf + ((long long)pb * HW + mt * 16) * 128;
#pragma unroll
        for (int i = 0; i < 4; i++) {
            int row = i * 4 + qq;
            uint4 vv = *(const uint4*)&qlds[wid][row][cg * 8];
            *(uint4*)(Yb + row * 128 + cg * 8) = vv;
        }
    }
}

// ---------------------------------------------------------------------------
// K3) fused middle kernel:
//   blocks 0..191:  offset net from qbf (bf16, pre-scaled; 1/SCALE folded into
//                   the depthwise weights) -> LN -> GELU -> 1x1 -> pos + prm.
//                   prm packs weights for the ROW-PAIRED table: x=(w00,w10),
//                   y=(w01,w11), z=(Y0*128+X0)*4 (dword byte offset).
//   blocks 192..2239: transpose x0,x1 chans 0:128 -> xT bf16 [v][b][m][c].
__global__ __launch_bounds__(256) void mid_kernel(const unsigned short* __restrict__ qbf,
                                                  const float* __restrict__ dw_w,
                                                  const float* __restrict__ dw_b,
                                                  const float* __restrict__ ln_g,
                                                  const float* __restrict__ ln_b,
                                                  const float* __restrict__ pw_w,
                                                  const float* __restrict__ x0,
                                                  const float* __restrict__ x1,
                                                  float* __restrict__ posb,
                                                  uint4* __restrict__ prmb,
                                                  unsigned short* __restrict__ xT) {
    __shared__ char sm[40960];                // 40 KB (qs 32K + dwout 8K)
    int blk = blockIdx.x;
    int tid = threadIdx.x;
    if (blk < 192) {
        unsigned short* qs = (unsigned short*)sm;            // 32 KB: 128m x 128c
        float (*dwout)[128] = (float(*)[128])(sm + 32768);   // 8 KB
        int pb = blk >> 4, hk = blk & 15;
        int p = pb >> 2;
        int c = tid & 127;
        int wk0 = tid >> 7;
        const float* dwp_g = dw_w + (p * 128 + c) * 16;
        float dwp[16];
#pragma unroll
        for (int j = 0; j < 16; j++) dwp[j] = dwp_g[j] * (1.f / SCALE);
        float acc[8];
#pragma unroll
        for (int o = 0; o < 8; o++) acc[o] = dw_b[p * 128 + c];
        const unsigned short* Q = qbf + ((long long)pb * HW + hk * 256) * 128;
        for (int pass = 0; pass < 2; pass++) {
            __syncthreads();
#pragma unroll
            for (int it = 0; it < 8; it++) {
                int idx = tid + it * 256;          // 2048 uint4
                int mloc = idx >> 4, cg = idx & 15;
                *(uint4*)(qs + mloc * 128 + cg * 8) =
                    *(const uint4*)(Q + (long long)(pass * 128 + mloc) * 128 + cg * 8);
            }
            __syncthreads();
#pragma unroll
            for (int o = 0; o < 8; o++) {
                int wk = wk0 + o * 2;
                float a = acc[o];
#pragma unroll
                for (int kyl = 0; kyl < 2; kyl++)
#pragma unroll
                    for (int kx = 0; kx < 4; kx++)
                        a += bflo((unsigned)qs[(kyl * 64 + wk * 4 + kx) * 128 + c])
                             * dwp[(pass * 2 + kyl) * 4 + kx];
                acc[o] = a;
            }
        }
        __syncthreads();
#pragma unroll
        for (int o = 0; o < 8; o++) dwout[wk0 + o * 2][c] = acc[o];
        __syncthreads();
        // LN phase: 4 waves x 4 wk each
        int wid = tid >> 6, lane = tid & 63;
        for (int i = 0; i < 4; i++) {
            int wk = wid * 4 + i;
            int s = hk * 16 + wk;
            float a0 = dwout[wk][lane], a1 = dwout[wk][lane + 64];
            float s1 = a0 + a1;
#pragma unroll
            for (int o = 1; o < 64; o <<= 1) s1 += __shfl_xor(s1, o);
            float mu = s1 * (1.f / 128.f);
            float d0 = a0 - mu, d1 = a1 - mu;
            float v2 = d0 * d0 + d1 * d1;
#pragma unroll
            for (int o = 1; o < 64; o <<= 1) v2 += __shfl_xor(v2, o);
            float rs = rsqrtf(v2 * (1.f / 128.f) + 1e-5f);
            int c0 = lane, c1 = lane + 64;
            float y0 = d0 * rs * ln_g[p * 128 + c0] + ln_b[p * 128 + c0];
            float y1 = d1 * rs * ln_g[p * 128 + c1] + ln_b[p * 128 + c1];
            float g0 = 0.5f * y0 * (1.f + erff(y0 * 0.70710678118654752f));
            float g1 = 0.5f * y1 * (1.f + erff(y1 * 0.70710678118654752f));
            float o0 = pw_w[(p * 2 + 0) * 128 + c0] * g0
                     + pw_w[(p * 2 + 0) * 128 + c1] * g1;
            float o1 = pw_w[(p * 2 + 1) * 128 + c0] * g0
                     + pw_w[(p * 2 + 1) * 128 + c1] * g1;
#pragma unroll
            for (int o = 1; o < 64; o <<= 1) o0 += __shfl_xor(o0, o);
#pragma unroll
            for (int o = 1; o < 64; o <<= 1) o1 += __shfl_xor(o1, o);
            if (lane == 0) {
                int wk2 = s & 15;
                float refy = (hk + 0.5f) * (2.f / 15.f) - 1.f;
                float refx = (wk2 + 0.5f) * (2.f / 15.f) - 1.f;
                float py = fminf(fmaxf(o0 + refy, -1.f), 1.f);
                float px = fminf(fmaxf(o1 + refx, -1.f), 1.f);
                int pbn = pb * 256 + s;
                posb[pbn * 2 + 0] = py;
                posb[pbn * 2 + 1] = px;
                float cy = 31.5f * (1.f - py), cx = 31.5f * (1.f - px);
                float yf = floorf(cy), xf = floorf(cx);
                float wy = cy - yf, wx = cx - xf;
                int Y0 = (int)yf, X0 = (int)xf;
                uint4 v;
                v.x = (unsigned)f2bf((1.f - wy) * (1.f - wx))
                    | ((unsigned)f2bf(wy * (1.f - wx)) << 16);   // (w00, w10)
                v.y = (unsigned)f2bf((1.f - wy) * wx)
                    | ((unsigned)f2bf(wy * wx) << 16);           // (w01, w11)
                v.z = (unsigned)((Y0 * 128 + X0) * 4);
                v.w = 0;
                prmb[pbn] = v;
            }
        }
    } else {
        // transpose part
        float (*ld2)[65] = (float(*)[65])sm;
        int rem = blk - 192;                  // 0..2047
        int v = rem >> 10;
        int rem1 = rem & 1023;
        int b = rem1 >> 8;
        int rem2 = rem1 & 255;
        int ct = rem2 >> 6;
        int mt = rem2 & 63;
        const float* src = ((v == 0) ? x0 : x1) + (long long)b * CC * HW
                           + (long long)(ct * 32) * HW + mt * 64;
#pragma unroll
        for (int it = 0; it < 2; it++) {
            int c = tid >> 3, x4 = (tid & 7) + it * 8;
            float4 w = *(const float4*)(src + (long long)c * HW + x4 * 4);
            ld2[c][x4 * 4 + 0] = w.x;
            ld2[c][x4 * 4 + 1] = w.y;
            ld2[c][x4 * 4 + 2] = w.z;
            ld2[c][x4 * 4 + 3] = w.w;
        }
        __syncthreads();
        int m = tid >> 2, cg = tid & 3;
        union { unsigned u[4]; } pk;
#pragma unroll
        for (int t = 0; t < 4; t++) {
            unsigned short h0 = f2bf(ld2[cg * 8 + 2 * t][m]);
            unsigned short h1 = f2bf(ld2[cg * 8 + 2 * t + 1][m]);
            pk.u[t] = (unsigned)h0 | ((unsigned)h1 << 16);
        }
        *(uint4*)(xT + (((long long)(v * 4 + b)) * HW + mt * 64 + m) * 128
                  + ct * 32 + cg * 8) = *(uint4*)pk.u;
    }
}

// ---------------------------------------------------------------------------
// K4) fused sample + K/V conv (MFMA), clamped-base bilinear (NaN-safe).
__global__ __launch_bounds__(256) void sample_kv(const unsigned short* __restrict__ xT,
                                                 const float* __restrict__ posb,
                                                 const unsigned short* __restrict__ wkh,
                                                 const unsigned short* __restrict__ wvh,
                                                 const float* __restrict__ bk,
                                                 const float* __restrict__ bv,
                                                 unsigned short* __restrict__ kbf,
                                                 unsigned short* __restrict__ vbf) {
    __shared__ unsigned short xls[32 * 128];      // 8 KB, XOR-swizzled rows
    int blk = blockIdx.x;                 // 96
    int pb = blk >> 3;
    int nt = blk & 7;
    int p = pb >> 2, b = pb & 3;
    int n0 = nt * 32;
    int tid = threadIdx.x;

    {
        int nl = tid >> 3, co = tid & 7;
        int n = n0 + nl;
        float py = posb[(pb * 256 + n) * 2 + 0];
        float px = posb[(pb * 256 + n) * 2 + 1];
        float yi = (py + 1.f) * 31.5f, xi = (px + 1.f) * 31.5f;
        yi = fminf(fmaxf(yi, 0.f), 63.f);
        xi = fminf(fmaxf(xi, 0.f), 63.f);
        int y0 = min((int)yi, 62);
        int x0i = min((int)xi, 62);
        float wy = yi - (float)y0, wx = xi - (float)x0i;
        float w00 = (1.f - wy) * (1.f - wx), w01 = (1.f - wy) * wx;
        float w10 = wy * (1.f - wx), w11 = wy * wx;
        int vsel = (p == 2) ? 1 : 0;
        const unsigned short* base = xT + ((long long)(vsel * 4 + b)) * HW * 128;
        int m00 = y0 * 64 + x0i;
        char* dst = (char*)xls;
#pragma unroll
        for (int cb = 0; cb < 2; cb++) {
            int c0 = co * 16 + cb * 8;
            bf16x8 a = *(const bf16x8*)(base + (long long)m00 * 128 + c0);
            bf16x8 bb = *(const bf16x8*)(base + (long long)(m00 + 1) * 128 + c0);
            bf16x8 cc = *(const bf16x8*)(base + (long long)(m00 + 64) * 128 + c0);
            bf16x8 dd = *(const bf16x8*)(base + (long long)(m00 + 65) * 128 + c0);
            union { unsigned u[4]; bf16x8 v; } R;
#pragma unroll
            for (int t = 0; t < 4; t++) {
                float r0 = w00 * bflo((unsigned)(unsigned short)a[2 * t])
                         + w01 * bflo((unsigned)(unsigned short)bb[2 * t])
                         + w10 * bflo((unsigned)(unsigned short)cc[2 * t])
                         + w11 * bflo((unsigned)(unsigned short)dd[2 * t]);
                float r1 = w00 * bflo((unsigned)(unsigned short)a[2 * t + 1])
                         + w01 * bflo((unsigned)(unsigned short)bb[2 * t + 1])
                         + w10 * bflo((unsigned)(unsigned short)cc[2 * t + 1])
                         + w11 * bflo((unsigned)(unsigned short)dd[2 * t + 1]);
                R.u[t] = (unsigned)f2bf(r0) | ((unsigned)f2bf(r1) << 16);
            }
            *(bf16x8*)(dst + ((nl * 256 + c0 * 2) ^ ((nl & 7) << 4))) = R.v;
        }
    }
    __syncthreads();

    int wid = tid >> 6, lane = tid & 63;
    int g = lane >> 4, lm = lane & 15;
    int ntile = wid & 1, isv = wid >> 1;
    int nl = ntile * 16 + lm;
    const char* srcl = (const char*)xls;
    bf16x8 xf[4];
#pragma unroll
    for (int ks = 0; ks < 4; ks++)
        xf[ks] = *(const bf16x8*)(srcl + ((nl * 256 + (ks * 32 + 8 * g) * 2)
                                          ^ ((nl & 7) << 4)));
    f32x4 zero = {0.f, 0.f, 0.f, 0.f};
    if (!isv) {
        const unsigned short* WK = wkh + p * 16384;
#pragma unroll
        for (int ct = 0; ct < 8; ct++) {
            f32x4 acc = zero;
#pragma unroll
            for (int ks = 0; ks < 4; ks++) {
                bf16x8 wf = *(const bf16x8*)(WK + (ct * 16 + lm) * 128 + ks * 32 + 8 * g);
                acc = __builtin_amdgcn_mfma_f32_16x16x32_bf16(xf[ks], wf, acc, 0, 0, 0);
            }
            float bias = bk[p * 128 + ct * 16 + lm];
#pragma unroll
            for (int r = 0; r < 4; r++) {
                int n = n0 + ntile * 16 + 4 * g + r;
                kbf[((long long)pb * 256 + n) * 128 + ct * 16 + lm] = f2bf(acc[r] + bias);
            }
        }
    } else {
        const unsigned short* WV = wvh + p * 16384;
#pragma unroll
        for (int ct = 0; ct < 8; ct++) {
            f32x4 acc = zero;
#pragma unroll
            for (int ks = 0; ks < 4; ks++) {
                bf16x8 wf = *(const bf16x8*)(WV + (ct * 16 + lm) * 128 + ks * 32 + 8 * g);
                acc = __builtin_amdgcn_mfma_f32_16x16x32_bf16(wf, xf[ks], acc, 0, 0, 0);
            }
#pragma unroll
            for (int r = 0; r < 4; r++) {
                int c = ct * 16 + 4 * g + r;
                vbf[((long long)pb * 128 + c) * 256 + n0 + ntile * 16 + lm]
                    = f2bf(acc[r] + bv[p * 128 + c]);
            }
        }
    }
}

// ---------------------------------------------------------------------------
// K5) MFMA attention v7: n split across wave pairs + ROW-PAIRED table:
//     bias = 2 aligned ds_read_b32 + 2 dot2 per logit (was 4 reads + 2
//     alignbyte). Stage dtab rows my..my+63 (32 KB) + prm (4 KB).
__global__ __launch_bounds__(512, 4) void attn_mfma(
        const unsigned short* __restrict__ qbf,
        const unsigned short* __restrict__ kbf,
        const unsigned short* __restrict__ vbf,
        const unsigned* __restrict__ dtabbf,
        const uint4* __restrict__ prmb,
        unsigned short* __restrict__ obf) {
    __shared__ unsigned tab[64 * 128 + 4];    // 32 KB (+pad)
    __shared__ uint4 prm[256];
    int tid = threadIdx.x;
    int wid = tid >> 6, lane = tid & 63;
    int g = lane >> 4, lm = lane & 15;
    int nh = wid >> 2;                        // n-half
    int mq = wid & 3;                         // mx quarter
    int bid = blockIdx.x;                     // 3072
    int my = bid & 63;
    int h = (bid >> 6) & 3;
    int b = (bid >> 8) & 3;
    int p = bid >> 10;
    int pb = p * 4 + b;

    {   // stage paired-table rows my..my+63 + params (512 threads)
        const uint4* ts = (const uint4*)(dtabbf + (long long)(p * 4 + h) * 16384
                                         + my * 128);
        uint4* td = (uint4*)tab;
#pragma unroll
        for (int i = 0; i < 4; i++) td[tid + i * 512] = ts[tid + i * 512];
        if (tid < 256) prm[tid] = prmb[pb * 256 + tid];
    }
    __syncthreads();

    int mx = (mq << 4) + lm;
    int nb = nh * 128;

    // ---- QK^T (swapped) for this wave's n-half ----
    bf16x8 qf = *(const bf16x8*)(qbf + ((long long)pb * HW + my * 64 + mx) * 128
                                 + h * 32 + 8 * g);
    const unsigned short* kbase = kbf + ((long long)pb * 256 + lm) * 128
                                  + h * 32 + 8 * g;
    f32x4 zero = {0.f, 0.f, 0.f, 0.f};
    f32x4 acc[8];
    __builtin_amdgcn_s_setprio(1);
#pragma unroll
    for (int ni = 0; ni < 8; ni++) {
        bf16x8 kf = *(const bf16x8*)(kbase + (nb + ni * 16) * 128);
        acc[ni] = __builtin_amdgcn_mfma_f32_16x16x32_bf16(kf, qf, zero, 0, 0, 0);
    }
    __builtin_amdgcn_s_setprio(0);

    // ---- RPE bias: 2 aligned dword reads + 2 dot2 per logit ----
    int laneoff = mx * 4;
    const char* tb = (const char*)tab;
#pragma unroll
    for (int ni = 0; ni < 8; ni++) {
#pragma unroll
        for (int r = 0; r < 4; r++) {
            int n = nb + ni * 16 + 4 * g + r;
            uint4 pw = prm[n];
            int va = (int)pw.z + laneoff;
            unsigned d0 = *(const unsigned*)(tb + va);
            unsigned d1 = *(const unsigned*)(tb + va + 4);
            float t = acc[ni][r];
            t = dot2bf(d0, pw.x, t);
            t = dot2bf(d1, pw.y, t);
            acc[ni][r] = t;
        }
    }

    // ---- local max over this half ----
    float mloc = -1e30f;
#pragma unroll
    for (int ni = 0; ni < 8; ni++)
        mloc = fmaxf(mloc, fmaxf(fmaxf(acc[ni][0], acc[ni][1]),
                                 fmaxf(acc[ni][2], acc[ni][3])));
    mloc = fmaxf(mloc, __shfl_xor(mloc, 16));
    mloc = fmaxf(mloc, __shfl_xor(mloc, 32));

    // exchange buffers in the dead tab region (after B0):
    //   mex bytes [0,512), sex [512,1024), oex [1024,9216),
    //   bounce bytes [9216,14336) -- all within 32 KB, disjoint.
    float* mex = (float*)tab;                 // [2][64]
    float* sex = (float*)tab + 128;           // [2][64]
    float* oex = (float*)tab + 256;           // [4 mq][64 lane][8]
    __syncthreads();                          // B0: all tab reads complete
    if (g == 0) mex[nh * 64 + mx] = mloc;
    __syncthreads();                          // B1
    float mglob = fmaxf(mex[mx], mex[64 + mx]);

    // ---- e, local sum, pack ----
    float lsum = 0.f;
    unsigned dwA[8], dwB[8];
#pragma unroll
    for (int ni = 0; ni < 8; ni++) {
        float e0 = __expf(acc[ni][0] - mglob);
        float e1 = __expf(acc[ni][1] - mglob);
        float e2 = __expf(acc[ni][2] - mglob);
        float e3 = __expf(acc[ni][3] - mglob);
        lsum += (e0 + e1) + (e2 + e3);
        asm("v_cvt_pk_bf16_f32 %0, %1, %2" : "=v"(dwA[ni]) : "v"(e0), "v"(e1));
        asm("v_cvt_pk_bf16_f32 %0, %1, %2" : "=v"(dwB[ni]) : "v"(e2), "v"(e3));
    }
    lsum += __shfl_xor(lsum, 16);
    lsum += __shfl_xor(lsum, 32);
    if (g == 0) sex[nh * 64 + mx] = lsum;

    // ---- PV for this n-half ----
    int src0 = ((g & 1) << 5) + lm;
    int src1 = src0 + 16;
    bool sel = (g >> 1) != 0;
    const unsigned short* vb0 = vbf + ((long long)pb * 128 + h * 32 + lm) * 256
                                + 8 * g + nb;
    f32x4 o0 = zero, o1 = zero;
#pragma unroll
    for (int st = 0; st < 4; st++) {
        unsigned d0a = __shfl(dwA[2 * st], src0), d0b = __shfl(dwA[2 * st + 1], src0);
        unsigned d1a = __shfl(dwB[2 * st], src0), d1b = __shfl(dwB[2 * st + 1], src0);
        unsigned d2a = __shfl(dwA[2 * st], src1), d2b = __shfl(dwA[2 * st + 1], src1);
        unsigned d3a = __shfl(dwB[2 * st], src1), d3b = __shfl(dwB[2 * st + 1], src1);
        union { unsigned u[4]; bf16x8 v; } pf;
        pf.u[0] = sel ? d0b : d0a;
        pf.u[1] = sel ? d1b : d1a;
        pf.u[2] = sel ? d2b : d2a;
        pf.u[3] = sel ? d3b : d3a;
        bf16x8 v0 = *(const bf16x8*)(vb0 + st * 32);
        bf16x8 v1 = *(const bf16x8*)(vb0 + 4096 + st * 32);
        __builtin_amdgcn_s_setprio(1);
        o0 = __builtin_amdgcn_mfma_f32_16x16x32_bf16(v0, pf.v, o0, 0, 0, 0);
        o1 = __builtin_amdgcn_mfma_f32_16x16x32_bf16(v1, pf.v, o1, 0, 0, 0);
        __builtin_amdgcn_s_setprio(0);
    }

    // ---- combine halves ----
    if (nh == 1) {
        float* od = oex + (mq * 64 + lane) * 8;
#pragma unroll
        for (int r = 0; r < 4; r++) { od[r] = o0[r]; od[4 + r] = o1[r]; }
    }
    __syncthreads();                          // B2
    if (nh == 1) return;

    const float* os = oex + (mq * 64 + lane) * 8;
#pragma unroll
    for (int r = 0; r < 4; r++) { o0[r] += os[r]; o1[r] += os[4 + r]; }
    float inv = 1.f / (sex[mx] + sex[64 + mx]);

    // ---- output: bf16 [m][c] via LDS bounce ----
    unsigned short* bounce = (unsigned short*)tab + 4608;
    {
        unsigned short* rw = bounce + mq * 640 + lm * 40;
        *(unsigned*)(rw + g * 4) =
            (unsigned)f2bf(o0[0] * inv) | ((unsigned)f2bf(o0[1] * inv) << 16);
        *(unsigned*)(rw + g * 4 + 2) =
            (unsigned)f2bf(o0[2] * inv) | ((unsigned)f2bf(o0[3] * inv) << 16);
        *(unsigned*)(rw + 16 + g * 4) =
            (unsigned)f2bf(o1[0] * inv) | ((unsigned)f2bf(o1[1] * inv) << 16);
        *(unsigned*)(rw + 16 + g * 4 + 2) =
            (unsigned)f2bf(o1[2] * inv) | ((unsigned)f2bf(o1[3] * inv) << 16);
    }
    int row = lane >> 2, cb = lane & 3;
    uint4 vv = *(const uint4*)(bounce + mq * 640 + row * 40 + cb * 8);
    *(uint4*)(obf + ((long long)pb * HW + my * 64 + mq * 16 + row) * 128
              + h * 32 + cb * 8) = vv;
}

// ---------------------------------------------------------------------------
// K6) conv_wo via MFMA (bf16): out = x + sum_p Wo[p] o[p] + bo on chans
//     128:256 of vars 1,2. obf is bf16 [m][c]: contiguous 16B B-fragments.
__global__ __launch_bounds__(256) void conv_wo(const float* __restrict__ x1,
                                               const float* __restrict__ x2,
                                               const unsigned short* __restrict__ obf,
                                               const unsigned short* __restrict__ woh,
                                               const float* __restrict__ bo,
                                               float* __restrict__ out) {
    int wid = threadIdx.x >> 6, lane = threadIdx.x & 63;
    int g = lane >> 4, lm = lane & 15;
    int gw = blockIdx.x * 4 + wid;            // 2048 waves
    int mt = gw & 255;
    int b = (gw >> 8) & 3;
    int vs = gw >> 10;
    int m = mt * 16 + lm;
    int np = vs + 1;

    f32x4 acc[8];
#pragma unroll
    for (int ct = 0; ct < 8; ct++) acc[ct] = (f32x4){0.f, 0.f, 0.f, 0.f};

    for (int pi = 0; pi < np; pi++) {
        int p = vs ? (1 + pi) : 0;
        const unsigned short* Om = obf + ((long long)(p * 4 + b) * HW + m) * 128;
        const unsigned short* WH = woh + p * 16384;
#pragma unroll
        for (int ksl = 0; ksl < 4; ksl++) {
            bf16x8 bh = *(const bf16x8*)(Om + ksl * 32 + 8 * g);
#pragma unroll
            for (int ct = 0; ct < 8; ct++) {
                bf16x8 A = *(const bf16x8*)(WH + (ct * 16 + lm) * 128 + ksl * 32 + 8 * g);
                acc[ct] = __builtin_amdgcn_mfma_f32_16x16x32_bf16(A, bh, acc[ct], 0, 0, 0);
            }
        }
    }

    int qi = vs + 1;
    const float* xq = (vs ? x2 : x1) + (long long)b * CC * HW;
#pragma unroll
    for (int ct = 0; ct < 8; ct++)
#pragma unroll
        for (int r = 0; r < 4; r++) {
            int c = ct * 16 + 4 * g + r;
            float bias = vs ? (bo[128 + c] + bo[256 + c]) : bo[c];
            float base = xq[(long long)(128 + c) * HW + m];
            out[(((long long)(qi * 4 + b)) * CC + 128 + c) * HW + m]
                = base + acc[ct][r] + bias;
        }
}

// ---------------------------------------------------------------------------
extern "C" void kernel_launch(void* const* d_in, const int* in_sizes, int n_in,
                              void* d_out, int out_size, void* d_ws, size_t ws_size,
                              hipStream_t stream) {
    const float* x0 = (const float*)d_in[0];
    const float* x1 = (const float*)d_in[1];
    const float* x2 = (const float*)d_in[2];
    const float* Wq = (const float*)d_in[3];
    const float* bq = (const float*)d_in[4];
    const float* Wk = (const float*)d_in[5];
    const float* bk = (const float*)d_in[6];
    const float* Wv = (const float*)d_in[7];
    const float* bv = (const float*)d_in[8];
    const float* Wo = (const float*)d_in[9];
    const float* bo = (const float*)d_in[10];
    const float* dw_w = (const float*)d_in[11];
    const float* dw_b = (const float*)d_in[12];
    const float* ln_g = (const float*)d_in[13];
    const float* ln_b = (const float*)d_in[14];
    const float* pw_w = (const float*)d_in[15];
    const float* rpe = (const float*)d_in[16];
    float* out = (float*)d_out;

    // Workspace. obf bf16 at ws start.
    float* ws = (float*)d_ws;
    unsigned short* obf = (unsigned short*)ws;               // 6291456 s (12 MB)
    float* posb = ws + 6291456;                              // 6144 f
    unsigned short* xT = (unsigned short*)(posb + 6144);     // 4194304 s (8 MB)
    unsigned short* qbf = xT + 4194304;                      // 12582912 s (24 MB)
    unsigned short* kbf = qbf + 12582912;                    // 393216 s
    unsigned short* vbf = kbf + 393216;                      // 393216 s
    unsigned* dtabbf = (unsigned*)(vbf + 393216);            // 196608 u (768 KB)
    uint4* prmb = (uint4*)(dtabbf + 196608);                 // 3072 uint4
    unsigned short* wqh = (unsigned short*)(prmb + 3072);    // 49152 s
    unsigned short* woh = wqh + 49152;
    unsigned short* wkh = woh + 49152;
    unsigned short* wvh = wkh + 49152;

    prep_copy<<<1048, 256, 0, stream>>>(rpe, Wq, Wo, Wk, Wv, x0, dtabbf,
                                        wqh, woh, wkh, wvh, out);
    conv_q<<<512, 256, 0, stream>>>(x1, x2, wqh, bq, qbf, out);
    mid_kernel<<<2240, 256, 0, stream>>>(qbf, dw_w, dw_b, ln_g, ln_b, pw_w,
                                         x0, x1, posb, prmb, xT);
    sample_kv<<<96, 256, 0, stream>>>(xT, posb, wkh, wvh, bk, bv, kbf, vbf);
    attn_mfma<<<3072, 512, 0, stream>>>(qbf, kbf, vbf, dtabbf, prmb, obf);
    conv_wo<<<512, 256, 0, stream>>>(x1, x2, obf, woh, bo, out);
}